// Round 1
// baseline (948.450 us; speedup 1.0000x reference)
//
#include <hip/hip_runtime.h>

// Problem constants: B=4, C_IN=64, NUM_HIDDEN=64, H=W=128, MOVESQ=9, T=8
#define NP 16384            // H*W
#define G3 192              // 3*NUM_HIDDEN
#define HID_SZ 4194304      // 4*64*NP
#define O_SZ   589824       // 4*9*NP
#define OUTS_OFF 33554432   // 8*HID_SZ
#define LOSS_OFF 38273024   // OUTS_OFF + 8*O_SZ

// Workspace layout (floats). Requires ~67.6 MB of d_ws.
#define WS_IALL 0           // 4*192*NP = 12,582,912
#define WS_HY   12582912    // 4*64*NP  =  4,194,304
#define WS_WHHT 16777216    // 64*192   = 12,288   (w_hh transposed)
#define WS_WHOT 16789504    // 64*9     = 576      (w_ho transposed)
#define WS_WIHT 16790080    // 576*192  = 110,592  (w_ih transposed)
#define WS_BCEP 16900672    // 8*256 partials
#define WS_BCET 16902720    // 1 scalar

__device__ __forceinline__ float frcp(float x) { return __builtin_amdgcn_rcpf(x); }

// ---------------------------------------------------------------- transposes
__global__ void prep_kernel(const float* __restrict__ w_hh, const float* __restrict__ w_ho,
                            const float* __restrict__ w_ih,
                            float* __restrict__ whhT, float* __restrict__ whoT,
                            float* __restrict__ wihT) {
    int i = blockIdx.x * 256 + threadIdx.x;
    if (i < 12288) {                       // whhT[c*192+o] = w_hh[o*64+c]
        int c = i / 192, o = i % 192;
        whhT[i] = w_hh[o * 64 + c];
    } else if (i < 12288 + 576) {          // whoT[c*9+d] = w_ho[d*64+c]
        int j = i - 12288;
        int c = j / 9, d = j % 9;
        whoT[j] = w_ho[d * 64 + c];
    } else if (i < 12288 + 576 + 110592) { // wihT[ick*192+oc] = w_ih[oc*576+ick]
        int k = i - 12864;
        int ick = k / 192, oc = k % 192;
        wihT[k] = w_ih[oc * 576 + ick];
    }
}

// ---------------------------------------------------------------- conv (once)
// i_all[b][oc][y][x] = b_ih[oc] + sum_{ic,ky,kx} x[b][ic][y+ky-1][x+kx-1]*w
// grid (256 pixel-blocks, 12 oc-chunks of 16); weights via uniform s_loads.
__global__ __launch_bounds__(256) void conv_kernel(const float* __restrict__ x,
                                                   const float* __restrict__ b_ih,
                                                   const float* __restrict__ wihT,
                                                   float* __restrict__ i_all) {
    const int p  = blockIdx.x * 256 + threadIdx.x;
    const int b  = p >> 14, yx = p & 16383, y = yx >> 7, xx = yx & 127;
    const int oc0 = blockIdx.y * 16;

    int   ofs[9];
    float okf[9];
#pragma unroll
    for (int ky = 0; ky < 3; ky++)
#pragma unroll
        for (int kx = 0; kx < 3; kx++) {
            int ny = y + ky - 1, nx = xx + kx - 1;
            bool ok = (ny >= 0) && (ny < 128) && (nx >= 0) && (nx < 128);
            int cy = min(max(ny, 0), 127), cx = min(max(nx, 0), 127);
            ofs[ky * 3 + kx] = cy * 128 + cx;
            okf[ky * 3 + kx] = ok ? 1.0f : 0.0f;
        }

    float acc[16];
#pragma unroll
    for (int k = 0; k < 16; k++) acc[k] = b_ih[oc0 + k];

    const float* xb = x + b * 64 * NP;
    for (int ic = 0; ic < 64; ic++) {
        const float* xc = xb + ic * NP;
#pragma unroll
        for (int kk = 0; kk < 9; kk++) {
            float xv = xc[ofs[kk]] * okf[kk];
            const float* wrow = wihT + (ic * 9 + kk) * 192 + oc0;  // uniform -> s_load
#pragma unroll
            for (int k = 0; k < 16; k++) acc[k] = fmaf(xv, wrow[k], acc[k]);
        }
    }
#pragma unroll
    for (int k = 0; k < 16; k++) i_all[(b * G3 + oc0 + k) * NP + yx] = acc[k];
}

// ---------------------------------------------------------------- per-step gates
// hh = W_hh @ hid + b_hh ; GRU gates ; hy ; o = softmax(W_ho @ hy + b_ho) ; bce partial
template <bool FIRST>
__global__ __launch_bounds__(256) void gates_kernel(const float* __restrict__ hid_prev,
                                                    const float* __restrict__ i_all,
                                                    const float* __restrict__ whhT,
                                                    const float* __restrict__ b_hh,
                                                    const float* __restrict__ whoT,
                                                    const float* __restrict__ b_ho,
                                                    const float* __restrict__ mask,
                                                    float* __restrict__ hy_out,
                                                    float* __restrict__ o_out,
                                                    float* __restrict__ bce_partial) {
    const int tid = threadIdx.x;
    const int p = blockIdx.x * 256 + tid;
    const int b = p >> 14, yx = p & 16383;

    // per-thread hid vector in LDS columns (conflict-free: lane t -> bank t%32)
    __shared__ float hlds[64 * 256];
    if (!FIRST) {
#pragma unroll 8
        for (int c = 0; c < 64; c++) hlds[c * 256 + tid] = hid_prev[(b * 64 + c) * NP + yx];
    }

    float olog[9];
#pragma unroll
    for (int d = 0; d < 9; d++) olog[d] = b_ho[d];

    const float* ia = i_all + b * G3 * NP + yx;

    for (int g0 = 0; g0 < 64; g0 += 8) {
        float ar[8], ai[8], an[8];
#pragma unroll
        for (int k = 0; k < 8; k++) {
            ar[k] = b_hh[g0 + k];
            ai[k] = b_hh[64 + g0 + k];
            an[k] = b_hh[128 + g0 + k];
        }
        if (!FIRST) {
            for (int c = 0; c < 64; c++) {
                float h = hlds[c * 256 + tid];
                const float* w = whhT + c * 192 + g0;  // uniform -> s_load_dwordx8 x3
#pragma unroll
                for (int k = 0; k < 8; k++) ar[k] = fmaf(h, w[k], ar[k]);
#pragma unroll
                for (int k = 0; k < 8; k++) ai[k] = fmaf(h, w[64 + k], ai[k]);
#pragma unroll
                for (int k = 0; k < 8; k++) an[k] = fmaf(h, w[128 + k], an[k]);
            }
        }
#pragma unroll
        for (int k = 0; k < 8; k++) {
            const int g = g0 + k;
            float ir  = ia[g * NP];
            float iiv = ia[(64 + g) * NP];
            float inn = ia[(128 + g) * NP];
            float r  = frcp(1.0f + __expf(-(ir + ar[k])));
            float ig = frcp(1.0f + __expf(-(iiv + ai[k])));
            float t2 = __expf(2.0f * (inn + r * an[k]));
            float n  = 1.0f - 2.0f * frcp(t2 + 1.0f);   // tanh, no NaN at extremes
            float hprev_g = FIRST ? 0.0f : hlds[g * 256 + tid];
            float hyv = n + ig * (hprev_g - n);
            hy_out[(b * 64 + g) * NP + yx] = hyv;
            const float* wh = whoT + g * 9;             // uniform -> s_load
#pragma unroll
            for (int d = 0; d < 9; d++) olog[d] = fmaf(hyv, wh[d], olog[d]);
        }
    }

    // softmax over 9
    float m = olog[0];
#pragma unroll
    for (int d = 1; d < 9; d++) m = fmaxf(m, olog[d]);
    float e[9], s = 0.0f;
#pragma unroll
    for (int d = 0; d < 9; d++) { e[d] = __expf(olog[d] - m); s += e[d]; }
    float inv = frcp(s);
#pragma unroll
    for (int d = 0; d < 9; d++) o_out[(b * 9 + d) * NP + yx] = e[d] * inv;

    // bce partial (deterministic block tree reduction)
    float o4 = e[4] * inv;
    float mk = mask[b * NP + yx];
    float v = mk * __logf(1.0f - o4) + (1.0f - mk) * __logf(o4);
    __shared__ float red[256];
    red[tid] = v;
    __syncthreads();
    for (int off = 128; off > 0; off >>= 1) {
        if (tid < off) red[tid] += red[tid + off];
        __syncthreads();
    }
    if (tid == 0) bce_partial[blockIdx.x] = red[0];
}

// ---------------------------------------------------------------- per-step merge + diff loss
// h_next(y,x,c) = sum_{ey,ex} hy(y+ey,x+ex,c) * o(j(ey,ex), y+ey, x+ex), j=3*(1-ey)+(1-ex)
// loss(b,i) += 0.01 * (o4(y+dy,x+dx) - o_i)^2 * o_i,  dy=i/3-1, dx=i%3-1
template <bool FIRSTLOSS>
__global__ __launch_bounds__(256) void merge_kernel(const float* __restrict__ hy,
                                                    const float* __restrict__ o_t,
                                                    float* __restrict__ h_next,
                                                    float* __restrict__ loss) {
    const int p = blockIdx.x * 256 + threadIdx.x;
    const int b = p >> 14, yx = p & 16383, y = yx >> 7, xx = yx & 127;
    const int cg = blockIdx.y;  // 0..3, 16 channels each
    const float* ob = o_t + b * 9 * NP;

    float onb[9];
    int   nofs[9];
#pragma unroll
    for (int ey = -1; ey <= 1; ey++) {
#pragma unroll
        for (int ex = -1; ex <= 1; ex++) {
            const int idx = (ey + 1) * 3 + (ex + 1);
            int ny = y + ey, nx = xx + ex;
            bool ok = (ny >= 0) && (ny < 128) && (nx >= 0) && (nx < 128);
            int cy = min(max(ny, 0), 127), cx = min(max(nx, 0), 127);
            nofs[idx] = cy * 128 + cx;
            const int j = 3 * (1 - ey) + (1 - ex);
            float v = ob[j * NP + nofs[idx]];
            onb[idx] = ok ? v : 0.0f;   // hy values finite -> 0*garbage-free via select
        }
    }

    const float* hyb = hy + b * 64 * NP;
#pragma unroll 4
    for (int cc = 0; cc < 16; cc++) {
        const int c = cg * 16 + cc;
        const float* hc = hyb + c * NP;
        float a = 0.0f;
#pragma unroll
        for (int idx = 0; idx < 9; idx++) a = fmaf(hc[nofs[idx]], onb[idx], a);
        h_next[(b * 64 + c) * NP + yx] = a;
    }

    if (cg == 0) {
        const float* o4p = ob + 4 * NP;
#pragma unroll
        for (int i = 0; i < 9; i++) {
            const int dy = i / 3 - 1, dx = i % 3 - 1;
            int ny = y + dy, nx = xx + dx;
            bool ok = (ny >= 0) && (ny < 128) && (nx >= 0) && (nx < 128);
            int cy = min(max(ny, 0), 127), cx = min(max(nx, 0), 127);
            float g = ok ? o4p[cy * 128 + cx] : 0.0f;
            float oi = ob[i * NP + yx];
            float d = g - oi;
            float dv = d * d * oi * 0.01f;
            const int li = (b * 9 + i) * NP + yx;
            if (FIRSTLOSS) loss[li] = dv;
            else           loss[li] += dv;
        }
    }
}

// ---------------------------------------------------------------- bce finalize
__global__ void bce_reduce_kernel(const float* __restrict__ partial, float* __restrict__ out_tot) {
    __shared__ float red[256];
    float s = 0.0f;
    for (int i = threadIdx.x; i < 2048; i += 256) s += partial[i];
    red[threadIdx.x] = s;
    __syncthreads();
    for (int off = 128; off > 0; off >>= 1) {
        if (threadIdx.x < off) red[threadIdx.x] += red[threadIdx.x + off];
        __syncthreads();
    }
    if (threadIdx.x == 0) *out_tot = -red[0] * (1.0f / 65536.0f);
}

__global__ void finalize_kernel(float* __restrict__ loss, const float* __restrict__ tot) {
    int i = blockIdx.x * 256 + threadIdx.x;
    loss[i] += *tot;
}

// ---------------------------------------------------------------- launcher
extern "C" void kernel_launch(void* const* d_in, const int* in_sizes, int n_in,
                              void* d_out, int out_size, void* d_ws, size_t ws_size,
                              hipStream_t stream) {
    const float* x    = (const float*)d_in[0];
    const float* mask = (const float*)d_in[1];
    const float* w_ih = (const float*)d_in[2];
    const float* b_ih = (const float*)d_in[3];
    const float* w_hh = (const float*)d_in[4];
    const float* b_hh = (const float*)d_in[5];
    const float* w_ho = (const float*)d_in[6];
    const float* b_ho = (const float*)d_in[7];
    float* out = (float*)d_out;
    float* ws  = (float*)d_ws;

    float* i_all = ws + WS_IALL;
    float* hy    = ws + WS_HY;
    float* whhT  = ws + WS_WHHT;
    float* whoT  = ws + WS_WHOT;
    float* wihT  = ws + WS_WIHT;
    float* bceP  = ws + WS_BCEP;
    float* bceT  = ws + WS_BCET;

    prep_kernel<<<483, 256, 0, stream>>>(w_hh, w_ho, w_ih, whhT, whoT, wihT);
    conv_kernel<<<dim3(256, 12), 256, 0, stream>>>(x, b_ih, wihT, i_all);

    for (int t = 0; t < 8; t++) {
        float* hprev = out + (t - 1) * HID_SZ;
        float* hnext = out + t * HID_SZ;
        float* o_t   = out + OUTS_OFF + t * O_SZ;
        float* lossp = out + LOSS_OFF;
        if (t == 0) {
            gates_kernel<true><<<256, 256, 0, stream>>>(nullptr, i_all, whhT, b_hh, whoT,
                                                        b_ho, mask, hy, o_t, bceP);
            merge_kernel<true><<<dim3(256, 4), 256, 0, stream>>>(hy, o_t, hnext, lossp);
        } else {
            gates_kernel<false><<<256, 256, 0, stream>>>(hprev, i_all, whhT, b_hh, whoT,
                                                         b_ho, mask, hy, o_t, bceP + t * 256);
            merge_kernel<false><<<dim3(256, 4), 256, 0, stream>>>(hy, o_t, hnext, lossp);
        }
    }

    bce_reduce_kernel<<<1, 256, 0, stream>>>(bceP, bceT);
    finalize_kernel<<<2304, 256, 0, stream>>>(out + LOSS_OFF, bceT);
}

// Round 2
// 675.469 us; speedup vs baseline: 1.4041x; 1.4041x over previous
//
#include <hip/hip_runtime.h>

// B=4, C_IN=64, NUM_HIDDEN=64, H=W=128, MOVESQ=9, T=8
#define NP 16384
#define HID_SZ 4194304      // 4*64*NP
#define O_SZ   589824       // 4*9*NP
#define OUTS_OFF 33554432   // 8*HID_SZ
#define LOSS_OFF 38273024   // OUTS_OFF + 8*O_SZ

// ws layout (float units). Total 16,902,721 floats = 67.6 MB (same as round 0).
#define WS_IALL 0           // 12,582,912: i_all [4][16384][192] CHANNEL-LAST
#define WS_XT   12582912    // 4,194,304 floats: xTh/xTl (8,388,608 ushorts); reused as hy after conv
#define WS_WHHT 16777216    // 12,288
#define WS_WHOT 16789504    // 576
#define WS_BTH  16790080    // 55,296 floats = 110,592 ushorts
#define WS_BTL  16845376    // 55,296 floats
#define WS_BCEP 16900672    // 2048
#define WS_BCET 16902720    // 1

typedef __attribute__((ext_vector_type(8))) short bf16x8;
typedef __attribute__((ext_vector_type(8))) unsigned short ushort8;
typedef __attribute__((ext_vector_type(4))) float f32x4;

__device__ __forceinline__ float frcp(float x) { return __builtin_amdgcn_rcpf(x); }
__device__ __forceinline__ unsigned short f2bf(float f) {
    unsigned int u = __float_as_uint(f);
    return (unsigned short)((u + 0x7fffu + ((u >> 16) & 1u)) >> 16);
}
__device__ __forceinline__ float bf2f(unsigned short h) {
    return __uint_as_float(((unsigned int)h) << 16);
}

// ------------------------------------------------------------- weight prep
// whhT[c*192+o]=w_hh[o][c]; whoT[c*9+d]=w_ho[d][c];
// BT[oc*576 + tap*64 + ic] = w_ih[oc][ic][tap] split into bf16 hi/lo.
__global__ void prep_weights(const float* __restrict__ w_hh, const float* __restrict__ w_ho,
                             const float* __restrict__ w_ih,
                             float* __restrict__ whhT, float* __restrict__ whoT,
                             unsigned short* __restrict__ BTh, unsigned short* __restrict__ BTl) {
    int i = blockIdx.x * 256 + threadIdx.x;
    if (i < 12288) {
        int c = i / 192, o = i % 192;
        whhT[i] = w_hh[o * 64 + c];
    } else if (i < 12864) {
        int j = i - 12288, c = j / 9, d = j % 9;
        whoT[j] = w_ho[d * 64 + c];
    } else if (i < 12864 + 110592) {
        int k2 = i - 12864;
        int oc = k2 / 576, kk = k2 % 576, tap = kk >> 6, ic = kk & 63;
        float f = w_ih[(oc * 64 + ic) * 9 + tap];
        unsigned short h = f2bf(f);
        BTh[k2] = h;
        BTl[k2] = f2bf(f - bf2f(h));
    }
}

// ------------------------------------------------------------- x -> channel-last bf16 hi/lo
__global__ __launch_bounds__(256) void transpose_x(const float* __restrict__ x,
                                                   unsigned short* __restrict__ xTh,
                                                   unsigned short* __restrict__ xTl) {
    const int p = blockIdx.x * 256 + threadIdx.x;
    const int b = p >> 14, yx = p & 16383;
    const size_t base = ((size_t)p) << 6;  // *64
    for (int ic0 = 0; ic0 < 64; ic0 += 8) {
        ushort8 vh, vl;
#pragma unroll
        for (int j = 0; j < 8; ++j) {
            float f = x[(((size_t)(b * 64 + ic0 + j)) << 14) + yx];
            unsigned short h = f2bf(f);
            vh[j] = h;
            vl[j] = f2bf(f - bf2f(h));
        }
        *(ushort8*)(xTh + base + ic0) = vh;
        *(ushort8*)(xTl + base + ic0) = vl;
    }
}

// ------------------------------------------------------------- conv as implicit-GEMM MFMA
// Block: 256 thr = 4 waves, 64 consecutive pixels (half an image row), wave w -> oc chunk 48w.
// K = 576 (tap-major: k = tap*64 + ic), 18 k-steps of 32.
__global__ __launch_bounds__(256) void conv_mfma(const unsigned short* __restrict__ xTh,
                                                 const unsigned short* __restrict__ xTl,
                                                 const unsigned short* __restrict__ BTh,
                                                 const unsigned short* __restrict__ BTl,
                                                 const float* __restrict__ b_ih,
                                                 float* __restrict__ i_all) {
    const int tid = threadIdx.x;
    const int wave = tid >> 6, lane = tid & 63;
    const int b = blockIdx.x >> 8;
    const int yx0 = (blockIdx.x << 6) & 16383;
    const int y = yx0 >> 7, x0 = yx0 & 127;
    const int oc0 = wave * 48;
    const int lrow = lane & 15, lk = (lane >> 4) << 3;
    const bf16x8 az = {};

    f32x4 acc[4][3] = {};

    for (int tap = 0; tap < 9; ++tap) {
        const int dy = tap / 3 - 1, dx = tap % 3 - 1;
        const int y2 = y + dy;
        const bool yok = (y2 >= 0) && (y2 < 128);
        const int cy = min(max(y2, 0), 127);
        for (int ih = 0; ih < 2; ++ih) {
            const int k0 = tap * 64 + ih * 32;
            bf16x8 Bh[3], Bl[3];
#pragma unroll
            for (int n = 0; n < 3; ++n) {
                const size_t bo = (size_t)(oc0 + n * 16 + lrow) * 576 + k0 + lk;
                Bh[n] = *(const bf16x8*)(BTh + bo);
                Bl[n] = *(const bf16x8*)(BTl + bo);
            }
            bf16x8 Ah[4], Al[4];
#pragma unroll
            for (int m = 0; m < 4; ++m) {
                const int x2 = x0 + m * 16 + lrow + dx;
                const bool ok = yok && (x2 >= 0) && (x2 < 128);
                const int cx = min(max(x2, 0), 127);
                const size_t ao = ((size_t)(b * 16384 + cy * 128 + cx)) * 64 + ih * 32 + lk;
                bf16x8 ah = *(const bf16x8*)(xTh + ao);
                bf16x8 al = *(const bf16x8*)(xTl + ao);
                Ah[m] = ok ? ah : az;
                Al[m] = ok ? al : az;
            }
#pragma unroll
            for (int m = 0; m < 4; ++m)
#pragma unroll
                for (int n = 0; n < 3; ++n) {
                    acc[m][n] = __builtin_amdgcn_mfma_f32_16x16x32_bf16(Ah[m], Bh[n], acc[m][n], 0, 0, 0);
                    acc[m][n] = __builtin_amdgcn_mfma_f32_16x16x32_bf16(Ah[m], Bl[n], acc[m][n], 0, 0, 0);
                    acc[m][n] = __builtin_amdgcn_mfma_f32_16x16x32_bf16(Al[m], Bh[n], acc[m][n], 0, 0, 0);
                }
        }
    }

    // C/D layout: col(oc) = lane&15, row(px) = (lane>>4)*4 + r  [verified mapping]
    const int crow0 = (lane >> 4) << 2;
#pragma unroll
    for (int n = 0; n < 3; ++n) {
        const int oc = oc0 + n * 16 + lrow;
        const float bias = b_ih[oc];
#pragma unroll
        for (int m = 0; m < 4; ++m)
#pragma unroll
            for (int r = 0; r < 4; ++r) {
                const int pm = m * 16 + crow0 + r;
                i_all[((size_t)b * 16384 + yx0 + pm) * 192 + oc] = acc[m][n][r] + bias;
            }
    }
}

// ------------------------------------------------------------- per-step: hy for one 16-g chunk
template <bool FIRST>
__global__ __launch_bounds__(128) void hy_kernel(const float* __restrict__ hprev,
                                                 const float* __restrict__ i_all,
                                                 const float* __restrict__ whhT,
                                                 const float* __restrict__ b_hh,
                                                 float* __restrict__ hy) {
    const int tid = threadIdx.x;
    const int p = blockIdx.x * 128 + tid;
    const int b = p >> 14, yx = p & 16383;
    const int g0 = blockIdx.y * 16;

    float ar[16], ai[16], an[16];
#pragma unroll
    for (int k = 0; k < 16; ++k) {
        ar[k] = b_hh[g0 + k];
        ai[k] = b_hh[64 + g0 + k];
        an[k] = b_hh[128 + g0 + k];
    }
    if (!FIRST) {
        const float* hp = hprev + (((size_t)b) << 20) + yx;
        for (int c0 = 0; c0 < 64; c0 += 8) {
            float h[8];
#pragma unroll
            for (int j = 0; j < 8; ++j) h[j] = hp[((size_t)(c0 + j)) << 14];
#pragma unroll
            for (int j = 0; j < 8; ++j) {
                const float* w = whhT + (c0 + j) * 192 + g0;  // uniform -> s_load
#pragma unroll
                for (int k = 0; k < 16; ++k) ar[k] = fmaf(h[j], w[k], ar[k]);
#pragma unroll
                for (int k = 0; k < 16; ++k) ai[k] = fmaf(h[j], w[64 + k], ai[k]);
#pragma unroll
                for (int k = 0; k < 16; ++k) an[k] = fmaf(h[j], w[128 + k], an[k]);
            }
        }
    }

    const f32x4* ia = (const f32x4*)(i_all + (size_t)p * 192);
    f32x4 fr[4], fi[4], fn[4];
#pragma unroll
    for (int j = 0; j < 4; ++j) {
        fr[j] = ia[(g0 >> 2) + j];
        fi[j] = ia[16 + (g0 >> 2) + j];
        fn[j] = ia[32 + (g0 >> 2) + j];
    }
#pragma unroll
    for (int k = 0; k < 16; ++k) {
        float r  = frcp(1.0f + __expf(-(fr[k >> 2][k & 3] + ar[k])));
        float ig = frcp(1.0f + __expf(-(fi[k >> 2][k & 3] + ai[k])));
        float t2 = __expf(2.0f * (fn[k >> 2][k & 3] + r * an[k]));
        float n  = 1.0f - 2.0f * frcp(t2 + 1.0f);
        float hpg = 0.0f;
        if (!FIRST) hpg = hprev[(((size_t)b) << 20) + (((size_t)(g0 + k)) << 14) + yx];
        hy[(((size_t)b) << 20) + (((size_t)(g0 + k)) << 14) + yx] = n + ig * (hpg - n);
    }
}

// ------------------------------------------------------------- per-step: softmax o + bce partial
__global__ __launch_bounds__(256) void o_kernel(const float* __restrict__ hy,
                                                const float* __restrict__ whoT,
                                                const float* __restrict__ b_ho,
                                                const float* __restrict__ mask,
                                                float* __restrict__ o_out,
                                                float* __restrict__ bceP) {
    const int tid = threadIdx.x;
    const int p = blockIdx.x * 256 + tid;
    const int b = p >> 14, yx = p & 16383;

    float olog[9];
#pragma unroll
    for (int d = 0; d < 9; ++d) olog[d] = b_ho[d];
    const float* hb = hy + (((size_t)b) << 20) + yx;
    for (int c0 = 0; c0 < 64; c0 += 8) {
        float h[8];
#pragma unroll
        for (int j = 0; j < 8; ++j) h[j] = hb[((size_t)(c0 + j)) << 14];
#pragma unroll
        for (int j = 0; j < 8; ++j) {
            const float* w = whoT + (c0 + j) * 9;  // uniform -> s_load
#pragma unroll
            for (int d = 0; d < 9; ++d) olog[d] = fmaf(h[j], w[d], olog[d]);
        }
    }
    float m = olog[0];
#pragma unroll
    for (int d = 1; d < 9; ++d) m = fmaxf(m, olog[d]);
    float e[9], s = 0.0f;
#pragma unroll
    for (int d = 0; d < 9; ++d) { e[d] = __expf(olog[d] - m); s += e[d]; }
    float inv = frcp(s);
#pragma unroll
    for (int d = 0; d < 9; ++d) o_out[(((size_t)(b * 9 + d)) << 14) + yx] = e[d] * inv;

    float o4 = e[4] * inv;
    float mk = mask[(((size_t)b) << 14) + yx];
    float v = mk * __logf(1.0f - o4) + (1.0f - mk) * __logf(o4);
    __shared__ float red[256];
    red[tid] = v;
    __syncthreads();
    for (int off = 128; off > 0; off >>= 1) {
        if (tid < off) red[tid] += red[tid + off];
        __syncthreads();
    }
    if (tid == 0) bceP[blockIdx.x] = red[0];
}

// ------------------------------------------------------------- per-step merge + diff loss
template <bool FIRSTLOSS>
__global__ __launch_bounds__(256) void merge_kernel(const float* __restrict__ hy,
                                                    const float* __restrict__ o_t,
                                                    float* __restrict__ h_next,
                                                    float* __restrict__ loss) {
    const int p = blockIdx.x * 256 + threadIdx.x;
    const int b = p >> 14, yx = p & 16383, y = yx >> 7, xx = yx & 127;
    const int cg = blockIdx.y;
    const float* ob = o_t + (((size_t)b) * 9 << 14);

    float onb[9];
    int nofs[9];
#pragma unroll
    for (int ey = -1; ey <= 1; ey++) {
#pragma unroll
        for (int ex = -1; ex <= 1; ex++) {
            const int idx = (ey + 1) * 3 + (ex + 1);
            int ny = y + ey, nx = xx + ex;
            bool ok = (ny >= 0) && (ny < 128) && (nx >= 0) && (nx < 128);
            int cy = min(max(ny, 0), 127), cx = min(max(nx, 0), 127);
            nofs[idx] = cy * 128 + cx;
            const int j = 3 * (1 - ey) + (1 - ex);
            float v = ob[(((size_t)j) << 14) + nofs[idx]];
            onb[idx] = ok ? v : 0.0f;
        }
    }

    const float* hyb = hy + (((size_t)b) << 20);
#pragma unroll 4
    for (int cc = 0; cc < 16; cc++) {
        const int c = cg * 16 + cc;
        const float* hc = hyb + (((size_t)c) << 14);
        float a = 0.0f;
#pragma unroll
        for (int idx = 0; idx < 9; idx++) a = fmaf(hc[nofs[idx]], onb[idx], a);
        h_next[(((size_t)(b * 64 + c)) << 14) + yx] = a;
    }

    if (cg == 0) {
        const float* o4p = ob + (4 << 14);
#pragma unroll
        for (int i = 0; i < 9; i++) {
            const int dy = i / 3 - 1, dx = i % 3 - 1;
            int ny = y + dy, nx = xx + dx;
            bool ok = (ny >= 0) && (ny < 128) && (nx >= 0) && (nx < 128);
            int cy = min(max(ny, 0), 127), cx = min(max(nx, 0), 127);
            float g = ok ? o4p[cy * 128 + cx] : 0.0f;
            float oi = ob[(((size_t)i) << 14) + yx];
            float d = g - oi;
            float dv = d * d * oi * 0.01f;
            const size_t li = (((size_t)(b * 9 + i)) << 14) + yx;
            if (FIRSTLOSS) loss[li] = dv;
            else           loss[li] += dv;
        }
    }
}

// ------------------------------------------------------------- bce finalize
__global__ void bce_reduce_kernel(const float* __restrict__ partial, float* __restrict__ out_tot) {
    __shared__ float red[256];
    float s = 0.0f;
    for (int i = threadIdx.x; i < 2048; i += 256) s += partial[i];
    red[threadIdx.x] = s;
    __syncthreads();
    for (int off = 128; off > 0; off >>= 1) {
        if (threadIdx.x < off) red[threadIdx.x] += red[threadIdx.x + off];
        __syncthreads();
    }
    if (threadIdx.x == 0) *out_tot = -red[0] * (1.0f / 65536.0f);
}

__global__ void finalize_kernel(float* __restrict__ loss, const float* __restrict__ tot) {
    int i = blockIdx.x * 256 + threadIdx.x;
    loss[i] += *tot;
}

// ------------------------------------------------------------- launcher
extern "C" void kernel_launch(void* const* d_in, const int* in_sizes, int n_in,
                              void* d_out, int out_size, void* d_ws, size_t ws_size,
                              hipStream_t stream) {
    const float* x    = (const float*)d_in[0];
    const float* mask = (const float*)d_in[1];
    const float* w_ih = (const float*)d_in[2];
    const float* b_ih = (const float*)d_in[3];
    const float* w_hh = (const float*)d_in[4];
    const float* b_hh = (const float*)d_in[5];
    const float* w_ho = (const float*)d_in[6];
    const float* b_ho = (const float*)d_in[7];
    float* out = (float*)d_out;
    float* ws  = (float*)d_ws;

    float* i_all = ws + WS_IALL;
    unsigned short* xTh = (unsigned short*)(ws + WS_XT);
    unsigned short* xTl = xTh + 4194304;
    float* hy    = ws + WS_XT;      // reuses xT region after conv
    float* whhT  = ws + WS_WHHT;
    float* whoT  = ws + WS_WHOT;
    unsigned short* BTh = (unsigned short*)(ws + WS_BTH);
    unsigned short* BTl = (unsigned short*)(ws + WS_BTL);
    float* bceP  = ws + WS_BCEP;
    float* bceT  = ws + WS_BCET;

    prep_weights<<<483, 256, 0, stream>>>(w_hh, w_ho, w_ih, whhT, whoT, BTh, BTl);
    transpose_x<<<256, 256, 0, stream>>>(x, xTh, xTl);
    conv_mfma<<<1024, 256, 0, stream>>>(xTh, xTl, BTh, BTl, b_ih, i_all);

    for (int t = 0; t < 8; t++) {
        float* hprev = out + (size_t)(t - 1) * HID_SZ;
        float* hnext = out + (size_t)t * HID_SZ;
        float* o_t   = out + OUTS_OFF + (size_t)t * O_SZ;
        float* lossp = out + LOSS_OFF;
        if (t == 0) {
            hy_kernel<true><<<dim3(512, 4), 128, 0, stream>>>(nullptr, i_all, whhT, b_hh, hy);
            o_kernel<<<256, 256, 0, stream>>>(hy, whoT, b_ho, mask, o_t, bceP);
            merge_kernel<true><<<dim3(256, 4), 256, 0, stream>>>(hy, o_t, hnext, lossp);
        } else {
            hy_kernel<false><<<dim3(512, 4), 128, 0, stream>>>(hprev, i_all, whhT, b_hh, hy);
            o_kernel<<<256, 256, 0, stream>>>(hy, whoT, b_ho, mask, o_t, bceP + t * 256);
            merge_kernel<false><<<dim3(256, 4), 256, 0, stream>>>(hy, o_t, hnext, lossp);
        }
    }

    bce_reduce_kernel<<<1, 256, 0, stream>>>(bceP, bceT);
    finalize_kernel<<<2304, 256, 0, stream>>>(out + LOSS_OFF, bceT);
}

// Round 3
// 623.525 us; speedup vs baseline: 1.5211x; 1.0833x over previous
//
#include <hip/hip_runtime.h>

// B=4, C_IN=64, NUM_HIDDEN=64, H=W=128, MOVESQ=9, T=8
#define NP 16384
#define HID_SZ 4194304      // 4*64*NP
#define O_SZ   589824       // 4*9*NP
#define OUTS_OFF 33554432   // 8*HID_SZ
#define LOSS_OFF 38273024   // OUTS_OFF + 8*O_SZ

// ws layout (float units), total ~59.2 MB
#define WS_IALL  0          // 6,291,456 floats = 12,582,912 ushorts: i_all bf16 [4][16384][192]
#define WS_XT    6291456    // xTh/xTl 8,388,608 ushorts total (overlaps HYA/HYB; conv-only)
#define WS_HYA   6291456    // 4,194,304 floats
#define WS_HYB   10485760   // 4,194,304 floats
#define WS_WHHBH 14680064   // 12,288 ushorts = 6144 floats
#define WS_WHHBL 14686208   // 6144 floats
#define WS_WHOT  14692352   // 576 floats
#define WS_BTH   14692928   // 110,592 ushorts = 55,296 floats
#define WS_BTL   14748224   // 55,296 floats
#define WS_BCEP  14803520   // 4096 floats
#define WS_BCET  14807616   // 1 float

typedef __attribute__((ext_vector_type(8))) short bf16x8;
typedef __attribute__((ext_vector_type(8))) unsigned short ushort8;
typedef __attribute__((ext_vector_type(4))) float f32x4;

__device__ __forceinline__ float frcp(float x) { return __builtin_amdgcn_rcpf(x); }
__device__ __forceinline__ unsigned short f2bf(float f) {
    unsigned int u = __float_as_uint(f);
    return (unsigned short)((u + 0x7fffu + ((u >> 16) & 1u)) >> 16);
}
__device__ __forceinline__ float bf2f(unsigned short h) {
    return __uint_as_float(((unsigned int)h) << 16);
}

// ------------------------------------------------------------- weight prep
__global__ void prep_weights(const float* __restrict__ w_hh, const float* __restrict__ w_ho,
                             const float* __restrict__ w_ih,
                             unsigned short* __restrict__ whhBh, unsigned short* __restrict__ whhBl,
                             float* __restrict__ whoT,
                             unsigned short* __restrict__ BTh, unsigned short* __restrict__ BTl) {
    int i = blockIdx.x * 256 + threadIdx.x;
    if (i < 12288) {                        // w_hh [192][64] elementwise bf16 split (B-frag layout)
        float f = w_hh[i];
        unsigned short h = f2bf(f);
        whhBh[i] = h;
        whhBl[i] = f2bf(f - bf2f(h));
    } else if (i < 12864) {                 // whoT[c*9+d] = w_ho[d][c]
        int j = i - 12288, c = j / 9, d = j % 9;
        whoT[j] = w_ho[d * 64 + c];
    } else if (i < 123456) {                // BT[oc][tap*64+ic] = w_ih[oc][ic][tap], bf16 split
        int k2 = i - 12864;
        int oc = k2 / 576, kk = k2 % 576, tap = kk >> 6, ic = kk & 63;
        float f = w_ih[(oc * 64 + ic) * 9 + tap];
        unsigned short h = f2bf(f);
        BTh[k2] = h;
        BTl[k2] = f2bf(f - bf2f(h));
    }
}

// ------------------------------------------------------------- x -> channel-last bf16 hi/lo
__global__ __launch_bounds__(256) void transpose_x(const float* __restrict__ x,
                                                   unsigned short* __restrict__ xTh,
                                                   unsigned short* __restrict__ xTl) {
    const int p = blockIdx.x * 256 + threadIdx.x;
    const int b = p >> 14, yx = p & 16383;
    const size_t base = ((size_t)p) << 6;
    for (int ic0 = 0; ic0 < 64; ic0 += 8) {
        ushort8 vh, vl;
#pragma unroll
        for (int j = 0; j < 8; ++j) {
            float f = x[(((size_t)(b * 64 + ic0 + j)) << 14) + yx];
            unsigned short h = f2bf(f);
            vh[j] = h;
            vl[j] = f2bf(f - bf2f(h));
        }
        *(ushort8*)(xTh + base + ic0) = vh;
        *(ushort8*)(xTl + base + ic0) = vl;
    }
}

// ------------------------------------------------------------- conv: implicit GEMM, LDS x-tile
// Block = one image row (128 px), 4 waves; wave w -> 32 px (m=2), all 192 oc (n=12).
// LDS: 3 rows x 130 px x 64 ic, bf16 h/l planes, XOR-swizzled; B read once per block (L2-hot).
__global__ __launch_bounds__(256) void conv_mfma(const unsigned short* __restrict__ xTh,
                                                 const unsigned short* __restrict__ xTl,
                                                 const unsigned short* __restrict__ BTh,
                                                 const unsigned short* __restrict__ BTl,
                                                 const float* __restrict__ b_ih,
                                                 unsigned short* __restrict__ i_all) {
    __shared__ __align__(16) unsigned char smem[99840];   // 2 planes of 3*130*128 B
    const int tid = threadIdx.x;
    const int b = blockIdx.x >> 7, y = blockIdx.x & 127;

    for (int ch = tid; ch < 3120; ch += 256) {            // 3*130*8 chunks of 8 ic
        const int row = ch / 1040;
        const int rem = ch - row * 1040;
        const int pxl = rem >> 3, icc = rem & 7;
        const int gy = y + row - 1, gx = pxl - 1;
        ushort8 vh = {}, vl = {};
        if (gy >= 0 && gy < 128 && gx >= 0 && gx < 128) {
            const size_t go = ((size_t)(b * 16384 + gy * 128 + gx)) * 64 + icc * 8;
            vh = *(const ushort8*)(xTh + go);
            vl = *(const ushort8*)(xTl + go);
        }
        const int off = (((row * 130 + pxl) * 128) + icc * 16) ^ ((pxl & 7) << 4);
        *(ushort8*)(smem + off) = vh;
        *(ushort8*)(smem + 49920 + off) = vl;
    }
    __syncthreads();

    const int lane = tid & 63, wv = tid >> 6;
    const int lrow = lane & 15, lkq = lane >> 4;
    const int px0 = wv * 32;

    f32x4 acc[2][12] = {};
    for (int tap = 0; tap < 9; ++tap) {
        const int row = tap / 3, dx = tap % 3 - 1;
#pragma unroll
        for (int ih = 0; ih < 2; ++ih) {
            bf16x8 Ah[2], Al[2];
#pragma unroll
            for (int m = 0; m < 2; ++m) {
                const int pxl = px0 + m * 16 + lrow + dx + 1;
                const int off = (((row * 130 + pxl) * 128) + ih * 64 + lkq * 16) ^ ((pxl & 7) << 4);
                Ah[m] = *(const bf16x8*)(smem + off);
                Al[m] = *(const bf16x8*)(smem + 49920 + off);
            }
#pragma unroll
            for (int n = 0; n < 12; ++n) {
                const int bo = (n * 16 + lrow) * 576 + tap * 64 + ih * 32 + lkq * 8;
                bf16x8 Bh = *(const bf16x8*)(BTh + bo);
                bf16x8 Bl = *(const bf16x8*)(BTl + bo);
#pragma unroll
                for (int m = 0; m < 2; ++m) {
                    acc[m][n] = __builtin_amdgcn_mfma_f32_16x16x32_bf16(Ah[m], Bh, acc[m][n], 0, 0, 0);
                    acc[m][n] = __builtin_amdgcn_mfma_f32_16x16x32_bf16(Ah[m], Bl, acc[m][n], 0, 0, 0);
                    acc[m][n] = __builtin_amdgcn_mfma_f32_16x16x32_bf16(Al[m], Bh, acc[m][n], 0, 0, 0);
                }
            }
        }
    }

#pragma unroll
    for (int n = 0; n < 12; ++n) {
        const int oc = n * 16 + lrow;
        const float bias = b_ih[oc];
#pragma unroll
        for (int m = 0; m < 2; ++m)
#pragma unroll
            for (int r = 0; r < 4; ++r) {
                const int px = px0 + m * 16 + lkq * 4 + r;
                i_all[((size_t)(b * 16384 + y * 128 + px)) * 192 + oc] = f2bf(acc[m][n][r] + bias);
            }
    }
}

// ------------------------------------------------------------- fused step kernel
// Block = one image row. Phases: 1) merge -> h_t (global + LDS bf16 split)  + prev-step diff loss
// 2) MFMA hh = h_t x w_hh  3) gates -> hy (LDS)  4) hy->global, softmax o, bce partial.
template <bool FIRST>
__global__ __launch_bounds__(256) void step_kernel(const float* __restrict__ hy_prev,
                                                   const float* __restrict__ o_prev,
                                                   const unsigned short* __restrict__ i_all,
                                                   const unsigned short* __restrict__ whhBh,
                                                   const unsigned short* __restrict__ whhBl,
                                                   const float* __restrict__ b_hh,
                                                   const float* __restrict__ whoT,
                                                   const float* __restrict__ b_ho,
                                                   const float* __restrict__ mask,
                                                   float* __restrict__ hidd_out,
                                                   float* __restrict__ hy_cur,
                                                   float* __restrict__ o_out,
                                                   float* __restrict__ loss, int firstloss,
                                                   float* __restrict__ bceP) {
    __shared__ __align__(16) unsigned char smem[67840]; // Ah 16K | Al 16K | hy_lds 34048 | red 1024
    float* hy_lds = (float*)(smem + 32768);
    float* red = (float*)(smem + 66816);

    const int tid = threadIdx.x;
    const int bid = blockIdx.x;
    const int b = bid >> 7, y = bid & 127;

    if constexpr (!FIRST) {
        const int px = tid & 127, chalf = tid >> 7;
        const int yx = y * 128 + px;
        const float* ob = o_prev + (((size_t)b * 9) << 14);
        float onb[9], okf[9];
        int nofs[9];
#pragma unroll
        for (int ey = -1; ey <= 1; ey++)
#pragma unroll
            for (int ex = -1; ex <= 1; ex++) {
                const int idx = (ey + 1) * 3 + (ex + 1);
                int ny = y + ey, nx = px + ex;
                bool ok = (ny >= 0) && (ny < 128) && (nx >= 0) && (nx < 128);
                int cy = min(max(ny, 0), 127), cx = min(max(nx, 0), 127);
                nofs[idx] = cy * 128 + cx;
                okf[idx] = ok ? 1.0f : 0.0f;
                const int j = 3 * (1 - ey) + (1 - ex);
                float v = ob[(((size_t)j) << 14) + nofs[idx]];
                onb[idx] = ok ? v : 0.0f;
            }
        const size_t hb = ((size_t)b) << 20;
        for (int q = 0; q < 4; ++q) {
            ushort8 vh, vl;
#pragma unroll
            for (int j = 0; j < 8; ++j) {
                const int c = chalf * 32 + q * 8 + j;
                const float* hc = hy_prev + hb + (((size_t)c) << 14);
                float a = 0.0f;
#pragma unroll
                for (int idx = 0; idx < 9; ++idx) a = fmaf(hc[nofs[idx]], onb[idx], a);
                hidd_out[hb + (((size_t)c) << 14) + yx] = a;
                unsigned short hh_ = f2bf(a);
                vh[j] = hh_;
                vl[j] = f2bf(a - bf2f(hh_));
            }
            const int off = (px * 128 + chalf * 64 + q * 16) ^ ((px & 7) << 4);
            *(ushort8*)(smem + off) = vh;
            *(ushort8*)(smem + 16384 + off) = vl;
        }
        if (chalf == 0) {   // diff loss for prev step's o
            const float* o4p = ob + (((size_t)4) << 14);
#pragma unroll
            for (int i = 0; i < 9; ++i) {
                float g = okf[i] * o4p[nofs[i]];
                float oi = ob[(((size_t)i) << 14) + yx];
                float d = g - oi;
                float dv = d * d * oi * 0.01f;
                const size_t li = (((size_t)(b * 9 + i)) << 14) + yx;
                if (firstloss) loss[li] = dv;
                else           loss[li] += dv;
            }
        }
        __syncthreads();
    }

    const int lane = tid & 63, wv = tid >> 6;
    const int lrow = lane & 15, lkq = lane >> 4;

    f32x4 acc[2][12] = {};
    if constexpr (!FIRST) {
        bf16x8 Ah[2][2], Al[2][2];
#pragma unroll
        for (int m = 0; m < 2; ++m)
#pragma unroll
            for (int ih = 0; ih < 2; ++ih) {
                const int pxa = wv * 32 + m * 16 + lrow;
                const int off = (pxa * 128 + ih * 64 + lkq * 16) ^ ((pxa & 7) << 4);
                Ah[m][ih] = *(const bf16x8*)(smem + off);
                Al[m][ih] = *(const bf16x8*)(smem + 16384 + off);
            }
#pragma unroll
        for (int n = 0; n < 12; ++n)
#pragma unroll
            for (int ih = 0; ih < 2; ++ih) {
                const int bo = (n * 16 + lrow) * 64 + ih * 32 + lkq * 8;
                bf16x8 Bh = *(const bf16x8*)(whhBh + bo);
                bf16x8 Bl = *(const bf16x8*)(whhBl + bo);
#pragma unroll
                for (int m = 0; m < 2; ++m) {
                    acc[m][n] = __builtin_amdgcn_mfma_f32_16x16x32_bf16(Ah[m][ih], Bh, acc[m][n], 0, 0, 0);
                    acc[m][n] = __builtin_amdgcn_mfma_f32_16x16x32_bf16(Ah[m][ih], Bl, acc[m][n], 0, 0, 0);
                    acc[m][n] = __builtin_amdgcn_mfma_f32_16x16x32_bf16(Al[m][ih], Bh, acc[m][n], 0, 0, 0);
                }
            }
    }

    // phase 3: gates
    float bhr[4], bhi[4], bhn[4];
#pragma unroll
    for (int nf = 0; nf < 4; ++nf) {
        bhr[nf] = b_hh[nf * 16 + lrow];
        bhi[nf] = b_hh[64 + nf * 16 + lrow];
        bhn[nf] = b_hh[128 + nf * 16 + lrow];
    }
#pragma unroll
    for (int m = 0; m < 2; ++m)
#pragma unroll
        for (int rr = 0; rr < 4; ++rr) {
            const int px = wv * 32 + m * 16 + lkq * 4 + rr;
            const unsigned short* ia = i_all + ((size_t)(b * 16384 + y * 128 + px)) * 192;
#pragma unroll
            for (int nf = 0; nf < 4; ++nf) {
                const int g = nf * 16 + lrow;
                float hr = bhr[nf], hig = bhi[nf], hn = bhn[nf];
                if constexpr (!FIRST) {
                    hr += acc[m][nf][rr];
                    hig += acc[m][nf + 4][rr];
                    hn += acc[m][nf + 8][rr];
                }
                float ir = bf2f(ia[g]), ii = bf2f(ia[64 + g]), inn = bf2f(ia[128 + g]);
                float rg = frcp(1.0f + __expf(-(ir + hr)));
                float ig = frcp(1.0f + __expf(-(ii + hig)));
                float t2 = __expf(2.0f * (inn + rg * hn));
                float nn = 1.0f - 2.0f * frcp(t2 + 1.0f);
                float hp = 0.0f;
                if constexpr (!FIRST) {
                    const int off = (px * 128 + g * 2) ^ ((px & 7) << 4);
                    hp = bf2f(*(const unsigned short*)(smem + off)) +
                         bf2f(*(const unsigned short*)(smem + 16384 + off));
                }
                hy_lds[g * 133 + px] = nn + ig * (hp - nn);
            }
        }
    __syncthreads();

    // phase 4a: hy -> global (coalesced)
#pragma unroll
    for (int i = 0; i < 32; ++i) {
        const int idx = tid + i * 256;
        const int c = idx >> 7, px2 = idx & 127;
        hy_cur[(((size_t)b) << 20) + (((size_t)c) << 14) + y * 128 + px2] = hy_lds[c * 133 + px2];
    }
    // phase 4b: softmax + o + bce
    float v = 0.0f;
    if (tid < 128) {
        const int px = tid;
        float olog[9];
#pragma unroll
        for (int d = 0; d < 9; ++d) olog[d] = b_ho[d];
        for (int c = 0; c < 64; ++c) {
            const float h = hy_lds[c * 133 + px];
            const float* w = whoT + c * 9;
#pragma unroll
            for (int d = 0; d < 9; ++d) olog[d] = fmaf(h, w[d], olog[d]);
        }
        float mx = olog[0];
#pragma unroll
        for (int d = 1; d < 9; ++d) mx = fmaxf(mx, olog[d]);
        float e[9], s = 0.0f;
#pragma unroll
        for (int d = 0; d < 9; ++d) { e[d] = __expf(olog[d] - mx); s += e[d]; }
        float inv = frcp(s);
        const int yx = y * 128 + px;
#pragma unroll
        for (int d = 0; d < 9; ++d) o_out[(((size_t)(b * 9 + d)) << 14) + yx] = e[d] * inv;
        float o4 = e[4] * inv;
        float mk = mask[(((size_t)b) << 14) + yx];
        v = mk * __logf(1.0f - o4) + (1.0f - mk) * __logf(o4);
    }
    red[tid] = v;
    __syncthreads();
    for (int off = 128; off > 0; off >>= 1) {
        if (tid < off) red[tid] += red[tid + off];
        __syncthreads();
    }
    if (tid == 0) bceP[bid] = red[0];
}

// ------------------------------------------------------------- final merge (h_8) + last loss + bce
__global__ __launch_bounds__(256) void final_merge(const float* __restrict__ hy_prev,
                                                   const float* __restrict__ o_prev,
                                                   float* __restrict__ hidd_out,
                                                   float* __restrict__ loss,
                                                   const float* __restrict__ bceT) {
    const int tid = threadIdx.x;
    const int bid = blockIdx.x;
    const int b = bid >> 7, y = bid & 127;
    const int px = tid & 127, chalf = tid >> 7;
    const int yx = y * 128 + px;
    const float* ob = o_prev + (((size_t)b * 9) << 14);
    float onb[9], okf[9];
    int nofs[9];
#pragma unroll
    for (int ey = -1; ey <= 1; ey++)
#pragma unroll
        for (int ex = -1; ex <= 1; ex++) {
            const int idx = (ey + 1) * 3 + (ex + 1);
            int ny = y + ey, nx = px + ex;
            bool ok = (ny >= 0) && (ny < 128) && (nx >= 0) && (nx < 128);
            int cy = min(max(ny, 0), 127), cx = min(max(nx, 0), 127);
            nofs[idx] = cy * 128 + cx;
            okf[idx] = ok ? 1.0f : 0.0f;
            const int j = 3 * (1 - ey) + (1 - ex);
            float v = ob[(((size_t)j) << 14) + nofs[idx]];
            onb[idx] = ok ? v : 0.0f;
        }
    const size_t hb = ((size_t)b) << 20;
    for (int cc = 0; cc < 32; ++cc) {
        const int c = chalf * 32 + cc;
        const float* hc = hy_prev + hb + (((size_t)c) << 14);
        float a = 0.0f;
#pragma unroll
        for (int idx = 0; idx < 9; ++idx) a = fmaf(hc[nofs[idx]], onb[idx], a);
        hidd_out[hb + (((size_t)c) << 14) + yx] = a;
    }
    if (chalf == 0) {
        const float bt = *bceT;
        const float* o4p = ob + (((size_t)4) << 14);
#pragma unroll
        for (int i = 0; i < 9; ++i) {
            float g = okf[i] * o4p[nofs[i]];
            float oi = ob[(((size_t)i) << 14) + yx];
            float d = g - oi;
            float dv = d * d * oi * 0.01f;
            const size_t li = (((size_t)(b * 9 + i)) << 14) + yx;
            loss[li] += dv + bt;
        }
    }
}

// ------------------------------------------------------------- bce reduce (4096 partials)
__global__ void bce_reduce_kernel(const float* __restrict__ partial, float* __restrict__ out_tot) {
    __shared__ float red[256];
    float s = 0.0f;
    for (int i = threadIdx.x; i < 4096; i += 256) s += partial[i];
    red[threadIdx.x] = s;
    __syncthreads();
    for (int off = 128; off > 0; off >>= 1) {
        if (threadIdx.x < off) red[threadIdx.x] += red[threadIdx.x + off];
        __syncthreads();
    }
    if (threadIdx.x == 0) *out_tot = -red[0] * (1.0f / 65536.0f);
}

// ------------------------------------------------------------- launcher
extern "C" void kernel_launch(void* const* d_in, const int* in_sizes, int n_in,
                              void* d_out, int out_size, void* d_ws, size_t ws_size,
                              hipStream_t stream) {
    const float* x    = (const float*)d_in[0];
    const float* mask = (const float*)d_in[1];
    const float* w_ih = (const float*)d_in[2];
    const float* b_ih = (const float*)d_in[3];
    const float* w_hh = (const float*)d_in[4];
    const float* b_hh = (const float*)d_in[5];
    const float* w_ho = (const float*)d_in[6];
    const float* b_ho = (const float*)d_in[7];
    float* out = (float*)d_out;
    float* ws  = (float*)d_ws;

    unsigned short* i_all = (unsigned short*)(ws + WS_IALL);
    unsigned short* xTh = (unsigned short*)(ws + WS_XT);
    unsigned short* xTl = xTh + 4194304;
    float* hyA = ws + WS_HYA;
    float* hyB = ws + WS_HYB;
    unsigned short* whhBh = (unsigned short*)(ws + WS_WHHBH);
    unsigned short* whhBl = (unsigned short*)(ws + WS_WHHBL);
    float* whoT = ws + WS_WHOT;
    unsigned short* BTh = (unsigned short*)(ws + WS_BTH);
    unsigned short* BTl = (unsigned short*)(ws + WS_BTL);
    float* bceP = ws + WS_BCEP;
    float* bceT = ws + WS_BCET;
    float* lossp = out + LOSS_OFF;

    prep_weights<<<483, 256, 0, stream>>>(w_hh, w_ho, w_ih, whhBh, whhBl, whoT, BTh, BTl);
    transpose_x<<<256, 256, 0, stream>>>(x, xTh, xTl);
    conv_mfma<<<512, 256, 0, stream>>>(xTh, xTl, BTh, BTl, b_ih, i_all);

    step_kernel<true><<<512, 256, 0, stream>>>(nullptr, nullptr, i_all, whhBh, whhBl,
                                               b_hh, whoT, b_ho, mask,
                                               nullptr, hyA, out + OUTS_OFF, lossp, 0, bceP);
    for (int t = 1; t < 8; ++t) {
        const float* hyp = (t & 1) ? hyA : hyB;
        float* hyc = (t & 1) ? hyB : hyA;
        step_kernel<false><<<512, 256, 0, stream>>>(hyp, out + OUTS_OFF + (size_t)(t - 1) * O_SZ,
                                                    i_all, whhBh, whhBl, b_hh, whoT, b_ho, mask,
                                                    out + (size_t)(t - 1) * HID_SZ, hyc,
                                                    out + OUTS_OFF + (size_t)t * O_SZ, lossp,
                                                    (t == 1) ? 1 : 0, bceP + t * 512);
    }
    bce_reduce_kernel<<<1, 256, 0, stream>>>(bceP, bceT);
    final_merge<<<512, 256, 0, stream>>>(hyB, out + OUTS_OFF + (size_t)7 * O_SZ,
                                         out + (size_t)7 * HID_SZ, lossp, bceT);
}

// Round 5
// 427.080 us; speedup vs baseline: 2.2208x; 1.4600x over previous
//
#include <hip/hip_runtime.h>

// B=4, C_IN=64, NUM_HIDDEN=64, H=W=128, MOVESQ=9, T=8
#define NP 16384
#define HID_SZ 4194304      // 4*64*NP
#define O_SZ   589824       // 4*9*NP
#define OUTS_OFF 33554432   // 8*HID_SZ
#define LOSS_OFF 38273024   // OUTS_OFF + 8*O_SZ

// ws layout (float units), total ~67.4 MB
#define WS_IALLP 0          // 8,388,608 floats = 16,777,216 ushorts: i_all permuted bf16
                            //   row stride 32768 ushorts per (b,y): 32 slots x 1024
#define WS_HYA   8388608    // 4,194,304 floats (xTh overlaps here during conv)
#define WS_HYB   12582912   // 4,194,304 floats
#define WS_WHH   16777216   // 6144 floats = 12,288 ushorts (w_hh bf16, native layout)
#define WS_WHOT  16783360   // 576 floats
#define WS_BTH   16783936   // 55,296 floats = 110,592 ushorts
#define WS_BCEP  16839232   // 4096 floats
#define WS_BCET  16843328   // 1 float

typedef __attribute__((ext_vector_type(8))) short bf16x8;
typedef __attribute__((ext_vector_type(8))) unsigned short ushort8;
typedef __attribute__((ext_vector_type(4))) float f32x4;

__device__ __forceinline__ float frcp(float x) { return __builtin_amdgcn_rcpf(x); }
__device__ __forceinline__ unsigned short f2bf(float f) {
    unsigned int u = __float_as_uint(f);
    return (unsigned short)((u + 0x7fffu + ((u >> 16) & 1u)) >> 16);
}
__device__ __forceinline__ float bf2f(unsigned short h) {
    return __uint_as_float(((unsigned int)h) << 16);
}

// ------------------------------------------------------------- weight prep
__global__ void prep_weights(const float* __restrict__ w_hh, const float* __restrict__ w_ho,
                             const float* __restrict__ w_ih,
                             unsigned short* __restrict__ whhB, float* __restrict__ whoT,
                             unsigned short* __restrict__ BTh) {
    int i = blockIdx.x * 256 + threadIdx.x;
    if (i < 12288) {                        // w_hh [192][64] -> bf16 (B-frag native layout)
        whhB[i] = f2bf(w_hh[i]);
    } else if (i < 12864) {                 // whoT[c*9+d] = w_ho[d][c]
        int j = i - 12288, c = j / 9, d = j % 9;
        whoT[j] = w_ho[d * 64 + c];
    } else if (i < 123456) {                // BT[oc][tap*64+ic] = w_ih[oc][ic][tap] bf16
        int k2 = i - 12864;
        int oc = k2 / 576, kk = k2 % 576, tap = kk >> 6, ic = kk & 63;
        BTh[k2] = f2bf(w_ih[(oc * 64 + ic) * 9 + tap]);
    }
}

// ------------------------------------------------------------- x -> channel-last bf16
__global__ __launch_bounds__(256) void transpose_x(const float* __restrict__ x,
                                                   unsigned short* __restrict__ xTh) {
    const int p = blockIdx.x * 256 + threadIdx.x;
    const int b = p >> 14, yx = p & 16383;
    const size_t base = ((size_t)p) << 6;
    for (int ic0 = 0; ic0 < 64; ic0 += 8) {
        ushort8 vh;
#pragma unroll
        for (int j = 0; j < 8; ++j)
            vh[j] = f2bf(x[(((size_t)(b * 64 + ic0 + j)) << 14) + yx]);
        *(ushort8*)(xTh + base + ic0) = vh;
    }
}

// ------------------------------------------------------------- conv: implicit GEMM (bf16)
// Block = one image row, 4 waves x 32 px; LDS x-tile 3x130x64 bf16 (50 KB).
// Epilogue writes i_all in PERMUTED fragment order, row stride 32768 ushorts:
//   [(b,y)<<15] + [(wv*8 + m*4 + r)<<10] + lane*16 ; slot n holds gate fragment n.
__global__ __launch_bounds__(256) void conv_mfma(const unsigned short* __restrict__ xTh,
                                                 const unsigned short* __restrict__ BTh,
                                                 const float* __restrict__ b_ih,
                                                 unsigned short* __restrict__ iallp) {
    __shared__ __align__(16) unsigned char smem[49920];
    const int tid = threadIdx.x;
    const int b = blockIdx.x >> 7, y = blockIdx.x & 127;

    for (int ch = tid; ch < 3120; ch += 256) {
        const int row = ch / 1040;
        const int rem = ch - row * 1040;
        const int pxl = rem >> 3, icc = rem & 7;
        const int gy = y + row - 1, gx = pxl - 1;
        ushort8 vh = {};
        if (gy >= 0 && gy < 128 && gx >= 0 && gx < 128) {
            const size_t go = ((size_t)(b * 16384 + gy * 128 + gx)) * 64 + icc * 8;
            vh = *(const ushort8*)(xTh + go);
        }
        const int off = (((row * 130 + pxl) * 128) + icc * 16) ^ ((pxl & 7) << 4);
        *(ushort8*)(smem + off) = vh;
    }
    __syncthreads();

    const int lane = tid & 63, wv = tid >> 6;
    const int lrow = lane & 15, lkq = lane >> 4;
    const int px0 = wv * 32;

    f32x4 acc[2][12] = {};
    for (int tap = 0; tap < 9; ++tap) {
        const int row = tap / 3, dx = tap % 3 - 1;
#pragma unroll
        for (int ih = 0; ih < 2; ++ih) {
            bf16x8 Ah[2];
#pragma unroll
            for (int m = 0; m < 2; ++m) {
                const int pxl = px0 + m * 16 + lrow + dx + 1;
                const int off = (((row * 130 + pxl) * 128) + ih * 64 + lkq * 16) ^ ((pxl & 7) << 4);
                Ah[m] = *(const bf16x8*)(smem + off);
            }
#pragma unroll
            for (int n = 0; n < 12; ++n) {
                const int bo = (n * 16 + lrow) * 576 + tap * 64 + ih * 32 + lkq * 8;
                bf16x8 Bh = *(const bf16x8*)(BTh + bo);
#pragma unroll
                for (int m = 0; m < 2; ++m)
                    acc[m][n] = __builtin_amdgcn_mfma_f32_16x16x32_bf16(Ah[m], Bh, acc[m][n], 0, 0, 0);
            }
        }
    }

    float bias[12];
#pragma unroll
    for (int n = 0; n < 12; ++n) bias[n] = b_ih[n * 16 + lrow];
    const size_t bb = ((size_t)(b * 128 + y)) << 15;   // FIXED: 32768-ushort row stride
#pragma unroll
    for (int m = 0; m < 2; ++m)
#pragma unroll
        for (int r = 0; r < 4; ++r) {
            ushort8 v0, v1;
#pragma unroll
            for (int n = 0; n < 8; ++n) v0[n] = f2bf(acc[m][n][r] + bias[n]);
#pragma unroll
            for (int n = 8; n < 12; ++n) v1[n - 8] = f2bf(acc[m][n][r] + bias[n]);
            v1[4] = 0; v1[5] = 0; v1[6] = 0; v1[7] = 0;
            const size_t o = bb + (size_t)((((wv * 2 + m) * 4 + r) << 10) + lane * 16);
            *(ushort8*)(iallp + o) = v0;
            *(ushort8*)(iallp + o + 8) = v1;
        }
}

// ------------------------------------------------------------- fused step kernel
// Block = one image row. ph1 merge -> h_t (global f32 + A_lds bf16) + prev diff-loss
// ph2 MFMA hh  ph3 gates (vector i_all_perm reads) -> hy_lds bf16  ph4 hy->global, softmax, bce.
template <bool FIRST>
__global__ __launch_bounds__(256) void step_kernel(const float* __restrict__ hy_prev,
                                                   const float* __restrict__ o_prev,
                                                   const unsigned short* __restrict__ iallp,
                                                   const unsigned short* __restrict__ whhB,
                                                   const float* __restrict__ b_hh,
                                                   const float* __restrict__ whoT,
                                                   const float* __restrict__ b_ho,
                                                   const float* __restrict__ mask,
                                                   float* __restrict__ hidd_out,
                                                   float* __restrict__ hy_cur,
                                                   float* __restrict__ o_out,
                                                   float* __restrict__ loss, int firstloss,
                                                   float* __restrict__ bceP) {
    __shared__ __align__(16) unsigned char smem[34304];
    // [0,16384): A_lds bf16 h_t swizzled | [16384,33280): hy_lds bf16 [64][132] | [33280,+1K): red
    unsigned short* hy_lds = (unsigned short*)(smem + 16384);
    float* red = (float*)(smem + 33280);

    const int tid = threadIdx.x;
    const int bid = blockIdx.x;
    const int b = bid >> 7, y = bid & 127;

    if constexpr (!FIRST) {
        const int px = tid & 127, chalf = tid >> 7;
        const int yx = y * 128 + px;
        const float* ob = o_prev + (((size_t)b * 9) << 14);
        float onb[9], okf[9];
        int nofs[9];
#pragma unroll
        for (int ey = -1; ey <= 1; ey++)
#pragma unroll
            for (int ex = -1; ex <= 1; ex++) {
                const int idx = (ey + 1) * 3 + (ex + 1);
                int ny = y + ey, nx = px + ex;
                bool ok = (ny >= 0) && (ny < 128) && (nx >= 0) && (nx < 128);
                int cy = min(max(ny, 0), 127), cx = min(max(nx, 0), 127);
                nofs[idx] = cy * 128 + cx;
                okf[idx] = ok ? 1.0f : 0.0f;
                const int j = 3 * (1 - ey) + (1 - ex);
                float v = ob[(((size_t)j) << 14) + nofs[idx]];
                onb[idx] = ok ? v : 0.0f;
            }
        const size_t hb = ((size_t)b) << 20;
        for (int q = 0; q < 4; ++q) {
            ushort8 vh;
#pragma unroll
            for (int j = 0; j < 8; ++j) {
                const int c = chalf * 32 + q * 8 + j;
                const float* hc = hy_prev + hb + (((size_t)c) << 14);
                float a = 0.0f;
#pragma unroll
                for (int idx = 0; idx < 9; ++idx) a = fmaf(hc[nofs[idx]], onb[idx], a);
                hidd_out[hb + (((size_t)c) << 14) + yx] = a;
                vh[j] = f2bf(a);
            }
            const int off = (px * 128 + chalf * 64 + q * 16) ^ ((px & 7) << 4);
            *(ushort8*)(smem + off) = vh;
        }
        if (chalf == 0) {
            const float* o4p = ob + (((size_t)4) << 14);
#pragma unroll
            for (int i = 0; i < 9; ++i) {
                float g = okf[i] * o4p[nofs[i]];
                float oi = ob[(((size_t)i) << 14) + yx];
                float d = g - oi;
                float dv = d * d * oi * 0.01f;
                const size_t li = (((size_t)(b * 9 + i)) << 14) + yx;
                if (firstloss) loss[li] = dv;
                else           loss[li] += dv;
            }
        }
        __syncthreads();
    }

    const int lane = tid & 63, wv = tid >> 6;
    const int lrow = lane & 15, lkq = lane >> 4;

    f32x4 acc[2][12] = {};
    if constexpr (!FIRST) {
        bf16x8 Ah[2][2];
#pragma unroll
        for (int m = 0; m < 2; ++m)
#pragma unroll
            for (int ih = 0; ih < 2; ++ih) {
                const int pxa = wv * 32 + m * 16 + lrow;
                const int off = (pxa * 128 + ih * 64 + lkq * 16) ^ ((pxa & 7) << 4);
                Ah[m][ih] = *(const bf16x8*)(smem + off);
            }
#pragma unroll
        for (int n = 0; n < 12; ++n)
#pragma unroll
            for (int ih = 0; ih < 2; ++ih) {
                const int bo = (n * 16 + lrow) * 64 + ih * 32 + lkq * 8;
                bf16x8 Bh = *(const bf16x8*)(whhB + bo);
#pragma unroll
                for (int m = 0; m < 2; ++m)
                    acc[m][n] = __builtin_amdgcn_mfma_f32_16x16x32_bf16(Ah[m][ih], Bh, acc[m][n], 0, 0, 0);
            }
    }

    // ph3: gates (vectorized permuted i_all reads)
    float bhr[4], bhi[4], bhn[4];
#pragma unroll
    for (int nf = 0; nf < 4; ++nf) {
        bhr[nf] = b_hh[nf * 16 + lrow];
        bhi[nf] = b_hh[64 + nf * 16 + lrow];
        bhn[nf] = b_hh[128 + nf * 16 + lrow];
    }
    const size_t ibase = (((size_t)(b * 128 + y)) << 15) + (size_t)(wv << 13);  // FIXED stride
#pragma unroll
    for (int m = 0; m < 2; ++m)
#pragma unroll
        for (int rr = 0; rr < 4; ++rr) {
            const int px = wv * 32 + m * 16 + lkq * 4 + rr;
            const size_t o = ibase + (size_t)(((m * 4 + rr) << 10) + lane * 16);
            ushort8 lo = *(const ushort8*)(iallp + o);
            ushort8 hi = *(const ushort8*)(iallp + o + 8);
#pragma unroll
            for (int nf = 0; nf < 4; ++nf) {
                const int g = nf * 16 + lrow;
                float hr = bhr[nf], hig = bhi[nf], hn = bhn[nf];
                if constexpr (!FIRST) {
                    hr += acc[m][nf][rr];
                    hig += acc[m][nf + 4][rr];
                    hn += acc[m][nf + 8][rr];
                }
                float ir = bf2f(lo[nf]), ii = bf2f(lo[4 + nf]), inn = bf2f(hi[nf]);
                float rg = frcp(1.0f + __expf(-(ir + hr)));
                float ig = frcp(1.0f + __expf(-(ii + hig)));
                float t2 = __expf(2.0f * (inn + rg * hn));
                float nn = 1.0f - 2.0f * frcp(t2 + 1.0f);
                float hp = 0.0f;
                if constexpr (!FIRST) {
                    const int offA = (px * 128 + g * 2) ^ ((px & 7) << 4);
                    hp = bf2f(*(const unsigned short*)(smem + offA));
                }
                hy_lds[g * 132 + px] = f2bf(nn + ig * (hp - nn));
            }
        }
    __syncthreads();

    // ph4a: hy -> global f32 (coalesced)
#pragma unroll
    for (int i = 0; i < 32; ++i) {
        const int idx = tid + i * 256;
        const int c = idx >> 7, px2 = idx & 127;
        hy_cur[(((size_t)b) << 20) + (((size_t)c) << 14) + y * 128 + px2] = bf2f(hy_lds[c * 132 + px2]);
    }
    // ph4b: softmax + o + bce
    float v = 0.0f;
    if (tid < 128) {
        const int px = tid;
        float olog[9];
#pragma unroll
        for (int d = 0; d < 9; ++d) olog[d] = b_ho[d];
        for (int c = 0; c < 64; ++c) {
            const float h = bf2f(hy_lds[c * 132 + px]);
            const float* w = whoT + c * 9;
#pragma unroll
            for (int d = 0; d < 9; ++d) olog[d] = fmaf(h, w[d], olog[d]);
        }
        float mx = olog[0];
#pragma unroll
        for (int d = 1; d < 9; ++d) mx = fmaxf(mx, olog[d]);
        float e[9], s = 0.0f;
#pragma unroll
        for (int d = 0; d < 9; ++d) { e[d] = __expf(olog[d] - mx); s += e[d]; }
        float inv = frcp(s);
        const int yx = y * 128 + px;
#pragma unroll
        for (int d = 0; d < 9; ++d) o_out[(((size_t)(b * 9 + d)) << 14) + yx] = e[d] * inv;
        float o4 = e[4] * inv;
        float mk = mask[(((size_t)b) << 14) + yx];
        v = mk * __logf(1.0f - o4) + (1.0f - mk) * __logf(o4);
    }
    red[tid] = v;
    __syncthreads();
    for (int off = 128; off > 0; off >>= 1) {
        if (tid < off) red[tid] += red[tid + off];
        __syncthreads();
    }
    if (tid == 0) bceP[bid] = red[0];
}

// ------------------------------------------------------------- final merge (h_8) + last loss + bce
__global__ __launch_bounds__(256) void final_merge(const float* __restrict__ hy_prev,
                                                   const float* __restrict__ o_prev,
                                                   float* __restrict__ hidd_out,
                                                   float* __restrict__ loss,
                                                   const float* __restrict__ bceT) {
    const int tid = threadIdx.x;
    const int bid = blockIdx.x;
    const int b = bid >> 7, y = bid & 127;
    const int px = tid & 127, chalf = tid >> 7;
    const int yx = y * 128 + px;
    const float* ob = o_prev + (((size_t)b * 9) << 14);
    float onb[9], okf[9];
    int nofs[9];
#pragma unroll
    for (int ey = -1; ey <= 1; ey++)
#pragma unroll
        for (int ex = -1; ex <= 1; ex++) {
            const int idx = (ey + 1) * 3 + (ex + 1);
            int ny = y + ey, nx = px + ex;
            bool ok = (ny >= 0) && (ny < 128) && (nx >= 0) && (nx < 128);
            int cy = min(max(ny, 0), 127), cx = min(max(nx, 0), 127);
            nofs[idx] = cy * 128 + cx;
            okf[idx] = ok ? 1.0f : 0.0f;
            const int j = 3 * (1 - ey) + (1 - ex);
            float v = ob[(((size_t)j) << 14) + nofs[idx]];
            onb[idx] = ok ? v : 0.0f;
        }
    const size_t hb = ((size_t)b) << 20;
    for (int cc = 0; cc < 32; ++cc) {
        const int c = chalf * 32 + cc;
        const float* hc = hy_prev + hb + (((size_t)c) << 14);
        float a = 0.0f;
#pragma unroll
        for (int idx = 0; idx < 9; ++idx) a = fmaf(hc[nofs[idx]], onb[idx], a);
        hidd_out[hb + (((size_t)c) << 14) + yx] = a;
    }
    if (chalf == 0) {
        const float bt = *bceT;
        const float* o4p = ob + (((size_t)4) << 14);
#pragma unroll
        for (int i = 0; i < 9; ++i) {
            float g = okf[i] * o4p[nofs[i]];
            float oi = ob[(((size_t)i) << 14) + yx];
            float d = g - oi;
            float dv = d * d * oi * 0.01f;
            const size_t li = (((size_t)(b * 9 + i)) << 14) + yx;
            loss[li] += dv + bt;
        }
    }
}

// ------------------------------------------------------------- bce reduce (4096 partials)
__global__ void bce_reduce_kernel(const float* __restrict__ partial, float* __restrict__ out_tot) {
    __shared__ float red[256];
    float s = 0.0f;
    for (int i = threadIdx.x; i < 4096; i += 256) s += partial[i];
    red[threadIdx.x] = s;
    __syncthreads();
    for (int off = 128; off > 0; off >>= 1) {
        if (threadIdx.x < off) red[threadIdx.x] += red[threadIdx.x + off];
        __syncthreads();
    }
    if (threadIdx.x == 0) *out_tot = -red[0] * (1.0f / 65536.0f);
}

// ------------------------------------------------------------- launcher
extern "C" void kernel_launch(void* const* d_in, const int* in_sizes, int n_in,
                              void* d_out, int out_size, void* d_ws, size_t ws_size,
                              hipStream_t stream) {
    const float* x    = (const float*)d_in[0];
    const float* mask = (const float*)d_in[1];
    const float* w_ih = (const float*)d_in[2];
    const float* b_ih = (const float*)d_in[3];
    const float* w_hh = (const float*)d_in[4];
    const float* b_hh = (const float*)d_in[5];
    const float* w_ho = (const float*)d_in[6];
    const float* b_ho = (const float*)d_in[7];
    float* out = (float*)d_out;
    float* ws  = (float*)d_ws;

    unsigned short* iallp = (unsigned short*)(ws + WS_IALLP);
    unsigned short* xTh = (unsigned short*)(ws + WS_HYA);   // conv-time only
    float* hyA = ws + WS_HYA;
    float* hyB = ws + WS_HYB;
    unsigned short* whhB = (unsigned short*)(ws + WS_WHH);
    float* whoT = ws + WS_WHOT;
    unsigned short* BTh = (unsigned short*)(ws + WS_BTH);
    float* bceP = ws + WS_BCEP;
    float* bceT = ws + WS_BCET;
    float* lossp = out + LOSS_OFF;

    prep_weights<<<483, 256, 0, stream>>>(w_hh, w_ho, w_ih, whhB, whoT, BTh);
    transpose_x<<<256, 256, 0, stream>>>(x, xTh);
    conv_mfma<<<512, 256, 0, stream>>>(xTh, BTh, b_ih, iallp);

    step_kernel<true><<<512, 256, 0, stream>>>(nullptr, nullptr, iallp, whhB,
                                               b_hh, whoT, b_ho, mask,
                                               nullptr, hyA, out + OUTS_OFF, lossp, 0, bceP);
    for (int t = 1; t < 8; ++t) {
        const float* hyp = (t & 1) ? hyA : hyB;
        float* hyc = (t & 1) ? hyB : hyA;
        step_kernel<false><<<512, 256, 0, stream>>>(hyp, out + OUTS_OFF + (size_t)(t - 1) * O_SZ,
                                                    iallp, whhB, b_hh, whoT, b_ho, mask,
                                                    out + (size_t)(t - 1) * HID_SZ, hyc,
                                                    out + OUTS_OFF + (size_t)t * O_SZ, lossp,
                                                    (t == 1) ? 1 : 0, bceP + t * 512);
    }
    bce_reduce_kernel<<<1, 256, 0, stream>>>(bceP, bceT);
    final_merge<<<512, 256, 0, stream>>>(hyB, out + OUTS_OFF + (size_t)7 * O_SZ,
                                         out + (size_t)7 * HID_SZ, lossp, bceT);
}

// Round 6
// 373.662 us; speedup vs baseline: 2.5383x; 1.1430x over previous
//
#include <hip/hip_runtime.h>

// B=4, C_IN=64, NUM_HIDDEN=64, H=W=128, MOVESQ=9, T=8
#define NP 16384
#define HID_SZ 4194304      // 4*64*NP
#define O_SZ   589824       // 4*9*NP
#define OUTS_OFF 33554432   // 8*HID_SZ
#define LOSS_OFF 38273024   // OUTS_OFF + 8*O_SZ

// ws layout (float units), ~50.6 MB
#define WS_IALLP 0          // 8,388,608 floats = 16,777,216 ushorts (1024 half-rows x 16384)
#define WS_HYA   8388608    // 2,097,152 floats = 4,194,304 ushorts (hy bf16) ; xTh overlaps (conv-time)
#define WS_HYB   10485760   // 2,097,152 floats
#define WS_WHH   12582912   // 6144 floats = 12,288 ushorts (w_hh bf16)
#define WS_WHOB  12589056   // 512 floats = 1024 ushorts (w_ho bf16, d-major 16x64, pad d>=9)
#define WS_BTH   12589568   // 55,296 floats = 110,592 ushorts
#define WS_BCEP  12644864   // 8192 floats
#define WS_BCET  12653056   // 1 float

typedef __attribute__((ext_vector_type(8))) short bf16x8;
typedef __attribute__((ext_vector_type(8))) unsigned short ushort8;
typedef __attribute__((ext_vector_type(4))) float f32x4;

__device__ __forceinline__ float frcp(float x) { return __builtin_amdgcn_rcpf(x); }
__device__ __forceinline__ unsigned short f2bf(float f) {
    unsigned int u = __float_as_uint(f);
    return (unsigned short)((u + 0x7fffu + ((u >> 16) & 1u)) >> 16);
}
__device__ __forceinline__ float bf2f(unsigned short h) {
    return __uint_as_float(((unsigned int)h) << 16);
}

// ------------------------------------------------------------- weight prep
__global__ void prep_weights(const float* __restrict__ w_hh, const float* __restrict__ w_ho,
                             const float* __restrict__ w_ih,
                             unsigned short* __restrict__ whhB, unsigned short* __restrict__ whoB,
                             unsigned short* __restrict__ BTh) {
    int i = blockIdx.x * 256 + threadIdx.x;
    if (i < 12288) {                        // w_hh [192][64] -> bf16 (B-frag native layout)
        whhB[i] = f2bf(w_hh[i]);
    } else if (i < 13312) {                 // whoB[d*64+c], d<16 (pad d>=9 with 0)
        int j = i - 12288, d = j >> 6, c = j & 63;
        whoB[j] = (d < 9) ? f2bf(w_ho[d * 64 + c]) : (unsigned short)0;
    } else if (i < 13312 + 110592) {        // BT[oc][tap*64+ic] = w_ih[oc][ic][tap] bf16
        int k2 = i - 13312;
        int oc = k2 / 576, kk = k2 % 576, tap = kk >> 6, ic = kk & 63;
        BTh[k2] = f2bf(w_ih[(oc * 64 + ic) * 9 + tap]);
    }
}

// ------------------------------------------------------------- x -> channel-last bf16
__global__ __launch_bounds__(256) void transpose_x(const float* __restrict__ x,
                                                   unsigned short* __restrict__ xTh) {
    const int p = blockIdx.x * 256 + threadIdx.x;
    const int b = p >> 14, yx = p & 16383;
    const size_t base = ((size_t)p) << 6;
    for (int ic0 = 0; ic0 < 64; ic0 += 8) {
        ushort8 vh;
#pragma unroll
        for (int j = 0; j < 8; ++j)
            vh[j] = f2bf(x[(((size_t)(b * 64 + ic0 + j)) << 14) + yx]);
        *(ushort8*)(xTh + base + ic0) = vh;
    }
}

// ------------------------------------------------------------- conv: implicit GEMM (bf16), half-row
// grid 1024: (b, y, half). 4 waves x 16 px. LDS x-tile 3x66x64 bf16 (25 KB) -> 4+ blocks/CU.
// i_all permuted: half-row base ((b*128+y)*2+hh)<<14 ; slot (wv*4+r)<<10 + lane*16.
__global__ __launch_bounds__(256, 4) void conv_mfma(const unsigned short* __restrict__ xTh,
                                                    const unsigned short* __restrict__ BTh,
                                                    const float* __restrict__ b_ih,
                                                    unsigned short* __restrict__ iallp) {
    __shared__ __align__(16) unsigned char smem[25344];
    const int tid = threadIdx.x;
    const int b = blockIdx.x >> 8, y = (blockIdx.x >> 1) & 127, hh2 = blockIdx.x & 1;

    for (int ch = tid; ch < 1584; ch += 256) {            // 3*66*8 chunks
        const int row = ch / 528;
        const int rem = ch - row * 528;
        const int pxl = rem >> 3, icc = rem & 7;
        const int gy = y + row - 1, gx = hh2 * 64 + pxl - 1;
        ushort8 vh = {};
        if (gy >= 0 && gy < 128 && gx >= 0 && gx < 128) {
            const size_t go = ((size_t)(b * 16384 + gy * 128 + gx)) * 64 + icc * 8;
            vh = *(const ushort8*)(xTh + go);
        }
        const int off = ((row * 66 + pxl) * 128 + icc * 16) ^ ((pxl & 7) << 4);
        *(ushort8*)(smem + off) = vh;
    }
    __syncthreads();

    const int lane = tid & 63, wv = tid >> 6;
    const int lrow = lane & 15, lkq = lane >> 4;

    f32x4 acc[12] = {};
    for (int tap = 0; tap < 9; ++tap) {
        const int row = tap / 3, dx = tap % 3 - 1;
#pragma unroll
        for (int ih = 0; ih < 2; ++ih) {
            const int pxl = wv * 16 + lrow + dx + 1;
            const int off = ((row * 66 + pxl) * 128 + ih * 64 + lkq * 16) ^ ((pxl & 7) << 4);
            bf16x8 Ah = *(const bf16x8*)(smem + off);
#pragma unroll
            for (int n = 0; n < 12; ++n) {
                const int bo = (n * 16 + lrow) * 576 + tap * 64 + ih * 32 + lkq * 8;
                bf16x8 Bh = *(const bf16x8*)(BTh + bo);
                acc[n] = __builtin_amdgcn_mfma_f32_16x16x32_bf16(Ah, Bh, acc[n], 0, 0, 0);
            }
        }
    }

    float bias[12];
#pragma unroll
    for (int n = 0; n < 12; ++n) bias[n] = b_ih[n * 16 + lrow];
    const size_t base = ((size_t)((b * 128 + y) * 2 + hh2)) << 14;
#pragma unroll
    for (int r = 0; r < 4; ++r) {
        ushort8 v0, v1;
#pragma unroll
        for (int n = 0; n < 8; ++n) v0[n] = f2bf(acc[n][r] + bias[n]);
#pragma unroll
        for (int n = 8; n < 12; ++n) v1[n - 8] = f2bf(acc[n][r] + bias[n]);
        v1[4] = 0; v1[5] = 0; v1[6] = 0; v1[7] = 0;
        const size_t o = base + (size_t)(((wv * 4 + r) << 10) + lane * 16);
        *(ushort8*)(iallp + o) = v0;
        *(ushort8*)(iallp + o + 8) = v1;
    }
}

// ------------------------------------------------------------- fused step kernel (half-row)
// ph1 merge -> h_t (f32 out + A_lds bf16) + prev diff-loss ; ph2 MFMA hh ; ph3 gates -> hy LDS
// ph4a hy -> global bf16 ; ph4b o-logits via MFMA + shuffle softmax + bce partial.
template <bool FIRST>
__global__ __launch_bounds__(256, 4) void step_kernel(const unsigned short* __restrict__ hyp,
                                                      const float* __restrict__ o_prev,
                                                      const unsigned short* __restrict__ iallp,
                                                      const unsigned short* __restrict__ whhB,
                                                      const float* __restrict__ b_hh,
                                                      const unsigned short* __restrict__ whoB,
                                                      const float* __restrict__ b_ho,
                                                      const float* __restrict__ mask,
                                                      float* __restrict__ hidd_out,
                                                      unsigned short* __restrict__ hy_cur,
                                                      float* __restrict__ o_out,
                                                      float* __restrict__ loss, int firstloss,
                                                      float* __restrict__ bceP) {
    __shared__ __align__(16) unsigned char smem[27648];
    // [0,8192) A_lds bf16 [64px][64ch] swz | [8192,17408) hy_c [64c][72px] | [17408,26624) hy_p [64px][72c] | red 1K
    unsigned short* hy_c = (unsigned short*)(smem + 8192);
    unsigned short* hy_p = (unsigned short*)(smem + 17408);
    float* red = (float*)(smem + 26624);

    const int tid = threadIdx.x;
    const int bid = blockIdx.x;
    const int b = bid >> 8, y = (bid >> 1) & 127, hh2 = bid & 1;
    const int pxb = hh2 * 64, yxrow = y * 128;

    if constexpr (!FIRST) {
        const int px = tid & 63, cq = tid >> 6;
        const int gpx = pxb + px, yx = yxrow + gpx;
        const float* ob = o_prev + (((size_t)b * 9) << 14);
        float onb[9], okf[9];
        int nofs[9];
#pragma unroll
        for (int ey = -1; ey <= 1; ey++)
#pragma unroll
            for (int ex = -1; ex <= 1; ex++) {
                const int idx = (ey + 1) * 3 + (ex + 1);
                int ny = y + ey, nx = gpx + ex;
                bool ok = (ny >= 0) && (ny < 128) && (nx >= 0) && (nx < 128);
                int cy = min(max(ny, 0), 127), cx = min(max(nx, 0), 127);
                nofs[idx] = cy * 128 + cx;
                okf[idx] = ok ? 1.0f : 0.0f;
                const int j = 3 * (1 - ey) + (1 - ex);
                float v = ob[(((size_t)j) << 14) + nofs[idx]];
                onb[idx] = ok ? v : 0.0f;
            }
#pragma unroll
        for (int q = 0; q < 2; ++q) {
            ushort8 vh;
#pragma unroll
            for (int j = 0; j < 8; ++j) {
                const int c = cq * 16 + q * 8 + j;
                const unsigned short* hc = hyp + (((size_t)(b * 64 + c)) << 14);
                float a = 0.0f;
#pragma unroll
                for (int idx = 0; idx < 9; ++idx) a = fmaf(bf2f(hc[nofs[idx]]), onb[idx], a);
                hidd_out[(((size_t)(b * 64 + c)) << 14) + yx] = a;
                vh[j] = f2bf(a);
            }
            const int off = (px * 128 + (cq * 16 + q * 8) * 2) ^ ((px & 7) << 4);
            *(ushort8*)(smem + off) = vh;
        }
        if (cq == 0) {
            const float* o4p = ob + (((size_t)4) << 14);
#pragma unroll
            for (int i = 0; i < 9; ++i) {
                float g = okf[i] * o4p[nofs[i]];
                float oi = ob[(((size_t)i) << 14) + yx];
                float d = g - oi;
                float dv = d * d * oi * 0.01f;
                const size_t li = (((size_t)(b * 9 + i)) << 14) + yx;
                if (firstloss) loss[li] = dv;
                else           loss[li] += dv;
            }
        }
        __syncthreads();
    }

    const int lane = tid & 63, wv = tid >> 6;
    const int lrow = lane & 15, lkq = lane >> 4;

    f32x4 acc[12] = {};
    if constexpr (!FIRST) {
        bf16x8 Ah[2];
#pragma unroll
        for (int ih = 0; ih < 2; ++ih) {
            const int pxa = wv * 16 + lrow;
            const int off = (pxa * 128 + ih * 64 + lkq * 16) ^ ((pxa & 7) << 4);
            Ah[ih] = *(const bf16x8*)(smem + off);
        }
#pragma unroll
        for (int n = 0; n < 12; ++n)
#pragma unroll
            for (int ih = 0; ih < 2; ++ih) {
                const int bo = (n * 16 + lrow) * 64 + ih * 32 + lkq * 8;
                bf16x8 Bh = *(const bf16x8*)(whhB + bo);
                acc[n] = __builtin_amdgcn_mfma_f32_16x16x32_bf16(Ah[ih], Bh, acc[n], 0, 0, 0);
            }
    }

    // ph3: gates
    float bhr[4], bhi[4], bhn[4];
#pragma unroll
    for (int nf = 0; nf < 4; ++nf) {
        bhr[nf] = b_hh[nf * 16 + lrow];
        bhi[nf] = b_hh[64 + nf * 16 + lrow];
        bhn[nf] = b_hh[128 + nf * 16 + lrow];
    }
    const size_t ibase = (((size_t)((b * 128 + y) * 2 + hh2)) << 14) + (size_t)(wv << 12);
#pragma unroll
    for (int rr = 0; rr < 4; ++rr) {
        const int pxl = wv * 16 + lkq * 4 + rr;
        const size_t o = ibase + (size_t)((rr << 10) + lane * 16);
        ushort8 lo = *(const ushort8*)(iallp + o);
        ushort8 hi = *(const ushort8*)(iallp + o + 8);
#pragma unroll
        for (int nf = 0; nf < 4; ++nf) {
            const int g = nf * 16 + lrow;
            float hr = bhr[nf], hig = bhi[nf], hn = bhn[nf];
            if constexpr (!FIRST) {
                hr += acc[nf][rr];
                hig += acc[nf + 4][rr];
                hn += acc[nf + 8][rr];
            }
            float ir = bf2f(lo[nf]), ii = bf2f(lo[4 + nf]), inn = bf2f(hi[nf]);
            float rg = frcp(1.0f + __expf(-(ir + hr)));
            float ig = frcp(1.0f + __expf(-(ii + hig)));
            float t2 = __expf(2.0f * (inn + rg * hn));
            float nn = 1.0f - 2.0f * frcp(t2 + 1.0f);
            float hp = 0.0f;
            if constexpr (!FIRST) {
                const int offA = (pxl * 128 + g * 2) ^ ((pxl & 7) << 4);
                hp = bf2f(*(const unsigned short*)(smem + offA));
            }
            unsigned short hv = f2bf(nn + ig * (hp - nn));
            hy_c[g * 72 + pxl] = hv;
            hy_p[pxl * 72 + g] = hv;
        }
    }
    __syncthreads();

    // ph4a: hy -> global bf16 (coalesced; 4 threads per channel row)
    {
        const int c = tid >> 2, q = tid & 3;
        const size_t gb = (((size_t)(b * 64 + c)) << 14) + yxrow + pxb + q * 16;
        *(ushort8*)(hy_cur + gb)     = *(const ushort8*)(hy_c + c * 72 + q * 16);
        *(ushort8*)(hy_cur + gb + 8) = *(const ushort8*)(hy_c + c * 72 + q * 16 + 8);
    }

    // ph4b: o-logits via MFMA + 16-lane-group shuffle softmax
    f32x4 aco = {};
#pragma unroll
    for (int ih = 0; ih < 2; ++ih) {
        const int pxa = wv * 16 + lrow;
        bf16x8 Ao = *(const bf16x8*)(hy_p + pxa * 72 + ih * 32 + lkq * 8);
        bf16x8 Bo = *(const bf16x8*)(whoB + lrow * 64 + ih * 32 + lkq * 8);
        aco = __builtin_amdgcn_mfma_f32_16x16x32_bf16(Ao, Bo, aco, 0, 0, 0);
    }
    const float bho = (lrow < 9) ? b_ho[lrow] : 0.0f;
    float ov[4];
    float vbce = 0.0f;
    const int yx0 = yxrow + pxb + wv * 16 + lkq * 4;
#pragma unroll
    for (int r = 0; r < 4; ++r) {
        float lg = aco[r] + bho;
        float v = (lrow < 9) ? lg : -1e30f;
        v = fmaxf(v, __shfl_xor(v, 1));
        v = fmaxf(v, __shfl_xor(v, 2));
        v = fmaxf(v, __shfl_xor(v, 4));
        v = fmaxf(v, __shfl_xor(v, 8));
        float e = (lrow < 9) ? __expf(lg - v) : 0.0f;
        float s = e;
        s += __shfl_xor(s, 1);
        s += __shfl_xor(s, 2);
        s += __shfl_xor(s, 4);
        s += __shfl_xor(s, 8);
        ov[r] = e * frcp(s);
    }
    if (lrow < 9) {
        f32x4 wvec = {ov[0], ov[1], ov[2], ov[3]};
        *(f32x4*)(o_out + (((size_t)(b * 9 + lrow)) << 14) + yx0) = wvec;
    }
    if (lrow == 4) {
        const f32x4 mk = *(const f32x4*)(mask + (((size_t)b) << 14) + yx0);
#pragma unroll
        for (int r = 0; r < 4; ++r)
            vbce += mk[r] * __logf(1.0f - ov[r]) + (1.0f - mk[r]) * __logf(ov[r]);
    }
    red[tid] = (lrow == 4) ? vbce : 0.0f;
    __syncthreads();
    for (int off = 128; off > 0; off >>= 1) {
        if (tid < off) red[tid] += red[tid + off];
        __syncthreads();
    }
    if (tid == 0) bceP[bid] = red[0];
}

// ------------------------------------------------------------- final merge (h_8) + last loss + bce
__global__ __launch_bounds__(256) void final_merge(const unsigned short* __restrict__ hyp,
                                                   const float* __restrict__ o_prev,
                                                   float* __restrict__ hidd_out,
                                                   float* __restrict__ loss,
                                                   const float* __restrict__ bceT) {
    const int tid = threadIdx.x;
    const int bid = blockIdx.x;
    const int b = bid >> 8, y = (bid >> 1) & 127, hh2 = bid & 1;
    const int px = tid & 63, cq = tid >> 6;
    const int gpx = hh2 * 64 + px, yx = y * 128 + gpx;
    const float* ob = o_prev + (((size_t)b * 9) << 14);
    float onb[9], okf[9];
    int nofs[9];
#pragma unroll
    for (int ey = -1; ey <= 1; ey++)
#pragma unroll
        for (int ex = -1; ex <= 1; ex++) {
            const int idx = (ey + 1) * 3 + (ex + 1);
            int ny = y + ey, nx = gpx + ex;
            bool ok = (ny >= 0) && (ny < 128) && (nx >= 0) && (nx < 128);
            int cy = min(max(ny, 0), 127), cx = min(max(nx, 0), 127);
            nofs[idx] = cy * 128 + cx;
            okf[idx] = ok ? 1.0f : 0.0f;
            const int j = 3 * (1 - ey) + (1 - ex);
            float v = ob[(((size_t)j) << 14) + nofs[idx]];
            onb[idx] = ok ? v : 0.0f;
        }
    for (int cc = 0; cc < 16; ++cc) {
        const int c = cq * 16 + cc;
        const unsigned short* hc = hyp + (((size_t)(b * 64 + c)) << 14);
        float a = 0.0f;
#pragma unroll
        for (int idx = 0; idx < 9; ++idx) a = fmaf(bf2f(hc[nofs[idx]]), onb[idx], a);
        hidd_out[(((size_t)(b * 64 + c)) << 14) + yx] = a;
    }
    if (cq == 0) {
        const float bt = *bceT;
        const float* o4p = ob + (((size_t)4) << 14);
#pragma unroll
        for (int i = 0; i < 9; ++i) {
            float g = okf[i] * o4p[nofs[i]];
            float oi = ob[(((size_t)i) << 14) + yx];
            float d = g - oi;
            float dv = d * d * oi * 0.01f;
            const size_t li = (((size_t)(b * 9 + i)) << 14) + yx;
            loss[li] += dv + bt;
        }
    }
}

// ------------------------------------------------------------- bce reduce (8192 partials)
__global__ void bce_reduce_kernel(const float* __restrict__ partial, float* __restrict__ out_tot) {
    __shared__ float red[256];
    float s = 0.0f;
    for (int i = threadIdx.x; i < 8192; i += 256) s += partial[i];
    red[threadIdx.x] = s;
    __syncthreads();
    for (int off = 128; off > 0; off >>= 1) {
        if (threadIdx.x < off) red[threadIdx.x] += red[threadIdx.x + off];
        __syncthreads();
    }
    if (threadIdx.x == 0) *out_tot = -red[0] * (1.0f / 65536.0f);
}

// ------------------------------------------------------------- launcher
extern "C" void kernel_launch(void* const* d_in, const int* in_sizes, int n_in,
                              void* d_out, int out_size, void* d_ws, size_t ws_size,
                              hipStream_t stream) {
    const float* x    = (const float*)d_in[0];
    const float* mask = (const float*)d_in[1];
    const float* w_ih = (const float*)d_in[2];
    const float* b_ih = (const float*)d_in[3];
    const float* w_hh = (const float*)d_in[4];
    const float* b_hh = (const float*)d_in[5];
    const float* w_ho = (const float*)d_in[6];
    const float* b_ho = (const float*)d_in[7];
    float* out = (float*)d_out;
    float* ws  = (float*)d_ws;

    unsigned short* iallp = (unsigned short*)(ws + WS_IALLP);
    unsigned short* xTh   = (unsigned short*)(ws + WS_HYA);   // conv-time only
    unsigned short* hyA   = (unsigned short*)(ws + WS_HYA);
    unsigned short* hyB   = (unsigned short*)(ws + WS_HYB);
    unsigned short* whhB  = (unsigned short*)(ws + WS_WHH);
    unsigned short* whoB  = (unsigned short*)(ws + WS_WHOB);
    unsigned short* BTh   = (unsigned short*)(ws + WS_BTH);
    float* bceP = ws + WS_BCEP;
    float* bceT = ws + WS_BCET;
    float* lossp = out + LOSS_OFF;

    prep_weights<<<484, 256, 0, stream>>>(w_hh, w_ho, w_ih, whhB, whoB, BTh);
    transpose_x<<<256, 256, 0, stream>>>(x, xTh);
    conv_mfma<<<1024, 256, 0, stream>>>(xTh, BTh, b_ih, iallp);

    step_kernel<true><<<1024, 256, 0, stream>>>(nullptr, nullptr, iallp, whhB, b_hh, whoB,
                                                b_ho, mask, nullptr, hyA, out + OUTS_OFF,
                                                lossp, 0, bceP);
    for (int t = 1; t < 8; ++t) {
        const unsigned short* hypr = (t & 1) ? hyA : hyB;
        unsigned short* hyc = (t & 1) ? hyB : hyA;
        step_kernel<false><<<1024, 256, 0, stream>>>(hypr, out + OUTS_OFF + (size_t)(t - 1) * O_SZ,
                                                     iallp, whhB, b_hh, whoB, b_ho, mask,
                                                     out + (size_t)(t - 1) * HID_SZ, hyc,
                                                     out + OUTS_OFF + (size_t)t * O_SZ, lossp,
                                                     (t == 1) ? 1 : 0, bceP + t * 1024);
    }
    bce_reduce_kernel<<<1, 256, 0, stream>>>(bceP, bceT);
    final_merge<<<1024, 256, 0, stream>>>(hyB, out + OUTS_OFF + (size_t)7 * O_SZ,
                                          out + (size_t)7 * HID_SZ, lossp, bceT);
}

// Round 7
// 285.017 us; speedup vs baseline: 3.3277x; 1.3110x over previous
//
#include <hip/hip_runtime.h>

// B=4, C_IN=64, NUM_HIDDEN=64, H=W=128, MOVESQ=9, T=8
#define NP 16384
#define HID_SZ 4194304      // 4*64*NP
#define O_SZ   589824       // 4*9*NP
#define OUTS_OFF 33554432   // 8*HID_SZ
#define LOSS_OFF 38273024   // OUTS_OFF + 8*O_SZ

// ws layout (float units), ~50.6 MB
#define WS_IALLP 0          // 8,388,608 floats = 16,777,216 ushorts (1024 half-rows x 16384)
#define WS_HYA   8388608    // 2,097,152 floats = 4,194,304 ushorts (hy bf16) ; xTh overlaps (conv-time)
#define WS_HYB   10485760   // 2,097,152 floats
#define WS_WHH   12582912   // 6144 floats = 12,288 ushorts (w_hh bf16, FRAGMENT order)
#define WS_WHOB  12589056   // 512 floats = 1024 ushorts (w_ho bf16, FRAGMENT order)
#define WS_BTH   12589568   // 55,296 floats = 110,592 ushorts (w_ih bf16, FRAGMENT order)
#define WS_BCEP  12644864   // 8192 floats
#define WS_BCET  12653056   // 1 float

typedef __attribute__((ext_vector_type(8))) short bf16x8;
typedef __attribute__((ext_vector_type(8))) unsigned short ushort8;
typedef __attribute__((ext_vector_type(4))) float f32x4;

__device__ __forceinline__ float frcp(float x) { return __builtin_amdgcn_rcpf(x); }
__device__ __forceinline__ unsigned short f2bf(float f) {
    unsigned int u = __float_as_uint(f);
    return (unsigned short)((u + 0x7fffu + ((u >> 16) & 1u)) >> 16);
}
__device__ __forceinline__ float bf2f(unsigned short h) {
    return __uint_as_float(((unsigned int)h) << 16);
}

// ------------------------------------------------------------- weight prep (fragment order)
// A B-fragment for mfma_16x16x32 is 512 ushorts: lane (lrow=lane&15 -> col, lkq=lane>>4 -> k-quad)
// holds 8 consecutive k elements. Fragment f stored at [f<<9 | lane*8 | e] -> coalesced 1KB loads.
__global__ void prep_weights(const float* __restrict__ w_hh, const float* __restrict__ w_ho,
                             const float* __restrict__ w_ih,
                             unsigned short* __restrict__ whhBf, unsigned short* __restrict__ whoBf,
                             unsigned short* __restrict__ BTf) {
    int i = blockIdx.x * 256 + threadIdx.x;
    if (i < 12288) {                        // whhBf: f = ih*12+n ; val = w_hh[n*16+lrow][ih*32+lkq*8+e]
        int f = i >> 9, r = i & 511;
        int lane = r >> 3, e = r & 7, lrow = lane & 15, lkq = lane >> 4;
        int ih = f / 12, n = f % 12;
        whhBf[i] = f2bf(w_hh[(n * 16 + lrow) * 64 + ih * 32 + lkq * 8 + e]);
    } else if (i < 13312) {                 // whoBf: f = ih ; val = w_ho[lrow][ih*32+lkq*8+e] (lrow<9)
        int j = i - 12288;
        int f = j >> 9, r = j & 511;
        int lane = r >> 3, e = r & 7, lrow = lane & 15, lkq = lane >> 4;
        whoBf[j] = (lrow < 9) ? f2bf(w_ho[lrow * 64 + f * 32 + lkq * 8 + e]) : (unsigned short)0;
    } else if (i < 13312 + 110592) {        // BTf: f = (tap*2+ih)*12+n ; val = w_ih[oc][ic][tap]
        int k2 = i - 13312;
        int f = k2 >> 9, r = k2 & 511;
        int lane = r >> 3, e = r & 7, lrow = lane & 15, lkq = lane >> 4;
        int tapih = f / 12, n = f % 12;
        int tap = tapih >> 1, ih = tapih & 1;
        int oc = n * 16 + lrow, ic = ih * 32 + lkq * 8 + e;
        BTf[k2] = f2bf(w_ih[(oc * 64 + ic) * 9 + tap]);
    }
}

// ------------------------------------------------------------- x -> channel-last bf16
__global__ __launch_bounds__(256) void transpose_x(const float* __restrict__ x,
                                                   unsigned short* __restrict__ xTh) {
    const int p = blockIdx.x * 256 + threadIdx.x;
    const int b = p >> 14, yx = p & 16383;
    const size_t base = ((size_t)p) << 6;
    for (int ic0 = 0; ic0 < 64; ic0 += 8) {
        ushort8 vh;
#pragma unroll
        for (int j = 0; j < 8; ++j)
            vh[j] = f2bf(x[(((size_t)(b * 64 + ic0 + j)) << 14) + yx]);
        *(ushort8*)(xTh + base + ic0) = vh;
    }
}

// ------------------------------------------------------------- conv: implicit GEMM (bf16), half-row
// grid 1024: (b, y, half). 4 waves x 16 px. LDS x-tile 3x66x64 bf16 (25 KB).
// B loads are coalesced fragment reads: BTf + (f<<9) + lane*8.
__global__ __launch_bounds__(256, 4) void conv_mfma(const unsigned short* __restrict__ xTh,
                                                    const unsigned short* __restrict__ BTf,
                                                    const float* __restrict__ b_ih,
                                                    unsigned short* __restrict__ iallp) {
    __shared__ __align__(16) unsigned char smem[25344];
    const int tid = threadIdx.x;
    const int b = blockIdx.x >> 8, y = (blockIdx.x >> 1) & 127, hh2 = blockIdx.x & 1;

    for (int ch = tid; ch < 1584; ch += 256) {            // 3*66*8 chunks
        const int row = ch / 528;
        const int rem = ch - row * 528;
        const int pxl = rem >> 3, icc = rem & 7;
        const int gy = y + row - 1, gx = hh2 * 64 + pxl - 1;
        ushort8 vh = {};
        if (gy >= 0 && gy < 128 && gx >= 0 && gx < 128) {
            const size_t go = ((size_t)(b * 16384 + gy * 128 + gx)) * 64 + icc * 8;
            vh = *(const ushort8*)(xTh + go);
        }
        const int off = ((row * 66 + pxl) * 128 + icc * 16) ^ ((pxl & 7) << 4);
        *(ushort8*)(smem + off) = vh;
    }
    __syncthreads();

    const int lane = tid & 63, wv = tid >> 6;
    const int lrow = lane & 15, lkq = lane >> 4;
    const unsigned short* BTl = BTf + lane * 8;

    f32x4 acc[12] = {};
#pragma unroll
    for (int tap = 0; tap < 9; ++tap) {
        const int row = tap / 3, dx = tap % 3 - 1;
#pragma unroll
        for (int ih = 0; ih < 2; ++ih) {
            const int pxl = wv * 16 + lrow + dx + 1;
            const int off = ((row * 66 + pxl) * 128 + ih * 64 + lkq * 16) ^ ((pxl & 7) << 4);
            bf16x8 Ah = *(const bf16x8*)(smem + off);
#pragma unroll
            for (int n = 0; n < 12; ++n) {
                bf16x8 Bh = *(const bf16x8*)(BTl + (((tap * 2 + ih) * 12 + n) << 9));
                acc[n] = __builtin_amdgcn_mfma_f32_16x16x32_bf16(Ah, Bh, acc[n], 0, 0, 0);
            }
        }
    }

    float bias[12];
#pragma unroll
    for (int n = 0; n < 12; ++n) bias[n] = b_ih[n * 16 + lrow];
    const size_t base = ((size_t)((b * 128 + y) * 2 + hh2)) << 14;
#pragma unroll
    for (int r = 0; r < 4; ++r) {
        ushort8 v0, v1;
#pragma unroll
        for (int n = 0; n < 8; ++n) v0[n] = f2bf(acc[n][r] + bias[n]);
#pragma unroll
        for (int n = 8; n < 12; ++n) v1[n - 8] = f2bf(acc[n][r] + bias[n]);
        v1[4] = 0; v1[5] = 0; v1[6] = 0; v1[7] = 0;
        const size_t o = base + (size_t)(((wv * 4 + r) << 10) + lane * 16);
        *(ushort8*)(iallp + o) = v0;
        *(ushort8*)(iallp + o + 8) = v1;
    }
}

// ------------------------------------------------------------- fused step kernel (half-row)
template <bool FIRST>
__global__ __launch_bounds__(256, 4) void step_kernel(const unsigned short* __restrict__ hyp,
                                                      const float* __restrict__ o_prev,
                                                      const unsigned short* __restrict__ iallp,
                                                      const unsigned short* __restrict__ whhBf,
                                                      const float* __restrict__ b_hh,
                                                      const unsigned short* __restrict__ whoBf,
                                                      const float* __restrict__ b_ho,
                                                      const float* __restrict__ mask,
                                                      float* __restrict__ hidd_out,
                                                      unsigned short* __restrict__ hy_cur,
                                                      float* __restrict__ o_out,
                                                      float* __restrict__ loss, int firstloss,
                                                      float* __restrict__ bceP) {
    __shared__ __align__(16) unsigned char smem[27648];
    // [0,8192) A_lds bf16 [64px][64ch] swz | [8192,17408) hy_c [64c][72px] | [17408,26624) hy_p [64px][72c] | red 1K
    unsigned short* hy_c = (unsigned short*)(smem + 8192);
    unsigned short* hy_p = (unsigned short*)(smem + 17408);
    float* red = (float*)(smem + 26624);

    const int tid = threadIdx.x;
    const int bid = blockIdx.x;
    const int b = bid >> 8, y = (bid >> 1) & 127, hh2 = bid & 1;
    const int pxb = hh2 * 64, yxrow = y * 128;

    if constexpr (!FIRST) {
        const int px = tid & 63, cq = tid >> 6;
        const int gpx = pxb + px, yx = yxrow + gpx;
        const float* ob = o_prev + (((size_t)b * 9) << 14);
        float onb[9], okf[9];
        int nofs[9];
#pragma unroll
        for (int ey = -1; ey <= 1; ey++)
#pragma unroll
            for (int ex = -1; ex <= 1; ex++) {
                const int idx = (ey + 1) * 3 + (ex + 1);
                int ny = y + ey, nx = gpx + ex;
                bool ok = (ny >= 0) && (ny < 128) && (nx >= 0) && (nx < 128);
                int cy = min(max(ny, 0), 127), cx = min(max(nx, 0), 127);
                nofs[idx] = cy * 128 + cx;
                okf[idx] = ok ? 1.0f : 0.0f;
                const int j = 3 * (1 - ey) + (1 - ex);
                float v = ob[(((size_t)j) << 14) + nofs[idx]];
                onb[idx] = ok ? v : 0.0f;
            }
#pragma unroll
        for (int q = 0; q < 2; ++q) {
            ushort8 vh;
#pragma unroll
            for (int j = 0; j < 8; ++j) {
                const int c = cq * 16 + q * 8 + j;
                const unsigned short* hc = hyp + (((size_t)(b * 64 + c)) << 14);
                float a = 0.0f;
#pragma unroll
                for (int idx = 0; idx < 9; ++idx) a = fmaf(bf2f(hc[nofs[idx]]), onb[idx], a);
                hidd_out[(((size_t)(b * 64 + c)) << 14) + yx] = a;
                vh[j] = f2bf(a);
            }
            const int off = (px * 128 + (cq * 16 + q * 8) * 2) ^ ((px & 7) << 4);
            *(ushort8*)(smem + off) = vh;
        }
        if (cq == 0) {
            const float* o4p = ob + (((size_t)4) << 14);
#pragma unroll
            for (int i = 0; i < 9; ++i) {
                float g = okf[i] * o4p[nofs[i]];
                float oi = ob[(((size_t)i) << 14) + yx];
                float d = g - oi;
                float dv = d * d * oi * 0.01f;
                const size_t li = (((size_t)(b * 9 + i)) << 14) + yx;
                if (firstloss) loss[li] = dv;
                else           loss[li] += dv;
            }
        }
        __syncthreads();
    }

    const int lane = tid & 63, wv = tid >> 6;
    const int lrow = lane & 15, lkq = lane >> 4;

    f32x4 acc[12] = {};
    if constexpr (!FIRST) {
        bf16x8 Ah[2];
#pragma unroll
        for (int ih = 0; ih < 2; ++ih) {
            const int pxa = wv * 16 + lrow;
            const int off = (pxa * 128 + ih * 64 + lkq * 16) ^ ((pxa & 7) << 4);
            Ah[ih] = *(const bf16x8*)(smem + off);
        }
#pragma unroll
        for (int ih = 0; ih < 2; ++ih)
#pragma unroll
            for (int n = 0; n < 12; ++n) {
                bf16x8 Bh = *(const bf16x8*)(whhBf + (((ih * 12 + n) << 9) + lane * 8));
                acc[n] = __builtin_amdgcn_mfma_f32_16x16x32_bf16(Ah[ih], Bh, acc[n], 0, 0, 0);
            }
    }

    // ph3: gates
    float bhr[4], bhi[4], bhn[4];
#pragma unroll
    for (int nf = 0; nf < 4; ++nf) {
        bhr[nf] = b_hh[nf * 16 + lrow];
        bhi[nf] = b_hh[64 + nf * 16 + lrow];
        bhn[nf] = b_hh[128 + nf * 16 + lrow];
    }
    const size_t ibase = (((size_t)((b * 128 + y) * 2 + hh2)) << 14) + (size_t)(wv << 12);
#pragma unroll
    for (int rr = 0; rr < 4; ++rr) {
        const int pxl = wv * 16 + lkq * 4 + rr;
        const size_t o = ibase + (size_t)((rr << 10) + lane * 16);
        ushort8 lo = *(const ushort8*)(iallp + o);
        ushort8 hi = *(const ushort8*)(iallp + o + 8);
#pragma unroll
        for (int nf = 0; nf < 4; ++nf) {
            const int g = nf * 16 + lrow;
            float hr = bhr[nf], hig = bhi[nf], hn = bhn[nf];
            if constexpr (!FIRST) {
                hr += acc[nf][rr];
                hig += acc[nf + 4][rr];
                hn += acc[nf + 8][rr];
            }
            float ir = bf2f(lo[nf]), ii = bf2f(lo[4 + nf]), inn = bf2f(hi[nf]);
            float rg = frcp(1.0f + __expf(-(ir + hr)));
            float ig = frcp(1.0f + __expf(-(ii + hig)));
            float t2 = __expf(2.0f * (inn + rg * hn));
            float nn = 1.0f - 2.0f * frcp(t2 + 1.0f);
            float hp = 0.0f;
            if constexpr (!FIRST) {
                const int offA = (pxl * 128 + g * 2) ^ ((pxl & 7) << 4);
                hp = bf2f(*(const unsigned short*)(smem + offA));
            }
            unsigned short hv = f2bf(nn + ig * (hp - nn));
            hy_c[g * 72 + pxl] = hv;
            hy_p[pxl * 72 + g] = hv;
        }
    }
    __syncthreads();

    // ph4a: hy -> global bf16 (coalesced)
    {
        const int c = tid >> 2, q = tid & 3;
        const size_t gb = (((size_t)(b * 64 + c)) << 14) + yxrow + pxb + q * 16;
        *(ushort8*)(hy_cur + gb)     = *(const ushort8*)(hy_c + c * 72 + q * 16);
        *(ushort8*)(hy_cur + gb + 8) = *(const ushort8*)(hy_c + c * 72 + q * 16 + 8);
    }

    // ph4b: o-logits via MFMA + 16-lane-group shuffle softmax
    f32x4 aco = {};
#pragma unroll
    for (int ih = 0; ih < 2; ++ih) {
        const int pxa = wv * 16 + lrow;
        bf16x8 Ao = *(const bf16x8*)(hy_p + pxa * 72 + ih * 32 + lkq * 8);
        bf16x8 Bo = *(const bf16x8*)(whoBf + ((ih << 9) + lane * 8));
        aco = __builtin_amdgcn_mfma_f32_16x16x32_bf16(Ao, Bo, aco, 0, 0, 0);
    }
    const float bho = (lrow < 9) ? b_ho[lrow] : 0.0f;
    float ov[4];
    float vbce = 0.0f;
    const int yx0 = yxrow + pxb + wv * 16 + lkq * 4;
#pragma unroll
    for (int r = 0; r < 4; ++r) {
        float lg = aco[r] + bho;
        float v = (lrow < 9) ? lg : -1e30f;
        v = fmaxf(v, __shfl_xor(v, 1));
        v = fmaxf(v, __shfl_xor(v, 2));
        v = fmaxf(v, __shfl_xor(v, 4));
        v = fmaxf(v, __shfl_xor(v, 8));
        float e = (lrow < 9) ? __expf(lg - v) : 0.0f;
        float s = e;
        s += __shfl_xor(s, 1);
        s += __shfl_xor(s, 2);
        s += __shfl_xor(s, 4);
        s += __shfl_xor(s, 8);
        ov[r] = e * frcp(s);
    }
    if (lrow < 9) {
        f32x4 wvec = {ov[0], ov[1], ov[2], ov[3]};
        *(f32x4*)(o_out + (((size_t)(b * 9 + lrow)) << 14) + yx0) = wvec;
    }
    if (lrow == 4) {
        const f32x4 mk = *(const f32x4*)(mask + (((size_t)b) << 14) + yx0);
#pragma unroll
        for (int r = 0; r < 4; ++r)
            vbce += mk[r] * __logf(1.0f - ov[r]) + (1.0f - mk[r]) * __logf(ov[r]);
    }
    red[tid] = (lrow == 4) ? vbce : 0.0f;
    __syncthreads();
    for (int off = 128; off > 0; off >>= 1) {
        if (tid < off) red[tid] += red[tid + off];
        __syncthreads();
    }
    if (tid == 0) bceP[bid] = red[0];
}

// ------------------------------------------------------------- final merge (h_8) + last loss + bce
__global__ __launch_bounds__(256) void final_merge(const unsigned short* __restrict__ hyp,
                                                   const float* __restrict__ o_prev,
                                                   float* __restrict__ hidd_out,
                                                   float* __restrict__ loss,
                                                   const float* __restrict__ bceT) {
    const int tid = threadIdx.x;
    const int bid = blockIdx.x;
    const int b = bid >> 8, y = (bid >> 1) & 127, hh2 = bid & 1;
    const int px = tid & 63, cq = tid >> 6;
    const int gpx = hh2 * 64 + px, yx = y * 128 + gpx;
    const float* ob = o_prev + (((size_t)b * 9) << 14);
    float onb[9], okf[9];
    int nofs[9];
#pragma unroll
    for (int ey = -1; ey <= 1; ey++)
#pragma unroll
        for (int ex = -1; ex <= 1; ex++) {
            const int idx = (ey + 1) * 3 + (ex + 1);
            int ny = y + ey, nx = gpx + ex;
            bool ok = (ny >= 0) && (ny < 128) && (nx >= 0) && (nx < 128);
            int cy = min(max(ny, 0), 127), cx = min(max(nx, 0), 127);
            nofs[idx] = cy * 128 + cx;
            okf[idx] = ok ? 1.0f : 0.0f;
            const int j = 3 * (1 - ey) + (1 - ex);
            float v = ob[(((size_t)j) << 14) + nofs[idx]];
            onb[idx] = ok ? v : 0.0f;
        }
    for (int cc = 0; cc < 16; ++cc) {
        const int c = cq * 16 + cc;
        const unsigned short* hc = hyp + (((size_t)(b * 64 + c)) << 14);
        float a = 0.0f;
#pragma unroll
        for (int idx = 0; idx < 9; ++idx) a = fmaf(bf2f(hc[nofs[idx]]), onb[idx], a);
        hidd_out[(((size_t)(b * 64 + c)) << 14) + yx] = a;
    }
    if (cq == 0) {
        const float bt = *bceT;
        const float* o4p = ob + (((size_t)4) << 14);
#pragma unroll
        for (int i = 0; i < 9; ++i) {
            float g = okf[i] * o4p[nofs[i]];
            float oi = ob[(((size_t)i) << 14) + yx];
            float d = g - oi;
            float dv = d * d * oi * 0.01f;
            const size_t li = (((size_t)(b * 9 + i)) << 14) + yx;
            loss[li] += dv + bt;
        }
    }
}

// ------------------------------------------------------------- bce reduce (8192 partials)
__global__ void bce_reduce_kernel(const float* __restrict__ partial, float* __restrict__ out_tot) {
    __shared__ float red[256];
    float s = 0.0f;
    for (int i = threadIdx.x; i < 8192; i += 256) s += partial[i];
    red[threadIdx.x] = s;
    __syncthreads();
    for (int off = 128; off > 0; off >>= 1) {
        if (threadIdx.x < off) red[threadIdx.x] += red[threadIdx.x + off];
        __syncthreads();
    }
    if (threadIdx.x == 0) *out_tot = -red[0] * (1.0f / 65536.0f);
}

// ------------------------------------------------------------- launcher
extern "C" void kernel_launch(void* const* d_in, const int* in_sizes, int n_in,
                              void* d_out, int out_size, void* d_ws, size_t ws_size,
                              hipStream_t stream) {
    const float* x    = (const float*)d_in[0];
    const float* mask = (const float*)d_in[1];
    const float* w_ih = (const float*)d_in[2];
    const float* b_ih = (const float*)d_in[3];
    const float* w_hh = (const float*)d_in[4];
    const float* b_hh = (const float*)d_in[5];
    const float* w_ho = (const float*)d_in[6];
    const float* b_ho = (const float*)d_in[7];
    float* out = (float*)d_out;
    float* ws  = (float*)d_ws;

    unsigned short* iallp = (unsigned short*)(ws + WS_IALLP);
    unsigned short* xTh   = (unsigned short*)(ws + WS_HYA);   // conv-time only
    unsigned short* hyA   = (unsigned short*)(ws + WS_HYA);
    unsigned short* hyB   = (unsigned short*)(ws + WS_HYB);
    unsigned short* whhBf = (unsigned short*)(ws + WS_WHH);
    unsigned short* whoBf = (unsigned short*)(ws + WS_WHOB);
    unsigned short* BTf   = (unsigned short*)(ws + WS_BTH);
    float* bceP = ws + WS_BCEP;
    float* bceT = ws + WS_BCET;
    float* lossp = out + LOSS_OFF;

    prep_weights<<<484, 256, 0, stream>>>(w_hh, w_ho, w_ih, whhBf, whoBf, BTf);
    transpose_x<<<256, 256, 0, stream>>>(x, xTh);
    conv_mfma<<<1024, 256, 0, stream>>>(xTh, BTf, b_ih, iallp);

    step_kernel<true><<<1024, 256, 0, stream>>>(nullptr, nullptr, iallp, whhBf, b_hh, whoBf,
                                                b_ho, mask, nullptr, hyA, out + OUTS_OFF,
                                                lossp, 0, bceP);
    for (int t = 1; t < 8; ++t) {
        const unsigned short* hypr = (t & 1) ? hyA : hyB;
        unsigned short* hyc = (t & 1) ? hyB : hyA;
        step_kernel<false><<<1024, 256, 0, stream>>>(hypr, out + OUTS_OFF + (size_t)(t - 1) * O_SZ,
                                                     iallp, whhBf, b_hh, whoBf, b_ho, mask,
                                                     out + (size_t)(t - 1) * HID_SZ, hyc,
                                                     out + OUTS_OFF + (size_t)t * O_SZ, lossp,
                                                     (t == 1) ? 1 : 0, bceP + t * 1024);
    }
    bce_reduce_kernel<<<1, 256, 0, stream>>>(bceP, bceT);
    final_merge<<<1024, 256, 0, stream>>>(hyB, out + OUTS_OFF + (size_t)7 * O_SZ,
                                          out + (size_t)7 * HID_SZ, lossp, bceT);
}

// Round 8
// 264.485 us; speedup vs baseline: 3.5860x; 1.0776x over previous
//
#include <hip/hip_runtime.h>

// B=4, C_IN=64, NUM_HIDDEN=64, H=W=128, MOVESQ=9, T=8
#define NP 16384
#define HID_SZ 4194304      // 4*64*NP
#define O_SZ   589824       // 4*9*NP
#define OUTS_OFF 33554432   // 8*HID_SZ
#define LOSS_OFF 38273024   // OUTS_OFF + 8*O_SZ

// ws layout (float units), ~42 MB
#define WS_IALL0 0           // 4,194,304 floats = 8,388,608 ushorts (16B slots)
#define WS_IALL1 4194304     // 2,097,152 floats = 4,194,304 ushorts (8B slots)
#define WS_HYA   6291456     // guard8 + 2,097,152 payload + guard8 (xTh overlaps, conv-time)
#define WS_HYB   8388624     // guard8 + 2,097,152 + guard8
#define WS_WHH   10485792    // 6144 floats (w_hh bf16 fragment order)
#define WS_WHOB  10491936    // 512 floats (w_ho bf16 fragment order)
#define WS_BTF   10492448    // 55,296 floats (w_ih bf16 fragment order)
#define WS_BCEP  10547744    // 8192 floats
#define WS_BCET  10555936    // 1 float

typedef __attribute__((ext_vector_type(8))) short bf16x8;
typedef __attribute__((ext_vector_type(8))) unsigned short ushort8;
typedef __attribute__((ext_vector_type(4))) unsigned short usht4;
typedef __attribute__((ext_vector_type(4))) float f32x4;

__device__ __forceinline__ float frcp(float x) { return __builtin_amdgcn_rcpf(x); }
__device__ __forceinline__ unsigned short f2bf(float f) {
    unsigned int u = __float_as_uint(f);
    return (unsigned short)((u + 0x7fffu + ((u >> 16) & 1u)) >> 16);
}
__device__ __forceinline__ float bf2f(unsigned short h) {
    return __uint_as_float(((unsigned int)h) << 16);
}
// XCD-chunked bijective swizzle for 1024-block grids: 128 consecutive logical ids per XCD
__device__ __forceinline__ int swz_bid(int bid) { return ((bid & 7) << 7) | (bid >> 3); }

// ------------------------------------------------------------- weight prep (fragment order)
__global__ void prep_weights(const float* __restrict__ w_hh, const float* __restrict__ w_ho,
                             const float* __restrict__ w_ih,
                             unsigned short* __restrict__ whhBf, unsigned short* __restrict__ whoBf,
                             unsigned short* __restrict__ BTf) {
    int i = blockIdx.x * 256 + threadIdx.x;
    if (i < 12288) {                        // whhBf: f=ih*12+n ; w_hh[n*16+lrow][ih*32+lkq*8+e]
        int f = i >> 9, r = i & 511;
        int lane = r >> 3, e = r & 7, lrow = lane & 15, lkq = lane >> 4;
        int ih = f / 12, n = f % 12;
        whhBf[i] = f2bf(w_hh[(n * 16 + lrow) * 64 + ih * 32 + lkq * 8 + e]);
    } else if (i < 13312) {                 // whoBf: f=ih ; w_ho[lrow][f*32+lkq*8+e] (lrow<9)
        int j = i - 12288;
        int f = j >> 9, r = j & 511;
        int lane = r >> 3, e = r & 7, lrow = lane & 15, lkq = lane >> 4;
        whoBf[j] = (lrow < 9) ? f2bf(w_ho[lrow * 64 + f * 32 + lkq * 8 + e]) : (unsigned short)0;
    } else if (i < 13312 + 110592) {        // BTf: f=(tap*2+ih)*12+n ; w_ih[oc][ic][tap]
        int k2 = i - 13312;
        int f = k2 >> 9, r = k2 & 511;
        int lane = r >> 3, e = r & 7, lrow = lane & 15, lkq = lane >> 4;
        int tapih = f / 12, n = f % 12;
        int tap = tapih >> 1, ih = tapih & 1;
        int oc = n * 16 + lrow, ic = ih * 32 + lkq * 8 + e;
        BTf[k2] = f2bf(w_ih[(oc * 64 + ic) * 9 + tap]);
    }
}

// ------------------------------------------------------------- x -> channel-last bf16
__global__ __launch_bounds__(256) void transpose_x(const float* __restrict__ x,
                                                   unsigned short* __restrict__ xTh) {
    const int p = blockIdx.x * 256 + threadIdx.x;
    const int b = p >> 14, yx = p & 16383;
    const size_t base = ((size_t)p) << 6;
    for (int ic0 = 0; ic0 < 64; ic0 += 8) {
        ushort8 vh;
#pragma unroll
        for (int j = 0; j < 8; ++j)
            vh[j] = f2bf(x[(((size_t)(b * 64 + ic0 + j)) << 14) + yx]);
        *(ushort8*)(xTh + base + ic0) = vh;
    }
}

// ------------------------------------------------------------- conv: implicit GEMM (bf16), half-row
__global__ __launch_bounds__(256, 4) void conv_mfma(const unsigned short* __restrict__ xTh,
                                                    const unsigned short* __restrict__ BTf,
                                                    const float* __restrict__ b_ih,
                                                    unsigned short* __restrict__ iall0,
                                                    unsigned short* __restrict__ iall1) {
    __shared__ __align__(16) unsigned char smem[25344];
    const int tid = threadIdx.x;
    const int bid = swz_bid(blockIdx.x);
    const int b = bid >> 8, y = (bid >> 1) & 127, hh2 = bid & 1;

    for (int ch = tid; ch < 1584; ch += 256) {            // 3*66*8 chunks
        const int row = ch / 528;
        const int rem = ch - row * 528;
        const int pxl = rem >> 3, icc = rem & 7;
        const int gy = y + row - 1, gx = hh2 * 64 + pxl - 1;
        ushort8 vh = {};
        if (gy >= 0 && gy < 128 && gx >= 0 && gx < 128) {
            const size_t go = ((size_t)(b * 16384 + gy * 128 + gx)) * 64 + icc * 8;
            vh = *(const ushort8*)(xTh + go);
        }
        const int off = ((row * 66 + pxl) * 128 + icc * 16) ^ ((pxl & 7) << 4);
        *(ushort8*)(smem + off) = vh;
    }
    __syncthreads();

    const int lane = tid & 63, wv = tid >> 6;
    const int lrow = lane & 15, lkq = lane >> 4;
    const unsigned short* BTl = BTf + lane * 8;

    f32x4 acc[12] = {};
#pragma unroll
    for (int tap = 0; tap < 9; ++tap) {
        const int row = tap / 3, dx = tap % 3 - 1;
#pragma unroll
        for (int ih = 0; ih < 2; ++ih) {
            const int pxl = wv * 16 + lrow + dx + 1;
            const int off = ((row * 66 + pxl) * 128 + ih * 64 + lkq * 16) ^ ((pxl & 7) << 4);
            bf16x8 Ah = *(const bf16x8*)(smem + off);
#pragma unroll
            for (int n = 0; n < 12; ++n) {
                bf16x8 Bh = *(const bf16x8*)(BTl + (((tap * 2 + ih) * 12 + n) << 9));
                acc[n] = __builtin_amdgcn_mfma_f32_16x16x32_bf16(Ah, Bh, acc[n], 0, 0, 0);
            }
        }
    }

    float bias[12];
#pragma unroll
    for (int n = 0; n < 12; ++n) bias[n] = b_ih[n * 16 + lrow];
    const size_t rowb = (size_t)((b * 128 + y) * 2 + hh2);
#pragma unroll
    for (int r = 0; r < 4; ++r) {
        ushort8 v0;
        usht4 v1;
#pragma unroll
        for (int n = 0; n < 8; ++n) v0[n] = f2bf(acc[n][r] + bias[n]);
#pragma unroll
        for (int n = 8; n < 12; ++n) v1[n - 8] = f2bf(acc[n][r] + bias[n]);
        *(ushort8*)(iall0 + (rowb << 13) + ((wv * 4 + r) << 9) + lane * 8) = v0;
        *(usht4*)(iall1 + (rowb << 12) + ((wv * 4 + r) << 8) + lane * 4) = v1;
    }
}

// ------------------------------------------------------------- fused step kernel (half-row)
// ph1: o-strip stage (LDS) + hy window loads (c,16px per thread) -> merge -> hidd_out + A_lds
// ph2: MFMA hh ; ph3: gates -> hy_p LDS + hy global (usht4) ; ph4: o-MFMA + softmax + bce.
template <bool FIRST>
__global__ __launch_bounds__(256, 4) void step_kernel(const unsigned short* __restrict__ hyp,
                                                      const float* __restrict__ o_prev,
                                                      const unsigned short* __restrict__ iall0,
                                                      const unsigned short* __restrict__ iall1,
                                                      const unsigned short* __restrict__ whhBf,
                                                      const float* __restrict__ b_hh,
                                                      const unsigned short* __restrict__ whoBf,
                                                      const float* __restrict__ b_ho,
                                                      const float* __restrict__ mask,
                                                      float* __restrict__ hidd_out,
                                                      unsigned short* __restrict__ hy_cur,
                                                      float* __restrict__ o_out,
                                                      float* __restrict__ bceP) {
    __shared__ __align__(16) unsigned char smem[19904];
    // [0,8192) A_lds | [8192,10640) ostrip 9x68 f32 | [10656,19872) hy_p 64x72 ush | [19872,+16) red
    float* ostrip = (float*)(smem + 8192);
    unsigned short* hy_p = (unsigned short*)(smem + 10656);
    float* red = (float*)(smem + 19872);

    const int tid = threadIdx.x;
    const int bid = swz_bid(blockIdx.x);
    const int b = bid >> 8, y = (bid >> 1) & 127, hh2 = bid & 1;
    const int pxb = hh2 * 64, yxrow = y * 128;

    if constexpr (!FIRST) {
        // hy windows: thread <-> (channel c, 16-px strip pq)
        const int c = tid >> 2, pq = tid & 3;
        const int gx0 = pxb + pq * 16;
        const unsigned short* hb = hyp + (((size_t)(b * 64 + c)) << 14);
        ushort8 w8[3][4];
#pragma unroll
        for (int r = 0; r < 3; ++r) {
            const int gyc = min(max(y + r - 1, 0), 127);
            const unsigned short* src = hb + gyc * 128 + gx0 - 8;   // guarded buffer
#pragma unroll
            for (int q = 0; q < 4; ++q) w8[r][q] = *(const ushort8*)(src + q * 8);
        }
        // o strips: 9 planes x 66, masked (plane j used at row y+1-j/3, x-shift 1-j%3)
        const float* ob = o_prev + (((size_t)b * 9) << 14);
        for (int e = tid; e < 594; e += 256) {
            const int j = e / 66, s = e - j * 66;
            const int rj = y + 1 - j / 3;
            const int gx = pxb - 1 + s;
            const bool ok = (rj >= 0) && (rj < 128) && (gx >= 0) && (gx < 128);
            ostrip[j * 68 + s] = ok ? ob[(((size_t)j) << 14) + rj * 128 + gx] : 0.0f;
        }
        __syncthreads();

        float a[16];
#pragma unroll
        for (int px = 0; px < 16; ++px) a[px] = 0.0f;
#pragma unroll
        for (int r = 0; r < 3; ++r) {
            float wf[18];   // window positions 7..24 (gx0-1 .. gx0+16)
#pragma unroll
            for (int k = 0; k < 18; ++k)
                wf[k] = bf2f((unsigned short)w8[r][(k + 7) >> 3][(k + 7) & 7]);
#pragma unroll
            for (int ex = -1; ex <= 1; ++ex) {
                const int idx = r * 3 + (ex + 1);
                const int j = 8 - idx;
                const float* osj = ostrip + j * 68 + pq * 16 + 1 + ex;
#pragma unroll
                for (int px = 0; px < 16; ++px)
                    a[px] = fmaf(wf[px + ex + 1], osj[px], a[px]);
            }
        }
        const size_t hob = (((size_t)(b * 64 + c)) << 14) + yxrow + gx0;
#pragma unroll
        for (int q = 0; q < 4; ++q) {
            f32x4 v = {a[q * 4], a[q * 4 + 1], a[q * 4 + 2], a[q * 4 + 3]};
            *(f32x4*)(hidd_out + hob + q * 4) = v;
        }
#pragma unroll
        for (int px = 0; px < 16; ++px) {
            const int pxl = pq * 16 + px;
            *(unsigned short*)(smem + ((pxl * 128 + c * 2) ^ ((pxl & 7) << 4))) = f2bf(a[px]);
        }
        __syncthreads();
    }

    const int lane = tid & 63, wv = tid >> 6;
    const int lrow = lane & 15, lkq = lane >> 4;

    f32x4 acc[12] = {};
    if constexpr (!FIRST) {
        bf16x8 Ah[2];
#pragma unroll
        for (int ih = 0; ih < 2; ++ih) {
            const int pxa = wv * 16 + lrow;
            const int off = (pxa * 128 + ih * 64 + lkq * 16) ^ ((pxa & 7) << 4);
            Ah[ih] = *(const bf16x8*)(smem + off);
        }
#pragma unroll
        for (int ih = 0; ih < 2; ++ih)
#pragma unroll
            for (int n = 0; n < 12; ++n) {
                bf16x8 Bh = *(const bf16x8*)(whhBf + (((ih * 12 + n) << 9) + lane * 8));
                acc[n] = __builtin_amdgcn_mfma_f32_16x16x32_bf16(Ah[ih], Bh, acc[n], 0, 0, 0);
            }
    }

    // ph3: gates (exact-packed iall reads, direct hy global stores)
    float bhr[4], bhi[4], bhn[4];
#pragma unroll
    for (int nf = 0; nf < 4; ++nf) {
        bhr[nf] = b_hh[nf * 16 + lrow];
        bhi[nf] = b_hh[64 + nf * 16 + lrow];
        bhn[nf] = b_hh[128 + nf * 16 + lrow];
    }
    const size_t rowb = (size_t)((b * 128 + y) * 2 + hh2);
    const unsigned short* p0 = iall0 + (rowb << 13) + (wv << 11) + lane * 8;
    const unsigned short* p1 = iall1 + (rowb << 12) + (wv << 10) + lane * 4;
    ushort8 lo[4];
    usht4 hi[4];
#pragma unroll
    for (int rr = 0; rr < 4; ++rr) {
        lo[rr] = *(const ushort8*)(p0 + (rr << 9));
        hi[rr] = *(const usht4*)(p1 + (rr << 8));
    }
#pragma unroll
    for (int nf = 0; nf < 4; ++nf) {
        const int g = nf * 16 + lrow;
        usht4 hv4;
#pragma unroll
        for (int rr = 0; rr < 4; ++rr) {
            const int pxl = wv * 16 + lkq * 4 + rr;
            float hr = bhr[nf], hig = bhi[nf], hn = bhn[nf];
            if constexpr (!FIRST) {
                hr += acc[nf][rr];
                hig += acc[nf + 4][rr];
                hn += acc[nf + 8][rr];
            }
            float ir = bf2f(lo[rr][nf]), ii = bf2f(lo[rr][4 + nf]), inn = bf2f(hi[rr][nf]);
            float rg = frcp(1.0f + __expf(-(ir + hr)));
            float ig = frcp(1.0f + __expf(-(ii + hig)));
            float t2 = __expf(2.0f * (inn + rg * hn));
            float nn = 1.0f - 2.0f * frcp(t2 + 1.0f);
            float hp = 0.0f;
            if constexpr (!FIRST) {
                const int offA = (pxl * 128 + g * 2) ^ ((pxl & 7) << 4);
                hp = bf2f(*(const unsigned short*)(smem + offA));
            }
            unsigned short hv = f2bf(nn + ig * (hp - nn));
            hy_p[pxl * 72 + g] = hv;
            hv4[rr] = hv;
        }
        *(usht4*)(hy_cur + (((size_t)(b * 64 + g)) << 14) + yxrow + pxb + wv * 16 + lkq * 4) = hv4;
    }
    __syncthreads();

    // ph4: o-logits via MFMA + 16-lane-group shuffle softmax + bce wave reduce
    f32x4 aco = {};
#pragma unroll
    for (int ih = 0; ih < 2; ++ih) {
        const int pxa = wv * 16 + lrow;
        bf16x8 Ao = *(const bf16x8*)(hy_p + pxa * 72 + ih * 32 + lkq * 8);
        bf16x8 Bo = *(const bf16x8*)(whoBf + ((ih << 9) + lane * 8));
        aco = __builtin_amdgcn_mfma_f32_16x16x32_bf16(Ao, Bo, aco, 0, 0, 0);
    }
    const float bho = (lrow < 9) ? b_ho[lrow] : 0.0f;
    float ov[4];
    float vbce = 0.0f;
    const int yx0 = yxrow + pxb + wv * 16 + lkq * 4;
#pragma unroll
    for (int r = 0; r < 4; ++r) {
        float lg = aco[r] + bho;
        float v = (lrow < 9) ? lg : -1e30f;
        v = fmaxf(v, __shfl_xor(v, 1));
        v = fmaxf(v, __shfl_xor(v, 2));
        v = fmaxf(v, __shfl_xor(v, 4));
        v = fmaxf(v, __shfl_xor(v, 8));
        float e = (lrow < 9) ? __expf(lg - v) : 0.0f;
        float s = e;
        s += __shfl_xor(s, 1);
        s += __shfl_xor(s, 2);
        s += __shfl_xor(s, 4);
        s += __shfl_xor(s, 8);
        ov[r] = e * frcp(s);
    }
    if (lrow < 9) {
        f32x4 wvec = {ov[0], ov[1], ov[2], ov[3]};
        *(f32x4*)(o_out + (((size_t)(b * 9 + lrow)) << 14) + yx0) = wvec;
    }
    if (lrow == 4) {
        const f32x4 mk = *(const f32x4*)(mask + (((size_t)b) << 14) + yx0);
#pragma unroll
        for (int r = 0; r < 4; ++r)
            vbce += mk[r] * __logf(1.0f - ov[r]) + (1.0f - mk[r]) * __logf(ov[r]);
    }
    float v = (lrow == 4) ? vbce : 0.0f;
#pragma unroll
    for (int d = 1; d < 64; d <<= 1) v += __shfl_xor(v, d);
    if (lane == 0) red[wv] = v;
    __syncthreads();
    if (tid == 0) bceP[bid] = red[0] + red[1] + red[2] + red[3];
}

// ------------------------------------------------------------- final merge (h_8 only)
__global__ __launch_bounds__(256, 4) void final_merge(const unsigned short* __restrict__ hyp,
                                                      const float* __restrict__ o_prev,
                                                      float* __restrict__ hidd_out) {
    __shared__ __align__(16) float ostrip[9 * 68];
    const int tid = threadIdx.x;
    const int bid = swz_bid(blockIdx.x);
    const int b = bid >> 8, y = (bid >> 1) & 127, hh2 = bid & 1;
    const int pxb = hh2 * 64, yxrow = y * 128;

    const int c = tid >> 2, pq = tid & 3;
    const int gx0 = pxb + pq * 16;
    const unsigned short* hb = hyp + (((size_t)(b * 64 + c)) << 14);
    ushort8 w8[3][4];
#pragma unroll
    for (int r = 0; r < 3; ++r) {
        const int gyc = min(max(y + r - 1, 0), 127);
        const unsigned short* src = hb + gyc * 128 + gx0 - 8;
#pragma unroll
        for (int q = 0; q < 4; ++q) w8[r][q] = *(const ushort8*)(src + q * 8);
    }
    const float* ob = o_prev + (((size_t)b * 9) << 14);
    for (int e = tid; e < 594; e += 256) {
        const int j = e / 66, s = e - j * 66;
        const int rj = y + 1 - j / 3;
        const int gx = pxb - 1 + s;
        const bool ok = (rj >= 0) && (rj < 128) && (gx >= 0) && (gx < 128);
        ostrip[j * 68 + s] = ok ? ob[(((size_t)j) << 14) + rj * 128 + gx] : 0.0f;
    }
    __syncthreads();

    float a[16];
#pragma unroll
    for (int px = 0; px < 16; ++px) a[px] = 0.0f;
#pragma unroll
    for (int r = 0; r < 3; ++r) {
        float wf[18];
#pragma unroll
        for (int k = 0; k < 18; ++k)
            wf[k] = bf2f((unsigned short)w8[r][(k + 7) >> 3][(k + 7) & 7]);
#pragma unroll
        for (int ex = -1; ex <= 1; ++ex) {
            const int idx = r * 3 + (ex + 1);
            const int j = 8 - idx;
            const float* osj = ostrip + j * 68 + pq * 16 + 1 + ex;
#pragma unroll
            for (int px = 0; px < 16; ++px)
                a[px] = fmaf(wf[px + ex + 1], osj[px], a[px]);
        }
    }
    const size_t hob = (((size_t)(b * 64 + c)) << 14) + yxrow + gx0;
#pragma unroll
    for (int q = 0; q < 4; ++q) {
        f32x4 v = {a[q * 4], a[q * 4 + 1], a[q * 4 + 2], a[q * 4 + 3]};
        *(f32x4*)(hidd_out + hob + q * 4) = v;
    }
}

// ------------------------------------------------------------- deferred diff-loss (+bce) over all t
__global__ __launch_bounds__(256, 4) void loss_kernel(const float* __restrict__ outs,
                                                      const float* __restrict__ bceT,
                                                      float* __restrict__ loss) {
    __shared__ float o4s[3 * 68];
    const int tid = threadIdx.x;
    const int bid = swz_bid(blockIdx.x);
    const int b = bid >> 8, y = (bid >> 1) & 127, hh2 = bid & 1;
    const int pxb = hh2 * 64;
    const int px = tid & 63, tq = tid >> 6;
    const int yx = y * 128 + pxb + px;
    const int i0 = tq, i1 = tq + 4;
    float a0 = 0.0f, a1 = 0.0f, a2 = 0.0f;
    for (int t = 0; t < 8; ++t) {
        const float* ot = outs + (size_t)t * O_SZ + (((size_t)b * 9) << 14);
        __syncthreads();
        for (int e = tid; e < 198; e += 256) {
            const int r = e / 66, s = e - r * 66;
            const int ry = y + r - 1, gx = pxb - 1 + s;
            const bool ok = (ry >= 0) && (ry < 128) && (gx >= 0) && (gx < 128);
            o4s[r * 68 + s] = ok ? ot[(((size_t)4) << 14) + ry * 128 + gx] : 0.0f;
        }
        __syncthreads();
        {
            const float oi = ot[(((size_t)i0) << 14) + yx];
            const float g = o4s[(i0 / 3) * 68 + px + 1 + (i0 % 3 - 1)];
            const float d = g - oi;
            a0 = fmaf(d * d, oi, a0);
        }
        {
            const float oi = ot[(((size_t)i1) << 14) + yx];
            const float g = o4s[(i1 / 3) * 68 + px + 1 + (i1 % 3 - 1)];
            const float d = g - oi;
            a1 = fmaf(d * d, oi, a1);
        }
        if (tq == 0) {
            const float oi = ot[(((size_t)8) << 14) + yx];
            const float g = o4s[2 * 68 + px + 2];
            const float d = g - oi;
            a2 = fmaf(d * d, oi, a2);
        }
    }
    const float bt = *bceT;
    loss[(((size_t)(b * 9 + i0)) << 14) + yx] = a0 * 0.01f + bt;
    loss[(((size_t)(b * 9 + i1)) << 14) + yx] = a1 * 0.01f + bt;
    if (tq == 0) loss[(((size_t)(b * 9 + 8)) << 14) + yx] = a2 * 0.01f + bt;
}

// ------------------------------------------------------------- bce reduce (8192 partials)
__global__ void bce_reduce_kernel(const float* __restrict__ partial, float* __restrict__ out_tot) {
    __shared__ float red[256];
    float s = 0.0f;
    for (int i = threadIdx.x; i < 8192; i += 256) s += partial[i];
    red[threadIdx.x] = s;
    __syncthreads();
    for (int off = 128; off > 0; off >>= 1) {
        if (threadIdx.x < off) red[threadIdx.x] += red[threadIdx.x + off];
        __syncthreads();
    }
    if (threadIdx.x == 0) *out_tot = -red[0] * (1.0f / 65536.0f);
}

// ------------------------------------------------------------- launcher
extern "C" void kernel_launch(void* const* d_in, const int* in_sizes, int n_in,
                              void* d_out, int out_size, void* d_ws, size_t ws_size,
                              hipStream_t stream) {
    const float* x    = (const float*)d_in[0];
    const float* mask = (const float*)d_in[1];
    const float* w_ih = (const float*)d_in[2];
    const float* b_ih = (const float*)d_in[3];
    const float* w_hh = (const float*)d_in[4];
    const float* b_hh = (const float*)d_in[5];
    const float* w_ho = (const float*)d_in[6];
    const float* b_ho = (const float*)d_in[7];
    float* out = (float*)d_out;
    float* ws  = (float*)d_ws;

    unsigned short* iall0 = (unsigned short*)(ws + WS_IALL0);
    unsigned short* iall1 = (unsigned short*)(ws + WS_IALL1);
    unsigned short* xTh   = (unsigned short*)(ws + WS_HYA);   // conv-time only (fits in HYA region)
    unsigned short* hyA   = (unsigned short*)(ws + WS_HYA + 8);   // guarded payload
    unsigned short* hyB   = (unsigned short*)(ws + WS_HYB + 8);
    unsigned short* whhBf = (unsigned short*)(ws + WS_WHH);
    unsigned short* whoBf = (unsigned short*)(ws + WS_WHOB);
    unsigned short* BTf   = (unsigned short*)(ws + WS_BTF);
    float* bceP = ws + WS_BCEP;
    float* bceT = ws + WS_BCET;
    float* lossp = out + LOSS_OFF;

    prep_weights<<<484, 256, 0, stream>>>(w_hh, w_ho, w_ih, whhBf, whoBf, BTf);
    transpose_x<<<256, 256, 0, stream>>>(x, xTh);
    conv_mfma<<<1024, 256, 0, stream>>>(xTh, BTf, b_ih, iall0, iall1);

    step_kernel<true><<<1024, 256, 0, stream>>>(nullptr, nullptr, iall0, iall1, whhBf, b_hh,
                                                whoBf, b_ho, mask, nullptr, hyA,
                                                out + OUTS_OFF, bceP);
    for (int t = 1; t < 8; ++t) {
        const unsigned short* hypr = (t & 1) ? hyA : hyB;
        unsigned short* hyc = (t & 1) ? hyB : hyA;
        step_kernel<false><<<1024, 256, 0, stream>>>(hypr, out + OUTS_OFF + (size_t)(t - 1) * O_SZ,
                                                     iall0, iall1, whhBf, b_hh, whoBf, b_ho, mask,
                                                     out + (size_t)(t - 1) * HID_SZ, hyc,
                                                     out + OUTS_OFF + (size_t)t * O_SZ,
                                                     bceP + t * 1024);
    }
    bce_reduce_kernel<<<1, 256, 0, stream>>>(bceP, bceT);
    final_merge<<<1024, 256, 0, stream>>>(hyB, out + OUTS_OFF + (size_t)7 * O_SZ,
                                          out + (size_t)7 * HID_SZ);
    loss_kernel<<<1024, 256, 0, stream>>>(out + OUTS_OFF, bceT, lossp);
}

// Round 10
// 255.859 us; speedup vs baseline: 3.7069x; 1.0337x over previous
//
#include <hip/hip_runtime.h>

// B=4, C_IN=64, NUM_HIDDEN=64, H=W=128, MOVESQ=9, T=8
#define NP 16384
#define HID_SZ 4194304      // 4*64*NP
#define O_SZ   589824       // 4*9*NP
#define OUTS_OFF 33554432   // 8*HID_SZ
#define LOSS_OFF 38273024   // OUTS_OFF + 8*O_SZ

// ws layout (float units), ~42 MB
#define WS_IALL0 0           // 4,194,304 floats = 8,388,608 ushorts (16B slots)
#define WS_IALL1 4194304     // 2,097,152 floats = 4,194,304 ushorts (8B slots)
#define WS_HYA   6291456     // guard8 + 2,097,152 payload + guard8 (xTh overlaps, conv-time)
#define WS_HYB   8388624     // guard8 + 2,097,152 + guard8
#define WS_WHH   10485792    // 6144 floats (w_hh bf16 fragment order)
#define WS_WHOB  10491936    // 512 floats (w_ho bf16 fragment order)
#define WS_BTF   10492448    // 55,296 floats (w_ih bf16 fragment order)
#define WS_BCEP  10547744    // 8192 floats
#define WS_BCET  10555936    // 1 float (unused now)

typedef __attribute__((ext_vector_type(8))) short bf16x8;
typedef __attribute__((ext_vector_type(8))) unsigned short ushort8;
typedef __attribute__((ext_vector_type(4))) unsigned short usht4;
typedef __attribute__((ext_vector_type(4))) float f32x4;

__device__ __forceinline__ float frcp(float x) { return __builtin_amdgcn_rcpf(x); }
__device__ __forceinline__ unsigned short f2bf(float f) {
    unsigned int u = __float_as_uint(f);
    return (unsigned short)((u + 0x7fffu + ((u >> 16) & 1u)) >> 16);
}
__device__ __forceinline__ float bf2f(unsigned short h) {
    return __uint_as_float(((unsigned int)h) << 16);
}
// XCD-chunked bijective swizzle for 1024-block grids
__device__ __forceinline__ int swz_bid(int bid) { return ((bid & 7) << 7) | (bid >> 3); }

// ------------------------------------------------------------- prep: transpose_x + weight frags
__global__ __launch_bounds__(256) void prep_all(const float* __restrict__ x,
                                                const float* __restrict__ w_hh,
                                                const float* __restrict__ w_ho,
                                                const float* __restrict__ w_ih,
                                                unsigned short* __restrict__ xTh,
                                                unsigned short* __restrict__ whhBf,
                                                unsigned short* __restrict__ whoBf,
                                                unsigned short* __restrict__ BTf) {
    const int tid = threadIdx.x;
    if (blockIdx.x < 256) {
        const int p = blockIdx.x * 256 + tid;
        const int b = p >> 14, yx = p & 16383;
        const size_t base = ((size_t)p) << 6;
        for (int ic0 = 0; ic0 < 64; ic0 += 8) {
            ushort8 vh;
#pragma unroll
            for (int j = 0; j < 8; ++j)
                vh[j] = f2bf(x[(((size_t)(b * 64 + ic0 + j)) << 14) + yx]);
            *(ushort8*)(xTh + base + ic0) = vh;
        }
    } else {
        int i = (blockIdx.x - 256) * 256 + tid;
        if (i < 12288) {                        // whhBf: f=ih*12+n
            int f = i >> 9, r = i & 511;
            int lane = r >> 3, e = r & 7, lrow = lane & 15, lkq = lane >> 4;
            int ih = f / 12, n = f % 12;
            whhBf[i] = f2bf(w_hh[(n * 16 + lrow) * 64 + ih * 32 + lkq * 8 + e]);
        } else if (i < 13312) {                 // whoBf: f=ih
            int j = i - 12288;
            int f = j >> 9, r = j & 511;
            int lane = r >> 3, e = r & 7, lrow = lane & 15, lkq = lane >> 4;
            whoBf[j] = (lrow < 9) ? f2bf(w_ho[lrow * 64 + f * 32 + lkq * 8 + e]) : (unsigned short)0;
        } else if (i < 13312 + 110592) {        // BTf: f=(tap*2+ih)*12+n
            int k2 = i - 13312;
            int f = k2 >> 9, r = k2 & 511;
            int lane = r >> 3, e = r & 7, lrow = lane & 15, lkq = lane >> 4;
            int tapih = f / 12, n = f % 12;
            int tap = tapih >> 1, ih = tapih & 1;
            int oc = n * 16 + lrow, ic = ih * 32 + lkq * 8 + e;
            BTf[k2] = f2bf(w_ih[(oc * 64 + ic) * 9 + tap]);
        }
    }
}

// ------------------------------------------------------------- conv: implicit GEMM (bf16), half-row
__global__ __launch_bounds__(256, 4) void conv_mfma(const unsigned short* __restrict__ xTh,
                                                    const unsigned short* __restrict__ BTf,
                                                    const float* __restrict__ b_ih,
                                                    unsigned short* __restrict__ iall0,
                                                    unsigned short* __restrict__ iall1) {
    __shared__ __align__(16) unsigned char smem[25344];
    const int tid = threadIdx.x;
    const int bid = swz_bid(blockIdx.x);
    const int b = bid >> 8, y = (bid >> 1) & 127, hh2 = bid & 1;

    for (int ch = tid; ch < 1584; ch += 256) {            // 3*66*8 chunks
        const int row = ch / 528;
        const int rem = ch - row * 528;
        const int pxl = rem >> 3, icc = rem & 7;
        const int gy = y + row - 1, gx = hh2 * 64 + pxl - 1;
        ushort8 vh = {};
        if (gy >= 0 && gy < 128 && gx >= 0 && gx < 128) {
            const size_t go = ((size_t)(b * 16384 + gy * 128 + gx)) * 64 + icc * 8;
            vh = *(const ushort8*)(xTh + go);
        }
        const int off = ((row * 66 + pxl) * 128 + icc * 16) ^ ((pxl & 7) << 4);
        *(ushort8*)(smem + off) = vh;
    }
    __syncthreads();

    const int lane = tid & 63, wv = tid >> 6;
    const int lrow = lane & 15, lkq = lane >> 4;
    const unsigned short* BTl = BTf + lane * 8;

    f32x4 acc[12] = {};
#pragma unroll
    for (int tap = 0; tap < 9; ++tap) {
        const int row = tap / 3, dx = tap % 3 - 1;
#pragma unroll
        for (int ih = 0; ih < 2; ++ih) {
            const int pxl = wv * 16 + lrow + dx + 1;
            const int off = ((row * 66 + pxl) * 128 + ih * 64 + lkq * 16) ^ ((pxl & 7) << 4);
            bf16x8 Ah = *(const bf16x8*)(smem + off);
#pragma unroll
            for (int n = 0; n < 12; ++n) {
                bf16x8 Bh = *(const bf16x8*)(BTl + (((tap * 2 + ih) * 12 + n) << 9));
                acc[n] = __builtin_amdgcn_mfma_f32_16x16x32_bf16(Ah, Bh, acc[n], 0, 0, 0);
            }
        }
    }

    float bias[12];
#pragma unroll
    for (int n = 0; n < 12; ++n) bias[n] = b_ih[n * 16 + lrow];
    const size_t rowb = (size_t)((b * 128 + y) * 2 + hh2);
#pragma unroll
    for (int r = 0; r < 4; ++r) {
        ushort8 v0;
        usht4 v1;
#pragma unroll
        for (int n = 0; n < 8; ++n) v0[n] = f2bf(acc[n][r] + bias[n]);
#pragma unroll
        for (int n = 8; n < 12; ++n) v1[n - 8] = f2bf(acc[n][r] + bias[n]);
        *(ushort8*)(iall0 + (rowb << 13) + ((wv * 4 + r) << 9) + lane * 8) = v0;
        *(usht4*)(iall1 + (rowb << 12) + ((wv * 4 + r) << 8) + lane * 4) = v1;
    }
}

// ------------------------------------------------------------- fused step kernel (half-row)
template <bool FIRST>
__global__ __launch_bounds__(256, 4) void step_kernel(const unsigned short* __restrict__ hyp,
                                                      const float* __restrict__ o_prev,
                                                      const unsigned short* __restrict__ iall0,
                                                      const unsigned short* __restrict__ iall1,
                                                      const unsigned short* __restrict__ whhBf,
                                                      const float* __restrict__ b_hh,
                                                      const unsigned short* __restrict__ whoBf,
                                                      const float* __restrict__ b_ho,
                                                      const float* __restrict__ mask,
                                                      float* __restrict__ hidd_out,
                                                      unsigned short* __restrict__ hy_cur,
                                                      float* __restrict__ o_out,
                                                      float* __restrict__ bceP) {
    __shared__ __align__(16) unsigned char smem[19904];
    // [0,8192) A_lds | [8192,10640) ostrip 9x68 f32 | [10656,19872) hy_p 64x72 ush | [19872,+16) red
    float* ostrip = (float*)(smem + 8192);
    unsigned short* hy_p = (unsigned short*)(smem + 10656);
    float* red = (float*)(smem + 19872);

    const int tid = threadIdx.x;
    const int bid = swz_bid(blockIdx.x);
    const int b = bid >> 8, y = (bid >> 1) & 127, hh2 = bid & 1;
    const int pxb = hh2 * 64, yxrow = y * 128;

    if constexpr (!FIRST) {
        // hy windows: thread <-> (channel c, 16-px strip pq)
        const int c = tid >> 2, pq = tid & 3;
        const int gx0 = pxb + pq * 16;
        const unsigned short* hb = hyp + (((size_t)(b * 64 + c)) << 14);
        ushort8 w8[3][4];
#pragma unroll
        for (int r = 0; r < 3; ++r) {
            const int gyc = min(max(y + r - 1, 0), 127);
            const unsigned short* src = hb + gyc * 128 + gx0 - 8;   // guarded buffer
#pragma unroll
            for (int q = 0; q < 4; ++q) w8[r][q] = *(const ushort8*)(src + q * 8);
        }
        // o strips: 9 planes x 66, masked (plane j used at row y+1-j/3, x-shift 1-j%3)
        const float* ob = o_prev + (((size_t)b * 9) << 14);
        for (int e = tid; e < 594; e += 256) {
            const int j = e / 66, s = e - j * 66;
            const int rj = y + 1 - j / 3;
            const int gx = pxb - 1 + s;
            const bool ok = (rj >= 0) && (rj < 128) && (gx >= 0) && (gx < 128);
            ostrip[j * 68 + s] = ok ? ob[(((size_t)j) << 14) + rj * 128 + gx] : 0.0f;
        }
        __syncthreads();

        float a[16];
#pragma unroll
        for (int px = 0; px < 16; ++px) a[px] = 0.0f;
#pragma unroll
        for (int r = 0; r < 3; ++r) {
            float wf[18];   // window positions gx0-1 .. gx0+16
#pragma unroll
            for (int k = 0; k < 18; ++k)
                wf[k] = bf2f((unsigned short)w8[r][(k + 7) >> 3][(k + 7) & 7]);
#pragma unroll
            for (int ex = -1; ex <= 1; ++ex) {
                const int idx = r * 3 + (ex + 1);
                const int j = 8 - idx;
                const float* osj = ostrip + j * 68 + pq * 16 + 1 + ex;
#pragma unroll
                for (int px = 0; px < 16; ++px)
                    a[px] = fmaf(wf[px + ex + 1], osj[px], a[px]);
            }
        }
        const size_t hob = (((size_t)(b * 64 + c)) << 14) + yxrow + gx0;
#pragma unroll
        for (int q = 0; q < 4; ++q) {
            f32x4 v = {a[q * 4], a[q * 4 + 1], a[q * 4 + 2], a[q * 4 + 3]};
            *(f32x4*)(hidd_out + hob + q * 4) = v;
        }
#pragma unroll
        for (int px = 0; px < 16; ++px) {
            const int pxl = pq * 16 + px;
            *(unsigned short*)(smem + ((pxl * 128 + c * 2) ^ ((pxl & 7) << 4))) = f2bf(a[px]);
        }
        __syncthreads();
    }

    const int lane = tid & 63, wv = tid >> 6;
    const int lrow = lane & 15, lkq = lane >> 4;

    f32x4 acc[12] = {};
    if constexpr (!FIRST) {
        bf16x8 Ah[2];
#pragma unroll
        for (int ih = 0; ih < 2; ++ih) {
            const int pxa = wv * 16 + lrow;
            const int off = (pxa * 128 + ih * 64 + lkq * 16) ^ ((pxa & 7) << 4);
            Ah[ih] = *(const bf16x8*)(smem + off);
        }
#pragma unroll
        for (int ih = 0; ih < 2; ++ih)
#pragma unroll
            for (int n = 0; n < 12; ++n) {
                bf16x8 Bh = *(const bf16x8*)(whhBf + (((ih * 12 + n) << 9) + lane * 8));
                acc[n] = __builtin_amdgcn_mfma_f32_16x16x32_bf16(Ah[ih], Bh, acc[n], 0, 0, 0);
            }
    }

    // ph3: gates (exact-packed iall reads, direct hy global stores)
    float bhr[4], bhi[4], bhn[4];
#pragma unroll
    for (int nf = 0; nf < 4; ++nf) {
        bhr[nf] = b_hh[nf * 16 + lrow];
        bhi[nf] = b_hh[64 + nf * 16 + lrow];
        bhn[nf] = b_hh[128 + nf * 16 + lrow];
    }
    const size_t rowb = (size_t)((b * 128 + y) * 2 + hh2);
    const unsigned short* p0 = iall0 + (rowb << 13) + (wv << 11) + lane * 8;
    const unsigned short* p1 = iall1 + (rowb << 12) + (wv << 10) + lane * 4;
    ushort8 lo[4];
    usht4 hi[4];
#pragma unroll
    for (int rr = 0; rr < 4; ++rr) {
        lo[rr] = *(const ushort8*)(p0 + (rr << 9));
        hi[rr] = *(const usht4*)(p1 + (rr << 8));
    }
#pragma unroll
    for (int nf = 0; nf < 4; ++nf) {
        const int g = nf * 16 + lrow;
        usht4 hv4;
#pragma unroll
        for (int rr = 0; rr < 4; ++rr) {
            const int pxl = wv * 16 + lkq * 4 + rr;
            float hr = bhr[nf], hig = bhi[nf], hn = bhn[nf];
            if constexpr (!FIRST) {
                hr += acc[nf][rr];
                hig += acc[nf + 4][rr];
                hn += acc[nf + 8][rr];
            }
            float ir = bf2f(lo[rr][nf]), ii = bf2f(lo[rr][4 + nf]), inn = bf2f(hi[rr][nf]);
            float rg = frcp(1.0f + __expf(-(ir + hr)));
            float ig = frcp(1.0f + __expf(-(ii + hig)));
            float t2 = __expf(2.0f * (inn + rg * hn));
            float nn = 1.0f - 2.0f * frcp(t2 + 1.0f);
            float hp = 0.0f;
            if constexpr (!FIRST) {
                const int offA = (pxl * 128 + g * 2) ^ ((pxl & 7) << 4);
                hp = bf2f(*(const unsigned short*)(smem + offA));
            }
            unsigned short hv = f2bf(nn + ig * (hp - nn));
            hy_p[pxl * 72 + g] = hv;
            hv4[rr] = hv;
        }
        *(usht4*)(hy_cur + (((size_t)(b * 64 + g)) << 14) + yxrow + pxb + wv * 16 + lkq * 4) = hv4;
    }
    __syncthreads();

    // ph4: o-logits via MFMA + 16-lane-group shuffle softmax + bce wave reduce
    f32x4 aco = {};
#pragma unroll
    for (int ih = 0; ih < 2; ++ih) {
        const int pxa = wv * 16 + lrow;
        bf16x8 Ao = *(const bf16x8*)(hy_p + pxa * 72 + ih * 32 + lkq * 8);
        bf16x8 Bo = *(const bf16x8*)(whoBf + ((ih << 9) + lane * 8));
        aco = __builtin_amdgcn_mfma_f32_16x16x32_bf16(Ao, Bo, aco, 0, 0, 0);
    }
    const float bho = (lrow < 9) ? b_ho[lrow] : 0.0f;
    float ov[4];
    float vbce = 0.0f;
    const int yx0 = yxrow + pxb + wv * 16 + lkq * 4;
#pragma unroll
    for (int r = 0; r < 4; ++r) {
        float lg = aco[r] + bho;
        float v = (lrow < 9) ? lg : -1e30f;
        v = fmaxf(v, __shfl_xor(v, 1));
        v = fmaxf(v, __shfl_xor(v, 2));
        v = fmaxf(v, __shfl_xor(v, 4));
        v = fmaxf(v, __shfl_xor(v, 8));
        float e = (lrow < 9) ? __expf(lg - v) : 0.0f;
        float s = e;
        s += __shfl_xor(s, 1);
        s += __shfl_xor(s, 2);
        s += __shfl_xor(s, 4);
        s += __shfl_xor(s, 8);
        ov[r] = e * frcp(s);
    }
    if (lrow < 9) {
        f32x4 wvec = {ov[0], ov[1], ov[2], ov[3]};
        *(f32x4*)(o_out + (((size_t)(b * 9 + lrow)) << 14) + yx0) = wvec;
    }
    if (lrow == 4) {
        const f32x4 mk = *(const f32x4*)(mask + (((size_t)b) << 14) + yx0);
#pragma unroll
        for (int r = 0; r < 4; ++r)
            vbce += mk[r] * __logf(1.0f - ov[r]) + (1.0f - mk[r]) * __logf(ov[r]);
    }
    float v = (lrow == 4) ? vbce : 0.0f;
#pragma unroll
    for (int d = 1; d < 64; d <<= 1) v += __shfl_xor(v, d);
    if (lane == 0) red[wv] = v;
    __syncthreads();
    if (tid == 0) bceP[bid] = red[0] + red[1] + red[2] + red[3];
}

// ------------------------------------------------------------- final: bce total + merge h_8 + loss
__global__ __launch_bounds__(256) void final_fused(const unsigned short* __restrict__ hyp,
                                                   const float* __restrict__ o_all,
                                                   const float* __restrict__ bceP,
                                                   float* __restrict__ hidd7,
                                                   float* __restrict__ loss) {
    __shared__ __align__(16) float ostrip[9 * 68];
    __shared__ float o4s[3 * 68];
    __shared__ float redsh[256];
    const int tid = threadIdx.x;
    const int bid = swz_bid(blockIdx.x);
    const int b = bid >> 8, y = (bid >> 1) & 127, hh2 = bid & 1;
    const int pxb = hh2 * 64, yxrow = y * 128;

    // bce total (per-block redundant reduce of 8192 partials)
    float s = 0.0f;
    for (int i = tid; i < 8192; i += 256) s += bceP[i];
    redsh[tid] = s;
    __syncthreads();
    for (int off = 128; off > 0; off >>= 1) {
        if (tid < off) redsh[tid] += redsh[tid + off];
        __syncthreads();
    }
    const float bt = -redsh[0] * (1.0f / 65536.0f);

    // merge h_8 from hy_7, o_7
    {
        const int c = tid >> 2, pq = tid & 3;
        const int gx0 = pxb + pq * 16;
        const float* ob = o_all + (size_t)7 * O_SZ + (((size_t)b * 9) << 14);
        for (int e = tid; e < 594; e += 256) {
            const int j = e / 66, ss = e - j * 66;
            const int rj = y + 1 - j / 3;
            const int gx = pxb - 1 + ss;
            const bool ok = (rj >= 0) && (rj < 128) && (gx >= 0) && (gx < 128);
            ostrip[j * 68 + ss] = ok ? ob[(((size_t)j) << 14) + rj * 128 + gx] : 0.0f;
        }
        __syncthreads();
        const unsigned short* hb = hyp + (((size_t)(b * 64 + c)) << 14);
        float a[16];
#pragma unroll
        for (int px = 0; px < 16; ++px) a[px] = 0.0f;
#pragma unroll
        for (int r = 0; r < 3; ++r) {
            const int gyc = min(max(y + r - 1, 0), 127);
            const unsigned short* src = hb + gyc * 128 + gx0 - 8;
            ushort8 w8[4];
#pragma unroll
            for (int q = 0; q < 4; ++q) w8[q] = *(const ushort8*)(src + q * 8);
            float wf[18];
#pragma unroll
            for (int k = 0; k < 18; ++k)
                wf[k] = bf2f((unsigned short)w8[(k + 7) >> 3][(k + 7) & 7]);
#pragma unroll
            for (int ex = -1; ex <= 1; ++ex) {
                const int j = 8 - (r * 3 + (ex + 1));
                const float* osj = ostrip + j * 68 + pq * 16 + 1 + ex;
#pragma unroll
                for (int px = 0; px < 16; ++px)
                    a[px] = fmaf(wf[px + ex + 1], osj[px], a[px]);
            }
        }
        const size_t hob = (((size_t)(b * 64 + c)) << 14) + yxrow + gx0;
#pragma unroll
        for (int q = 0; q < 4; ++q) {
            f32x4 v = {a[q * 4], a[q * 4 + 1], a[q * 4 + 2], a[q * 4 + 3]};
            *(f32x4*)(hidd7 + hob + q * 4) = v;
        }
    }

    // deferred diff-loss over all t
    const int px = tid & 63, tq = tid >> 6;
    const int yx = yxrow + pxb + px;
    const int i0 = tq, i1 = tq + 4;
    float a0 = 0.0f, a1 = 0.0f, a2 = 0.0f;
    for (int t = 0; t < 8; ++t) {
        const float* ot = o_all + (size_t)t * O_SZ + (((size_t)b * 9) << 14);
        __syncthreads();
        for (int e = tid; e < 198; e += 256) {
            const int r = e / 66, ss = e - r * 66;
            const int ry = y + r - 1, gx = pxb - 1 + ss;
            const bool ok = (ry >= 0) && (ry < 128) && (gx >= 0) && (gx < 128);
            o4s[r * 68 + ss] = ok ? ot[(((size_t)4) << 14) + ry * 128 + gx] : 0.0f;
        }
        __syncthreads();
        {
            const float oi = ot[(((size_t)i0) << 14) + yx];
            const float g = o4s[(i0 / 3) * 68 + px + 1 + (i0 % 3 - 1)];
            const float d = g - oi;
            a0 = fmaf(d * d, oi, a0);
        }
        {
            const float oi = ot[(((size_t)i1) << 14) + yx];
            const float g = o4s[(i1 / 3) * 68 + px + 1 + (i1 % 3 - 1)];
            const float d = g - oi;
            a1 = fmaf(d * d, oi, a1);
        }
        if (tq == 0) {
            const float oi = ot[(((size_t)8) << 14) + yx];
            const float g = o4s[2 * 68 + px + 2];
            const float d = g - oi;
            a2 = fmaf(d * d, oi, a2);
        }
    }
    loss[(((size_t)(b * 9 + i0)) << 14) + yx] = a0 * 0.01f + bt;
    loss[(((size_t)(b * 9 + i1)) << 14) + yx] = a1 * 0.01f + bt;
    if (tq == 0) loss[(((size_t)(b * 9 + 8)) << 14) + yx] = a2 * 0.01f + bt;
}

// ------------------------------------------------------------- launcher
extern "C" void kernel_launch(void* const* d_in, const int* in_sizes, int n_in,
                              void* d_out, int out_size, void* d_ws, size_t ws_size,
                              hipStream_t stream) {
    const float* x    = (const float*)d_in[0];
    const float* mask = (const float*)d_in[1];
    const float* w_ih = (const float*)d_in[2];
    const float* b_ih = (const float*)d_in[3];
    const float* w_hh = (const float*)d_in[4];
    const float* b_hh = (const float*)d_in[5];
    const float* w_ho = (const float*)d_in[6];
    const float* b_ho = (const float*)d_in[7];
    float* out = (float*)d_out;
    float* ws  = (float*)d_ws;

    unsigned short* iall0 = (unsigned short*)(ws + WS_IALL0);
    unsigned short* iall1 = (unsigned short*)(ws + WS_IALL1);
    unsigned short* xTh   = (unsigned short*)(ws + WS_HYA);       // conv-time only
    unsigned short* hyA   = (unsigned short*)(ws + WS_HYA + 8);   // guarded payload
    unsigned short* hyB   = (unsigned short*)(ws + WS_HYB + 8);
    unsigned short* whhBf = (unsigned short*)(ws + WS_WHH);
    unsigned short* whoBf = (unsigned short*)(ws + WS_WHOB);
    unsigned short* BTf   = (unsigned short*)(ws + WS_BTF);
    float* bceP = ws + WS_BCEP;
    float* lossp = out + LOSS_OFF;

    prep_all<<<740, 256, 0, stream>>>(x, w_hh, w_ho, w_ih, xTh, whhBf, whoBf, BTf);
    conv_mfma<<<1024, 256, 0, stream>>>(xTh, BTf, b_ih, iall0, iall1);

    step_kernel<true><<<1024, 256, 0, stream>>>(nullptr, nullptr, iall0, iall1, whhBf, b_hh,
                                                whoBf, b_ho, mask, nullptr, hyA,
                                                out + OUTS_OFF, bceP);
    for (int t = 1; t < 8; ++t) {
        const unsigned short* hypr = (t & 1) ? hyA : hyB;
        unsigned short* hyc = (t & 1) ? hyB : hyA;
        step_kernel<false><<<1024, 256, 0, stream>>>(hypr, out + OUTS_OFF + (size_t)(t - 1) * O_SZ,
                                                     iall0, iall1, whhBf, b_hh, whoBf, b_ho, mask,
                                                     out + (size_t)(t - 1) * HID_SZ, hyc,
                                                     out + OUTS_OFF + (size_t)t * O_SZ,
                                                     bceP + t * 1024);
    }
    final_fused<<<1024, 256, 0, stream>>>(hyB, out + OUTS_OFF, bceP,
                                          out + (size_t)7 * HID_SZ, lossp);
}

// Round 11
// 225.571 us; speedup vs baseline: 4.2047x; 1.1343x over previous
//
#include <hip/hip_runtime.h>

// B=4, C_IN=64, NUM_HIDDEN=64, H=W=128, MOVESQ=9, T=8
#define NP 16384
#define HID_SZ 4194304      // 4*64*NP
#define O_SZ   589824       // 4*9*NP
#define OUTS_OFF 33554432   // 8*HID_SZ
#define LOSS_OFF 38273024   // OUTS_OFF + 8*O_SZ

// ws layout (float units), ~50.6 MB
#define WS_IALL0 0           // 4,194,304 floats = 8,388,608 ushorts (16B slots)
#define WS_IALL1 4194304     // 2,097,152 floats = 4,194,304 ushorts (8B slots)
#define WS_XTH   6291456     // 2,097,152 floats = 4,194,304 ushorts (x channel-last bf16)
#define WS_HYA   8388608     // guard8 + 4,194,304 ushorts + guard8
#define WS_HYB   10485776    // guard8 + 4,194,304 ushorts + guard8
#define WS_WHH   12582944    // 6144 floats (w_hh bf16 fragment order)
#define WS_WHOB  12589088    // 512 floats (w_ho bf16 fragment order)
#define WS_BTF   12589600    // 55,296 floats (w_ih bf16 fragment order)
#define WS_BCEP  12644896    // 8192 floats

typedef __attribute__((ext_vector_type(8))) short bf16x8;
typedef __attribute__((ext_vector_type(8))) unsigned short ushort8;
typedef __attribute__((ext_vector_type(4))) unsigned short usht4;
typedef __attribute__((ext_vector_type(4))) float f32x4;

__device__ __forceinline__ float frcp(float x) { return __builtin_amdgcn_rcpf(x); }
__device__ __forceinline__ unsigned short f2bf(float f) {
    unsigned int u = __float_as_uint(f);
    return (unsigned short)((u + 0x7fffu + ((u >> 16) & 1u)) >> 16);
}
__device__ __forceinline__ float bf2f(unsigned short h) {
    return __uint_as_float(((unsigned int)h) << 16);
}
// XCD-chunked bijective swizzle for 1024-block grids
__device__ __forceinline__ int swz_bid(int bid) { return ((bid & 7) << 7) | (bid >> 3); }

// ------------------------------------------------------------- prep: transpose_x + weight frags
__global__ __launch_bounds__(256) void prep_all(const float* __restrict__ x,
                                                const float* __restrict__ w_hh,
                                                const float* __restrict__ w_ho,
                                                const float* __restrict__ w_ih,
                                                unsigned short* __restrict__ xTh,
                                                unsigned short* __restrict__ whhBf,
                                                unsigned short* __restrict__ whoBf,
                                                unsigned short* __restrict__ BTf) {
    const int tid = threadIdx.x;
    if (blockIdx.x < 256) {
        const int p = blockIdx.x * 256 + tid;
        const int b = p >> 14, yx = p & 16383;
        const size_t base = ((size_t)p) << 6;
        for (int ic0 = 0; ic0 < 64; ic0 += 8) {
            ushort8 vh;
#pragma unroll
            for (int j = 0; j < 8; ++j)
                vh[j] = f2bf(x[(((size_t)(b * 64 + ic0 + j)) << 14) + yx]);
            *(ushort8*)(xTh + base + ic0) = vh;
        }
    } else {
        int i = (blockIdx.x - 256) * 256 + tid;
        if (i < 12288) {                        // whhBf: f=ih*12+n
            int f = i >> 9, r = i & 511;
            int lane = r >> 3, e = r & 7, lrow = lane & 15, lkq = lane >> 4;
            int ih = f / 12, n = f % 12;
            whhBf[i] = f2bf(w_hh[(n * 16 + lrow) * 64 + ih * 32 + lkq * 8 + e]);
        } else if (i < 13312) {                 // whoBf: f=ih
            int j = i - 12288;
            int f = j >> 9, r = j & 511;
            int lane = r >> 3, e = r & 7, lrow = lane & 15, lkq = lane >> 4;
            whoBf[j] = (lrow < 9) ? f2bf(w_ho[lrow * 64 + f * 32 + lkq * 8 + e]) : (unsigned short)0;
        } else if (i < 13312 + 110592) {        // BTf: f=(tap*2+ih)*12+n
            int k2 = i - 13312;
            int f = k2 >> 9, r = k2 & 511;
            int lane = r >> 3, e = r & 7, lrow = lane & 15, lkq = lane >> 4;
            int tapih = f / 12, n = f % 12;
            int tap = tapih >> 1, ih = tapih & 1;
            int oc = n * 16 + lrow, ic = ih * 32 + lkq * 8 + e;
            BTf[k2] = f2bf(w_ih[(oc * 64 + ic) * 9 + tap]);
        }
    }
}

// ------------------------------------------------------------- conv + step0 fused
// conv implicit-GEMM; epilogue keeps bf16 gate inputs in regs, writes iall (for t>=1),
// then gates(t=0) -> hy_0 + o_0 softmax + bce partial. No cross-block dep (h_0 = 0).
__global__ __launch_bounds__(256, 4) void conv_step0(const unsigned short* __restrict__ xTh,
                                                     const unsigned short* __restrict__ BTf,
                                                     const float* __restrict__ b_ih,
                                                     const float* __restrict__ b_hh,
                                                     const unsigned short* __restrict__ whoBf,
                                                     const float* __restrict__ b_ho,
                                                     const float* __restrict__ mask,
                                                     unsigned short* __restrict__ iall0,
                                                     unsigned short* __restrict__ iall1,
                                                     unsigned short* __restrict__ hy_cur,
                                                     float* __restrict__ o_out,
                                                     float* __restrict__ bceP) {
    __shared__ __align__(16) unsigned char smem[25344];
    unsigned short* hy_p = (unsigned short*)(smem + 10656);
    float* red = (float*)(smem + 19872);
    const int tid = threadIdx.x;
    const int bid = swz_bid(blockIdx.x);
    const int b = bid >> 8, y = (bid >> 1) & 127, hh2 = bid & 1;
    const int pxb = hh2 * 64, yxrow = y * 128;

    for (int ch = tid; ch < 1584; ch += 256) {            // 3*66*8 chunks
        const int row = ch / 528;
        const int rem = ch - row * 528;
        const int pxl = rem >> 3, icc = rem & 7;
        const int gy = y + row - 1, gx = pxb + pxl - 1;
        ushort8 vh = {};
        if (gy >= 0 && gy < 128 && gx >= 0 && gx < 128) {
            const size_t go = ((size_t)(b * 16384 + gy * 128 + gx)) * 64 + icc * 8;
            vh = *(const ushort8*)(xTh + go);
        }
        const int off = ((row * 66 + pxl) * 128 + icc * 16) ^ ((pxl & 7) << 4);
        *(ushort8*)(smem + off) = vh;
    }
    __syncthreads();

    const int lane = tid & 63, wv = tid >> 6;
    const int lrow = lane & 15, lkq = lane >> 4;
    const unsigned short* BTl = BTf + lane * 8;

    f32x4 acc[12] = {};
#pragma unroll
    for (int tap = 0; tap < 9; ++tap) {
        const int row = tap / 3, dx = tap % 3 - 1;
#pragma unroll
        for (int ih = 0; ih < 2; ++ih) {
            const int pxl = wv * 16 + lrow + dx + 1;
            const int off = ((row * 66 + pxl) * 128 + ih * 64 + lkq * 16) ^ ((pxl & 7) << 4);
            bf16x8 Ah = *(const bf16x8*)(smem + off);
#pragma unroll
            for (int n = 0; n < 12; ++n) {
                bf16x8 Bh = *(const bf16x8*)(BTl + (((tap * 2 + ih) * 12 + n) << 9));
                acc[n] = __builtin_amdgcn_mfma_f32_16x16x32_bf16(Ah, Bh, acc[n], 0, 0, 0);
            }
        }
    }

    float bias[12];
#pragma unroll
    for (int n = 0; n < 12; ++n) bias[n] = b_ih[n * 16 + lrow];
    const size_t rowb = (size_t)((b * 128 + y) * 2 + hh2);
    ushort8 v0[4];
    usht4 v1[4];
#pragma unroll
    for (int r = 0; r < 4; ++r) {
#pragma unroll
        for (int n = 0; n < 8; ++n) v0[r][n] = f2bf(acc[n][r] + bias[n]);
#pragma unroll
        for (int n = 8; n < 12; ++n) v1[r][n - 8] = f2bf(acc[n][r] + bias[n]);
        *(ushort8*)(iall0 + (rowb << 13) + ((wv * 4 + r) << 9) + lane * 8) = v0[r];
        *(usht4*)(iall1 + (rowb << 12) + ((wv * 4 + r) << 8) + lane * 4) = v1[r];
    }
    __syncthreads();   // all x-tile reads complete before hy_p overlaps the region

    // gates (t=0, h_prev = 0), inputs = bf16-rounded v0/v1 (identical to old iall path)
    float bhr[4], bhi[4], bhn[4];
#pragma unroll
    for (int nf = 0; nf < 4; ++nf) {
        bhr[nf] = b_hh[nf * 16 + lrow];
        bhi[nf] = b_hh[64 + nf * 16 + lrow];
        bhn[nf] = b_hh[128 + nf * 16 + lrow];
    }
#pragma unroll
    for (int nf = 0; nf < 4; ++nf) {
        const int g = nf * 16 + lrow;
        usht4 hv4;
#pragma unroll
        for (int rr = 0; rr < 4; ++rr) {
            const int pxl = wv * 16 + lkq * 4 + rr;
            float ir = bf2f(v0[rr][nf]), ii = bf2f(v0[rr][4 + nf]), inn = bf2f(v1[rr][nf]);
            float rg = frcp(1.0f + __expf(-(ir + bhr[nf])));
            float ig = frcp(1.0f + __expf(-(ii + bhi[nf])));
            float t2 = __expf(2.0f * (inn + rg * bhn[nf]));
            float nn = 1.0f - 2.0f * frcp(t2 + 1.0f);
            unsigned short hv = f2bf(nn + ig * (0.0f - nn));
            hy_p[pxl * 72 + g] = hv;
            hv4[rr] = hv;
        }
        *(usht4*)(hy_cur + (((size_t)(b * 64 + g)) << 14) + yxrow + pxb + wv * 16 + lkq * 4) = hv4;
    }
    __syncthreads();

    // o-logits via MFMA + 16-lane-group shuffle softmax + bce wave reduce
    f32x4 aco = {};
#pragma unroll
    for (int ih = 0; ih < 2; ++ih) {
        const int pxa = wv * 16 + lrow;
        bf16x8 Ao = *(const bf16x8*)(hy_p + pxa * 72 + ih * 32 + lkq * 8);
        bf16x8 Bo = *(const bf16x8*)(whoBf + ((ih << 9) + lane * 8));
        aco = __builtin_amdgcn_mfma_f32_16x16x32_bf16(Ao, Bo, aco, 0, 0, 0);
    }
    const float bho = (lrow < 9) ? b_ho[lrow] : 0.0f;
    float ov[4];
    float vbce = 0.0f;
    const int yx0 = yxrow + pxb + wv * 16 + lkq * 4;
#pragma unroll
    for (int r = 0; r < 4; ++r) {
        float lg = aco[r] + bho;
        float v = (lrow < 9) ? lg : -1e30f;
        v = fmaxf(v, __shfl_xor(v, 1));
        v = fmaxf(v, __shfl_xor(v, 2));
        v = fmaxf(v, __shfl_xor(v, 4));
        v = fmaxf(v, __shfl_xor(v, 8));
        float e = (lrow < 9) ? __expf(lg - v) : 0.0f;
        float s = e;
        s += __shfl_xor(s, 1);
        s += __shfl_xor(s, 2);
        s += __shfl_xor(s, 4);
        s += __shfl_xor(s, 8);
        ov[r] = e * frcp(s);
    }
    if (lrow < 9) {
        f32x4 wvec = {ov[0], ov[1], ov[2], ov[3]};
        *(f32x4*)(o_out + (((size_t)(b * 9 + lrow)) << 14) + yx0) = wvec;
    }
    if (lrow == 4) {
        const f32x4 mk = *(const f32x4*)(mask + (((size_t)b) << 14) + yx0);
#pragma unroll
        for (int r = 0; r < 4; ++r)
            vbce += mk[r] * __logf(1.0f - ov[r]) + (1.0f - mk[r]) * __logf(ov[r]);
    }
    float v = (lrow == 4) ? vbce : 0.0f;
#pragma unroll
    for (int d = 1; d < 64; d <<= 1) v += __shfl_xor(v, d);
    if (lane == 0) red[wv] = v;
    __syncthreads();
    if (tid == 0) bceP[bid] = red[0] + red[1] + red[2] + red[3];
}

// ------------------------------------------------------------- fused step kernel (t>=1, half-row)
__global__ __launch_bounds__(256, 4) void step_kernel(const unsigned short* __restrict__ hyp,
                                                      const float* __restrict__ o_prev,
                                                      const unsigned short* __restrict__ iall0,
                                                      const unsigned short* __restrict__ iall1,
                                                      const unsigned short* __restrict__ whhBf,
                                                      const float* __restrict__ b_hh,
                                                      const unsigned short* __restrict__ whoBf,
                                                      const float* __restrict__ b_ho,
                                                      const float* __restrict__ mask,
                                                      float* __restrict__ hidd_out,
                                                      unsigned short* __restrict__ hy_cur,
                                                      float* __restrict__ o_out,
                                                      float* __restrict__ bceP) {
    __shared__ __align__(16) unsigned char smem[19904];
    float* ostrip = (float*)(smem + 8192);
    unsigned short* hy_p = (unsigned short*)(smem + 10656);
    float* red = (float*)(smem + 19872);

    const int tid = threadIdx.x;
    const int bid = swz_bid(blockIdx.x);
    const int b = bid >> 8, y = (bid >> 1) & 127, hh2 = bid & 1;
    const int pxb = hh2 * 64, yxrow = y * 128;

    {
        const int c = tid >> 2, pq = tid & 3;
        const int gx0 = pxb + pq * 16;
        const unsigned short* hb = hyp + (((size_t)(b * 64 + c)) << 14);
        ushort8 w8[3][4];
#pragma unroll
        for (int r = 0; r < 3; ++r) {
            const int gyc = min(max(y + r - 1, 0), 127);
            const unsigned short* src = hb + gyc * 128 + gx0 - 8;   // guarded buffer
#pragma unroll
            for (int q = 0; q < 4; ++q) w8[r][q] = *(const ushort8*)(src + q * 8);
        }
        const float* ob = o_prev + (((size_t)b * 9) << 14);
        for (int e = tid; e < 594; e += 256) {
            const int j = e / 66, s = e - j * 66;
            const int rj = y + 1 - j / 3;
            const int gx = pxb - 1 + s;
            const bool ok = (rj >= 0) && (rj < 128) && (gx >= 0) && (gx < 128);
            ostrip[j * 68 + s] = ok ? ob[(((size_t)j) << 14) + rj * 128 + gx] : 0.0f;
        }
        __syncthreads();

        float a[16];
#pragma unroll
        for (int px = 0; px < 16; ++px) a[px] = 0.0f;
#pragma unroll
        for (int r = 0; r < 3; ++r) {
            float wf[18];
#pragma unroll
            for (int k = 0; k < 18; ++k)
                wf[k] = bf2f((unsigned short)w8[r][(k + 7) >> 3][(k + 7) & 7]);
#pragma unroll
            for (int ex = -1; ex <= 1; ++ex) {
                const int idx = r * 3 + (ex + 1);
                const int j = 8 - idx;
                const float* osj = ostrip + j * 68 + pq * 16 + 1 + ex;
#pragma unroll
                for (int px = 0; px < 16; ++px)
                    a[px] = fmaf(wf[px + ex + 1], osj[px], a[px]);
            }
        }
        const size_t hob = (((size_t)(b * 64 + c)) << 14) + yxrow + gx0;
#pragma unroll
        for (int q = 0; q < 4; ++q) {
            f32x4 v = {a[q * 4], a[q * 4 + 1], a[q * 4 + 2], a[q * 4 + 3]};
            *(f32x4*)(hidd_out + hob + q * 4) = v;
        }
#pragma unroll
        for (int px = 0; px < 16; ++px) {
            const int pxl = pq * 16 + px;
            *(unsigned short*)(smem + ((pxl * 128 + c * 2) ^ ((pxl & 7) << 4))) = f2bf(a[px]);
        }
        __syncthreads();
    }

    const int lane = tid & 63, wv = tid >> 6;
    const int lrow = lane & 15, lkq = lane >> 4;

    f32x4 acc[12] = {};
    {
        bf16x8 Ah[2];
#pragma unroll
        for (int ih = 0; ih < 2; ++ih) {
            const int pxa = wv * 16 + lrow;
            const int off = (pxa * 128 + ih * 64 + lkq * 16) ^ ((pxa & 7) << 4);
            Ah[ih] = *(const bf16x8*)(smem + off);
        }
#pragma unroll
        for (int ih = 0; ih < 2; ++ih)
#pragma unroll
            for (int n = 0; n < 12; ++n) {
                bf16x8 Bh = *(const bf16x8*)(whhBf + (((ih * 12 + n) << 9) + lane * 8));
                acc[n] = __builtin_amdgcn_mfma_f32_16x16x32_bf16(Ah[ih], Bh, acc[n], 0, 0, 0);
            }
    }

    // gates
    float bhr[4], bhi[4], bhn[4];
#pragma unroll
    for (int nf = 0; nf < 4; ++nf) {
        bhr[nf] = b_hh[nf * 16 + lrow];
        bhi[nf] = b_hh[64 + nf * 16 + lrow];
        bhn[nf] = b_hh[128 + nf * 16 + lrow];
    }
    const size_t rowb = (size_t)((b * 128 + y) * 2 + hh2);
    const unsigned short* p0 = iall0 + (rowb << 13) + (wv << 11) + lane * 8;
    const unsigned short* p1 = iall1 + (rowb << 12) + (wv << 10) + lane * 4;
    ushort8 lo[4];
    usht4 hi[4];
#pragma unroll
    for (int rr = 0; rr < 4; ++rr) {
        lo[rr] = *(const ushort8*)(p0 + (rr << 9));
        hi[rr] = *(const usht4*)(p1 + (rr << 8));
    }
#pragma unroll
    for (int nf = 0; nf < 4; ++nf) {
        const int g = nf * 16 + lrow;
        usht4 hv4;
#pragma unroll
        for (int rr = 0; rr < 4; ++rr) {
            const int pxl = wv * 16 + lkq * 4 + rr;
            float hr = bhr[nf] + acc[nf][rr];
            float hig = bhi[nf] + acc[nf + 4][rr];
            float hn = bhn[nf] + acc[nf + 8][rr];
            float ir = bf2f(lo[rr][nf]), ii = bf2f(lo[rr][4 + nf]), inn = bf2f(hi[rr][nf]);
            float rg = frcp(1.0f + __expf(-(ir + hr)));
            float ig = frcp(1.0f + __expf(-(ii + hig)));
            float t2 = __expf(2.0f * (inn + rg * hn));
            float nn = 1.0f - 2.0f * frcp(t2 + 1.0f);
            const int offA = (pxl * 128 + g * 2) ^ ((pxl & 7) << 4);
            float hp = bf2f(*(const unsigned short*)(smem + offA));
            unsigned short hv = f2bf(nn + ig * (hp - nn));
            hy_p[pxl * 72 + g] = hv;
            hv4[rr] = hv;
        }
        *(usht4*)(hy_cur + (((size_t)(b * 64 + g)) << 14) + yxrow + pxb + wv * 16 + lkq * 4) = hv4;
    }
    __syncthreads();

    // o-logits via MFMA + shuffle softmax + bce
    f32x4 aco = {};
#pragma unroll
    for (int ih = 0; ih < 2; ++ih) {
        const int pxa = wv * 16 + lrow;
        bf16x8 Ao = *(const bf16x8*)(hy_p + pxa * 72 + ih * 32 + lkq * 8);
        bf16x8 Bo = *(const bf16x8*)(whoBf + ((ih << 9) + lane * 8));
        aco = __builtin_amdgcn_mfma_f32_16x16x32_bf16(Ao, Bo, aco, 0, 0, 0);
    }
    const float bho = (lrow < 9) ? b_ho[lrow] : 0.0f;
    float ov[4];
    float vbce = 0.0f;
    const int yx0 = yxrow + pxb + wv * 16 + lkq * 4;
#pragma unroll
    for (int r = 0; r < 4; ++r) {
        float lg = aco[r] + bho;
        float v = (lrow < 9) ? lg : -1e30f;
        v = fmaxf(v, __shfl_xor(v, 1));
        v = fmaxf(v, __shfl_xor(v, 2));
        v = fmaxf(v, __shfl_xor(v, 4));
        v = fmaxf(v, __shfl_xor(v, 8));
        float e = (lrow < 9) ? __expf(lg - v) : 0.0f;
        float s = e;
        s += __shfl_xor(s, 1);
        s += __shfl_xor(s, 2);
        s += __shfl_xor(s, 4);
        s += __shfl_xor(s, 8);
        ov[r] = e * frcp(s);
    }
    if (lrow < 9) {
        f32x4 wvec = {ov[0], ov[1], ov[2], ov[3]};
        *(f32x4*)(o_out + (((size_t)(b * 9 + lrow)) << 14) + yx0) = wvec;
    }
    if (lrow == 4) {
        const f32x4 mk = *(const f32x4*)(mask + (((size_t)b) << 14) + yx0);
#pragma unroll
        for (int r = 0; r < 4; ++r)
            vbce += mk[r] * __logf(1.0f - ov[r]) + (1.0f - mk[r]) * __logf(ov[r]);
    }
    float v = (lrow == 4) ? vbce : 0.0f;
#pragma unroll
    for (int d = 1; d < 64; d <<= 1) v += __shfl_xor(v, d);
    if (lane == 0) red[wv] = v;
    __syncthreads();
    if (tid == 0) bceP[bid] = red[0] + red[1] + red[2] + red[3];
}

// ------------------------------------------------------------- final: bce total + merge h_8 + loss
__global__ __launch_bounds__(256) void final_fused(const unsigned short* __restrict__ hyp,
                                                   const float* __restrict__ o_all,
                                                   const float* __restrict__ bceP,
                                                   float* __restrict__ hidd7,
                                                   float* __restrict__ loss) {
    __shared__ __align__(16) float ostrip[9 * 68];
    __shared__ float o4s[3 * 68];
    __shared__ float redsh[256];
    const int tid = threadIdx.x;
    const int bid = swz_bid(blockIdx.x);
    const int b = bid >> 8, y = (bid >> 1) & 127, hh2 = bid & 1;
    const int pxb = hh2 * 64, yxrow = y * 128;

    float s = 0.0f;
    for (int i = tid; i < 8192; i += 256) s += bceP[i];
    redsh[tid] = s;
    __syncthreads();
    for (int off = 128; off > 0; off >>= 1) {
        if (tid < off) redsh[tid] += redsh[tid + off];
        __syncthreads();
    }
    const float bt = -redsh[0] * (1.0f / 65536.0f);

    {
        const int c = tid >> 2, pq = tid & 3;
        const int gx0 = pxb + pq * 16;
        const float* ob = o_all + (size_t)7 * O_SZ + (((size_t)b * 9) << 14);
        for (int e = tid; e < 594; e += 256) {
            const int j = e / 66, ss = e - j * 66;
            const int rj = y + 1 - j / 3;
            const int gx = pxb - 1 + ss;
            const bool ok = (rj >= 0) && (rj < 128) && (gx >= 0) && (gx < 128);
            ostrip[j * 68 + ss] = ok ? ob[(((size_t)j) << 14) + rj * 128 + gx] : 0.0f;
        }
        __syncthreads();
        const unsigned short* hb = hyp + (((size_t)(b * 64 + c)) << 14);
        float a[16];
#pragma unroll
        for (int px = 0; px < 16; ++px) a[px] = 0.0f;
#pragma unroll
        for (int r = 0; r < 3; ++r) {
            const int gyc = min(max(y + r - 1, 0), 127);
            const unsigned short* src = hb + gyc * 128 + gx0 - 8;
            ushort8 w8[4];
#pragma unroll
            for (int q = 0; q < 4; ++q) w8[q] = *(const ushort8*)(src + q * 8);
            float wf[18];
#pragma unroll
            for (int k = 0; k < 18; ++k)
                wf[k] = bf2f((unsigned short)w8[(k + 7) >> 3][(k + 7) & 7]);
#pragma unroll
            for (int ex = -1; ex <= 1; ++ex) {
                const int j = 8 - (r * 3 + (ex + 1));
                const float* osj = ostrip + j * 68 + pq * 16 + 1 + ex;
#pragma unroll
                for (int px = 0; px < 16; ++px)
                    a[px] = fmaf(wf[px + ex + 1], osj[px], a[px]);
            }
        }
        const size_t hob = (((size_t)(b * 64 + c)) << 14) + yxrow + gx0;
#pragma unroll
        for (int q = 0; q < 4; ++q) {
            f32x4 v = {a[q * 4], a[q * 4 + 1], a[q * 4 + 2], a[q * 4 + 3]};
            *(f32x4*)(hidd7 + hob + q * 4) = v;
        }
    }

    const int px = tid & 63, tq = tid >> 6;
    const int yx = yxrow + pxb + px;
    const int i0 = tq, i1 = tq + 4;
    float a0 = 0.0f, a1 = 0.0f, a2 = 0.0f;
    for (int t = 0; t < 8; ++t) {
        const float* ot = o_all + (size_t)t * O_SZ + (((size_t)b * 9) << 14);
        __syncthreads();
        for (int e = tid; e < 198; e += 256) {
            const int r = e / 66, ss = e - r * 66;
            const int ry = y + r - 1, gx = pxb - 1 + ss;
            const bool ok = (ry >= 0) && (ry < 128) && (gx >= 0) && (gx < 128);
            o4s[r * 68 + ss] = ok ? ot[(((size_t)4) << 14) + ry * 128 + gx] : 0.0f;
        }
        __syncthreads();
        {
            const float oi = ot[(((size_t)i0) << 14) + yx];
            const float g = o4s[(i0 / 3) * 68 + px + 1 + (i0 % 3 - 1)];
            const float d = g - oi;
            a0 = fmaf(d * d, oi, a0);
        }
        {
            const float oi = ot[(((size_t)i1) << 14) + yx];
            const float g = o4s[(i1 / 3) * 68 + px + 1 + (i1 % 3 - 1)];
            const float d = g - oi;
            a1 = fmaf(d * d, oi, a1);
        }
        if (tq == 0) {
            const float oi = ot[(((size_t)8) << 14) + yx];
            const float g = o4s[2 * 68 + px + 2];
            const float d = g - oi;
            a2 = fmaf(d * d, oi, a2);
        }
    }
    loss[(((size_t)(b * 9 + i0)) << 14) + yx] = a0 * 0.01f + bt;
    loss[(((size_t)(b * 9 + i1)) << 14) + yx] = a1 * 0.01f + bt;
    if (tq == 0) loss[(((size_t)(b * 9 + 8)) << 14) + yx] = a2 * 0.01f + bt;
}

// ------------------------------------------------------------- launcher
extern "C" void kernel_launch(void* const* d_in, const int* in_sizes, int n_in,
                              void* d_out, int out_size, void* d_ws, size_t ws_size,
                              hipStream_t stream) {
    const float* x    = (const float*)d_in[0];
    const float* mask = (const float*)d_in[1];
    const float* w_ih = (const float*)d_in[2];
    const float* b_ih = (const float*)d_in[3];
    const float* w_hh = (const float*)d_in[4];
    const float* b_hh = (const float*)d_in[5];
    const float* w_ho = (const float*)d_in[6];
    const float* b_ho = (const float*)d_in[7];
    float* out = (float*)d_out;
    float* ws  = (float*)d_ws;

    unsigned short* iall0 = (unsigned short*)(ws + WS_IALL0);
    unsigned short* iall1 = (unsigned short*)(ws + WS_IALL1);
    unsigned short* xTh   = (unsigned short*)(ws + WS_XTH);
    unsigned short* hyA   = (unsigned short*)(ws + WS_HYA) + 8;   // guarded payload
    unsigned short* hyB   = (unsigned short*)(ws + WS_HYB) + 8;
    unsigned short* whhBf = (unsigned short*)(ws + WS_WHH);
    unsigned short* whoBf = (unsigned short*)(ws + WS_WHOB);
    unsigned short* BTf   = (unsigned short*)(ws + WS_BTF);
    float* bceP = ws + WS_BCEP;
    float* lossp = out + LOSS_OFF;

    prep_all<<<740, 256, 0, stream>>>(x, w_hh, w_ho, w_ih, xTh, whhBf, whoBf, BTf);
    conv_step0<<<1024, 256, 0, stream>>>(xTh, BTf, b_ih, b_hh, whoBf, b_ho, mask,
                                         iall0, iall1, hyA, out + OUTS_OFF, bceP);
    for (int t = 1; t < 8; ++t) {
        const unsigned short* hypr = (t & 1) ? hyA : hyB;
        unsigned short* hyc = (t & 1) ? hyB : hyA;
        step_kernel<<<1024, 256, 0, stream>>>(hypr, out + OUTS_OFF + (size_t)(t - 1) * O_SZ,
                                              iall0, iall1, whhBf, b_hh, whoBf, b_ho, mask,
                                              out + (size_t)(t - 1) * HID_SZ, hyc,
                                              out + OUTS_OFF + (size_t)t * O_SZ,
                                              bceP + t * 1024);
    }
    final_fused<<<1024, 256, 0, stream>>>(hyB, out + OUTS_OFF, bceP,
                                          out + (size_t)7 * HID_SZ, lossp);
}

// Round 12
// 224.425 us; speedup vs baseline: 4.2261x; 1.0051x over previous
//
#include <hip/hip_runtime.h>

// B=4, C_IN=64, NUM_HIDDEN=64, H=W=128, MOVESQ=9, T=8
#define NP 16384
#define HID_SZ 4194304      // 4*64*NP
#define O_SZ   589824       // 4*9*NP
#define OUTS_OFF 33554432   // 8*HID_SZ
#define LOSS_OFF 38273024   // OUTS_OFF + 8*O_SZ

// ws layout (float units), ~50.6 MB
#define WS_IALL0 0           // 4,194,304 floats = 8,388,608 ushorts (16B slots)
#define WS_IALL1 4194304     // 2,097,152 floats = 4,194,304 ushorts (8B slots)
#define WS_XTH   6291456     // 2,097,152 floats = 4,194,304 ushorts (x channel-last bf16)
#define WS_HYA   8388608     // guard8 + 4,194,304 ushorts + guard8
#define WS_HYB   10485776    // guard8 + 4,194,304 ushorts + guard8
#define WS_WHH   12582944    // 6144 floats (w_hh bf16 fragment order)
#define WS_WHOB  12589088    // 512 floats (w_ho bf16 fragment order)
#define WS_BTF   12589600    // 55,296 floats (w_ih bf16 fragment order)
#define WS_BCEP  12644896    // 8192 floats

typedef __attribute__((ext_vector_type(8))) short bf16x8;
typedef __attribute__((ext_vector_type(8))) unsigned short ushort8;
typedef __attribute__((ext_vector_type(4))) unsigned short usht4;
typedef __attribute__((ext_vector_type(4))) float f32x4;

__device__ __forceinline__ float frcp(float x) { return __builtin_amdgcn_rcpf(x); }
__device__ __forceinline__ unsigned short f2bf(float f) {
    unsigned int u = __float_as_uint(f);
    return (unsigned short)((u + 0x7fffu + ((u >> 16) & 1u)) >> 16);
}
__device__ __forceinline__ float bf2f(unsigned short h) {
    return __uint_as_float(((unsigned int)h) << 16);
}
// XCD-chunked bijective swizzle for 1024-block grids
__device__ __forceinline__ int swz_bid(int bid) { return ((bid & 7) << 7) | (bid >> 3); }

// ------------------------------------------------------------- prep: transpose_x + weight frags
__global__ __launch_bounds__(256) void prep_all(const float* __restrict__ x,
                                                const float* __restrict__ w_hh,
                                                const float* __restrict__ w_ho,
                                                const float* __restrict__ w_ih,
                                                unsigned short* __restrict__ xTh,
                                                unsigned short* __restrict__ whhBf,
                                                unsigned short* __restrict__ whoBf,
                                                unsigned short* __restrict__ BTf) {
    const int tid = threadIdx.x;
    if (blockIdx.x < 256) {
        const int p = blockIdx.x * 256 + tid;
        const int b = p >> 14, yx = p & 16383;
        const size_t base = ((size_t)p) << 6;
        for (int ic0 = 0; ic0 < 64; ic0 += 8) {
            ushort8 vh;
#pragma unroll
            for (int j = 0; j < 8; ++j)
                vh[j] = f2bf(x[(((size_t)(b * 64 + ic0 + j)) << 14) + yx]);
            *(ushort8*)(xTh + base + ic0) = vh;
        }
    } else {
        int i = (blockIdx.x - 256) * 256 + tid;
        if (i < 12288) {                        // whhBf: f=ih*12+n
            int f = i >> 9, r = i & 511;
            int lane = r >> 3, e = r & 7, lrow = lane & 15, lkq = lane >> 4;
            int ih = f / 12, n = f % 12;
            whhBf[i] = f2bf(w_hh[(n * 16 + lrow) * 64 + ih * 32 + lkq * 8 + e]);
        } else if (i < 13312) {                 // whoBf: f=ih
            int j = i - 12288;
            int f = j >> 9, r = j & 511;
            int lane = r >> 3, e = r & 7, lrow = lane & 15, lkq = lane >> 4;
            whoBf[j] = (lrow < 9) ? f2bf(w_ho[lrow * 64 + f * 32 + lkq * 8 + e]) : (unsigned short)0;
        } else if (i < 13312 + 110592) {        // BTf: f=(tap*2+ih)*12+n
            int k2 = i - 13312;
            int f = k2 >> 9, r = k2 & 511;
            int lane = r >> 3, e = r & 7, lrow = lane & 15, lkq = lane >> 4;
            int tapih = f / 12, n = f % 12;
            int tap = tapih >> 1, ih = tapih & 1;
            int oc = n * 16 + lrow, ic = ih * 32 + lkq * 8 + e;
            BTf[k2] = f2bf(w_ih[(oc * 64 + ic) * 9 + tap]);
        }
    }
}

// ------------------------------------------------------------- conv + step0 fused
// Conv: wave w = (px-half m2 = w>>1, n-half nh = w&1): 2 A-frags x 6 B-frags per (tap,ih)
// -> B VMEM loads halved vs 1x12 split. Epilogue bounces fragments through an LDS mirror in
// exact iall slot format, so iall bytes and all downstream kernels are unchanged.
__global__ __launch_bounds__(256, 4) void conv_step0(const unsigned short* __restrict__ xTh,
                                                     const unsigned short* __restrict__ BTf,
                                                     const float* __restrict__ b_ih,
                                                     const float* __restrict__ b_hh,
                                                     const unsigned short* __restrict__ whoBf,
                                                     const float* __restrict__ b_ho,
                                                     const float* __restrict__ mask,
                                                     unsigned short* __restrict__ iall0,
                                                     unsigned short* __restrict__ iall1,
                                                     unsigned short* __restrict__ hy_cur,
                                                     float* __restrict__ o_out,
                                                     float* __restrict__ bceP) {
    __shared__ __align__(16) unsigned char smem[25344];
    unsigned short* ml0 = (unsigned short*)smem;            // mirror of iall0 row: 16 KB
    unsigned short* ml1 = (unsigned short*)(smem + 16384);  // mirror of iall1 row:  8 KB
    unsigned short* hy_p = (unsigned short*)(smem + 10656); // valid after mirror consumed
    float* red = (float*)(smem + 19872);
    const int tid = threadIdx.x;
    const int bid = swz_bid(blockIdx.x);
    const int b = bid >> 8, y = (bid >> 1) & 127, hh2 = bid & 1;
    const int pxb = hh2 * 64, yxrow = y * 128;

    for (int ch = tid; ch < 1584; ch += 256) {            // 3*66*8 chunks
        const int row = ch / 528;
        const int rem = ch - row * 528;
        const int pxl = rem >> 3, icc = rem & 7;
        const int gy = y + row - 1, gx = pxb + pxl - 1;
        ushort8 vh = {};
        if (gy >= 0 && gy < 128 && gx >= 0 && gx < 128) {
            const size_t go = ((size_t)(b * 16384 + gy * 128 + gx)) * 64 + icc * 8;
            vh = *(const ushort8*)(xTh + go);
        }
        const int off = ((row * 66 + pxl) * 128 + icc * 16) ^ ((pxl & 7) << 4);
        *(ushort8*)(smem + off) = vh;
    }
    __syncthreads();

    const int lane = tid & 63, wv = tid >> 6;
    const int lrow = lane & 15, lkq = lane >> 4;
    const int m2 = wv >> 1, nh = wv & 1;
    const unsigned short* BTl = BTf + lane * 8;

    f32x4 acc[2][6] = {};
#pragma unroll
    for (int tap = 0; tap < 9; ++tap) {
        const int row = tap / 3, dx = tap % 3 - 1;
#pragma unroll
        for (int ih = 0; ih < 2; ++ih) {
            bf16x8 Ah[2];
#pragma unroll
            for (int mm = 0; mm < 2; ++mm) {
                const int pxl = m2 * 32 + mm * 16 + lrow + dx + 1;
                const int off = ((row * 66 + pxl) * 128 + ih * 64 + lkq * 16) ^ ((pxl & 7) << 4);
                Ah[mm] = *(const bf16x8*)(smem + off);
            }
#pragma unroll
            for (int nn = 0; nn < 6; ++nn) {
                const int n = nh * 6 + nn;
                bf16x8 Bh = *(const bf16x8*)(BTl + (((tap * 2 + ih) * 12 + n) << 9));
#pragma unroll
                for (int mm = 0; mm < 2; ++mm)
                    acc[mm][nn] = __builtin_amdgcn_mfma_f32_16x16x32_bf16(Ah[mm], Bh, acc[mm][nn], 0, 0, 0);
            }
        }
    }
    __syncthreads();   // x-tile dead; mirror may overwrite

    float bias[6];
#pragma unroll
    for (int nn = 0; nn < 6; ++nn) bias[nn] = b_ih[(nh * 6 + nn) * 16 + lrow];
    // bounce acc -> LDS mirror in iall slot format (value(px,oc): slot s=(px>>4)*4+(px&3),
    // lane_t = ((px>>2)&3)*16 + (oc&15) = lane here; n = oc>>4)
#pragma unroll
    for (int mm = 0; mm < 2; ++mm) {
        const int sbase = (m2 * 2 + mm) * 4;
#pragma unroll
        for (int r = 0; r < 4; ++r) {
            const int s = sbase + r;
#pragma unroll
            for (int np = 0; np < 3; ++np) {
                const int n = nh * 6 + np * 2;
                unsigned int pk = (unsigned int)f2bf(acc[mm][np * 2][r] + bias[np * 2])
                                | ((unsigned int)f2bf(acc[mm][np * 2 + 1][r] + bias[np * 2 + 1]) << 16);
                if (n < 8) *(unsigned int*)(ml0 + s * 512 + lane * 8 + n) = pk;
                else       *(unsigned int*)(ml1 + s * 256 + lane * 4 + (n - 8)) = pk;
            }
        }
    }
    __syncthreads();

    // read gate chunks (old per-wave slot ownership) -> regs; write iall global (bytes identical)
    ushort8 lo[4];
    usht4 hi[4];
#pragma unroll
    for (int rr = 0; rr < 4; ++rr) {
        lo[rr] = *(const ushort8*)(ml0 + ((wv * 4 + rr) << 9) + lane * 8);
        hi[rr] = *(const usht4*)(ml1 + ((wv * 4 + rr) << 8) + lane * 4);
    }
    __syncthreads();   // mirror dead; hy_p region may be written

    const size_t rowb = (size_t)((b * 128 + y) * 2 + hh2);
#pragma unroll
    for (int rr = 0; rr < 4; ++rr) {
        *(ushort8*)(iall0 + (rowb << 13) + ((wv * 4 + rr) << 9) + lane * 8) = lo[rr];
        *(usht4*)(iall1 + (rowb << 12) + ((wv * 4 + rr) << 8) + lane * 4) = hi[rr];
    }

    // gates (t=0, h_prev = 0)
    float bhr[4], bhi[4], bhn[4];
#pragma unroll
    for (int nf = 0; nf < 4; ++nf) {
        bhr[nf] = b_hh[nf * 16 + lrow];
        bhi[nf] = b_hh[64 + nf * 16 + lrow];
        bhn[nf] = b_hh[128 + nf * 16 + lrow];
    }
#pragma unroll
    for (int nf = 0; nf < 4; ++nf) {
        const int g = nf * 16 + lrow;
        usht4 hv4;
#pragma unroll
        for (int rr = 0; rr < 4; ++rr) {
            const int pxl = wv * 16 + lkq * 4 + rr;
            float ir = bf2f(lo[rr][nf]), ii = bf2f(lo[rr][4 + nf]), inn = bf2f(hi[rr][nf]);
            float rg = frcp(1.0f + __expf(-(ir + bhr[nf])));
            float ig = frcp(1.0f + __expf(-(ii + bhi[nf])));
            float t2 = __expf(2.0f * (inn + rg * bhn[nf]));
            float nn = 1.0f - 2.0f * frcp(t2 + 1.0f);
            unsigned short hv = f2bf(nn + ig * (0.0f - nn));
            hy_p[pxl * 72 + g] = hv;
            hv4[rr] = hv;
        }
        *(usht4*)(hy_cur + (((size_t)(b * 64 + g)) << 14) + yxrow + pxb + wv * 16 + lkq * 4) = hv4;
    }
    __syncthreads();

    // o-logits via MFMA + 16-lane-group shuffle softmax + bce wave reduce
    f32x4 aco = {};
#pragma unroll
    for (int ih = 0; ih < 2; ++ih) {
        const int pxa = wv * 16 + lrow;
        bf16x8 Ao = *(const bf16x8*)(hy_p + pxa * 72 + ih * 32 + lkq * 8);
        bf16x8 Bo = *(const bf16x8*)(whoBf + ((ih << 9) + lane * 8));
        aco = __builtin_amdgcn_mfma_f32_16x16x32_bf16(Ao, Bo, aco, 0, 0, 0);
    }
    const float bho = (lrow < 9) ? b_ho[lrow] : 0.0f;
    float ov[4];
    float vbce = 0.0f;
    const int yx0 = yxrow + pxb + wv * 16 + lkq * 4;
#pragma unroll
    for (int r = 0; r < 4; ++r) {
        float lg = aco[r] + bho;
        float v = (lrow < 9) ? lg : -1e30f;
        v = fmaxf(v, __shfl_xor(v, 1));
        v = fmaxf(v, __shfl_xor(v, 2));
        v = fmaxf(v, __shfl_xor(v, 4));
        v = fmaxf(v, __shfl_xor(v, 8));
        float e = (lrow < 9) ? __expf(lg - v) : 0.0f;
        float s = e;
        s += __shfl_xor(s, 1);
        s += __shfl_xor(s, 2);
        s += __shfl_xor(s, 4);
        s += __shfl_xor(s, 8);
        ov[r] = e * frcp(s);
    }
    if (lrow < 9) {
        f32x4 wvec = {ov[0], ov[1], ov[2], ov[3]};
        *(f32x4*)(o_out + (((size_t)(b * 9 + lrow)) << 14) + yx0) = wvec;
    }
    if (lrow == 4) {
        const f32x4 mk = *(const f32x4*)(mask + (((size_t)b) << 14) + yx0);
#pragma unroll
        for (int r = 0; r < 4; ++r)
            vbce += mk[r] * __logf(1.0f - ov[r]) + (1.0f - mk[r]) * __logf(ov[r]);
    }
    float v = (lrow == 4) ? vbce : 0.0f;
#pragma unroll
    for (int d = 1; d < 64; d <<= 1) v += __shfl_xor(v, d);
    if (lane == 0) red[wv] = v;
    __syncthreads();
    if (tid == 0) bceP[bid] = red[0] + red[1] + red[2] + red[3];
}

// ------------------------------------------------------------- fused step kernel (t>=1, half-row)
__global__ __launch_bounds__(256, 4) void step_kernel(const unsigned short* __restrict__ hyp,
                                                      const float* __restrict__ o_prev,
                                                      const unsigned short* __restrict__ iall0,
                                                      const unsigned short* __restrict__ iall1,
                                                      const unsigned short* __restrict__ whhBf,
                                                      const float* __restrict__ b_hh,
                                                      const unsigned short* __restrict__ whoBf,
                                                      const float* __restrict__ b_ho,
                                                      const float* __restrict__ mask,
                                                      float* __restrict__ hidd_out,
                                                      unsigned short* __restrict__ hy_cur,
                                                      float* __restrict__ o_out,
                                                      float* __restrict__ bceP) {
    __shared__ __align__(16) unsigned char smem[19904];
    float* ostrip = (float*)(smem + 8192);
    unsigned short* hy_p = (unsigned short*)(smem + 10656);
    float* red = (float*)(smem + 19872);

    const int tid = threadIdx.x;
    const int bid = swz_bid(blockIdx.x);
    const int b = bid >> 8, y = (bid >> 1) & 127, hh2 = bid & 1;
    const int pxb = hh2 * 64, yxrow = y * 128;
    const int lane = tid & 63, wv = tid >> 6;
    const int lrow = lane & 15, lkq = lane >> 4;

    // hoisted iall loads (t-invariant addresses): latency hides under ph1
    const size_t rowb = (size_t)((b * 128 + y) * 2 + hh2);
    const unsigned short* p0 = iall0 + (rowb << 13) + (wv << 11) + lane * 8;
    const unsigned short* p1 = iall1 + (rowb << 12) + (wv << 10) + lane * 4;
    ushort8 lo[4];
    usht4 hi[4];
#pragma unroll
    for (int rr = 0; rr < 4; ++rr) {
        lo[rr] = *(const ushort8*)(p0 + (rr << 9));
        hi[rr] = *(const usht4*)(p1 + (rr << 8));
    }

    {
        const int c = tid >> 2, pq = tid & 3;
        const int gx0 = pxb + pq * 16;
        const unsigned short* hb = hyp + (((size_t)(b * 64 + c)) << 14);
        ushort8 w8[3][4];
#pragma unroll
        for (int r = 0; r < 3; ++r) {
            const int gyc = min(max(y + r - 1, 0), 127);
            const unsigned short* src = hb + gyc * 128 + gx0 - 8;   // guarded buffer
#pragma unroll
            for (int q = 0; q < 4; ++q) w8[r][q] = *(const ushort8*)(src + q * 8);
        }
        const float* ob = o_prev + (((size_t)b * 9) << 14);
        for (int e = tid; e < 594; e += 256) {
            const int j = e / 66, s = e - j * 66;
            const int rj = y + 1 - j / 3;
            const int gx = pxb - 1 + s;
            const bool ok = (rj >= 0) && (rj < 128) && (gx >= 0) && (gx < 128);
            ostrip[j * 68 + s] = ok ? ob[(((size_t)j) << 14) + rj * 128 + gx] : 0.0f;
        }
        __syncthreads();

        float a[16];
#pragma unroll
        for (int px = 0; px < 16; ++px) a[px] = 0.0f;
#pragma unroll
        for (int r = 0; r < 3; ++r) {
            float wf[18];
#pragma unroll
            for (int k = 0; k < 18; ++k)
                wf[k] = bf2f((unsigned short)w8[r][(k + 7) >> 3][(k + 7) & 7]);
#pragma unroll
            for (int ex = -1; ex <= 1; ++ex) {
                const int idx = r * 3 + (ex + 1);
                const int j = 8 - idx;
                const float* osj = ostrip + j * 68 + pq * 16 + 1 + ex;
#pragma unroll
                for (int px = 0; px < 16; ++px)
                    a[px] = fmaf(wf[px + ex + 1], osj[px], a[px]);
            }
        }
        const size_t hob = (((size_t)(b * 64 + c)) << 14) + yxrow + gx0;
#pragma unroll
        for (int q = 0; q < 4; ++q) {
            f32x4 v = {a[q * 4], a[q * 4 + 1], a[q * 4 + 2], a[q * 4 + 3]};
            *(f32x4*)(hidd_out + hob + q * 4) = v;
        }
#pragma unroll
        for (int px = 0; px < 16; ++px) {
            const int pxl = pq * 16 + px;
            *(unsigned short*)(smem + ((pxl * 128 + c * 2) ^ ((pxl & 7) << 4))) = f2bf(a[px]);
        }
        __syncthreads();
    }

    f32x4 acc[12] = {};
    {
        bf16x8 Ah[2];
#pragma unroll
        for (int ih = 0; ih < 2; ++ih) {
            const int pxa = wv * 16 + lrow;
            const int off = (pxa * 128 + ih * 64 + lkq * 16) ^ ((pxa & 7) << 4);
            Ah[ih] = *(const bf16x8*)(smem + off);
        }
#pragma unroll
        for (int ih = 0; ih < 2; ++ih)
#pragma unroll
            for (int n = 0; n < 12; ++n) {
                bf16x8 Bh = *(const bf16x8*)(whhBf + (((ih * 12 + n) << 9) + lane * 8));
                acc[n] = __builtin_amdgcn_mfma_f32_16x16x32_bf16(Ah[ih], Bh, acc[n], 0, 0, 0);
            }
    }

    // gates
    float bhr[4], bhi[4], bhn[4];
#pragma unroll
    for (int nf = 0; nf < 4; ++nf) {
        bhr[nf] = b_hh[nf * 16 + lrow];
        bhi[nf] = b_hh[64 + nf * 16 + lrow];
        bhn[nf] = b_hh[128 + nf * 16 + lrow];
    }
#pragma unroll
    for (int nf = 0; nf < 4; ++nf) {
        const int g = nf * 16 + lrow;
        usht4 hv4;
#pragma unroll
        for (int rr = 0; rr < 4; ++rr) {
            const int pxl = wv * 16 + lkq * 4 + rr;
            float hr = bhr[nf] + acc[nf][rr];
            float hig = bhi[nf] + acc[nf + 4][rr];
            float hn = bhn[nf] + acc[nf + 8][rr];
            float ir = bf2f(lo[rr][nf]), ii = bf2f(lo[rr][4 + nf]), inn = bf2f(hi[rr][nf]);
            float rg = frcp(1.0f + __expf(-(ir + hr)));
            float ig = frcp(1.0f + __expf(-(ii + hig)));
            float t2 = __expf(2.0f * (inn + rg * hn));
            float nn = 1.0f - 2.0f * frcp(t2 + 1.0f);
            const int offA = (pxl * 128 + g * 2) ^ ((pxl & 7) << 4);
            float hp = bf2f(*(const unsigned short*)(smem + offA));
            unsigned short hv = f2bf(nn + ig * (hp - nn));
            hy_p[pxl * 72 + g] = hv;
            hv4[rr] = hv;
        }
        *(usht4*)(hy_cur + (((size_t)(b * 64 + g)) << 14) + yxrow + pxb + wv * 16 + lkq * 4) = hv4;
    }
    __syncthreads();

    // o-logits via MFMA + shuffle softmax + bce
    f32x4 aco = {};
#pragma unroll
    for (int ih = 0; ih < 2; ++ih) {
        const int pxa = wv * 16 + lrow;
        bf16x8 Ao = *(const bf16x8*)(hy_p + pxa * 72 + ih * 32 + lkq * 8);
        bf16x8 Bo = *(const bf16x8*)(whoBf + ((ih << 9) + lane * 8));
        aco = __builtin_amdgcn_mfma_f32_16x16x32_bf16(Ao, Bo, aco, 0, 0, 0);
    }
    const float bho = (lrow < 9) ? b_ho[lrow] : 0.0f;
    float ov[4];
    float vbce = 0.0f;
    const int yx0 = yxrow + pxb + wv * 16 + lkq * 4;
#pragma unroll
    for (int r = 0; r < 4; ++r) {
        float lg = aco[r] + bho;
        float v = (lrow < 9) ? lg : -1e30f;
        v = fmaxf(v, __shfl_xor(v, 1));
        v = fmaxf(v, __shfl_xor(v, 2));
        v = fmaxf(v, __shfl_xor(v, 4));
        v = fmaxf(v, __shfl_xor(v, 8));
        float e = (lrow < 9) ? __expf(lg - v) : 0.0f;
        float s = e;
        s += __shfl_xor(s, 1);
        s += __shfl_xor(s, 2);
        s += __shfl_xor(s, 4);
        s += __shfl_xor(s, 8);
        ov[r] = e * frcp(s);
    }
    if (lrow < 9) {
        f32x4 wvec = {ov[0], ov[1], ov[2], ov[3]};
        *(f32x4*)(o_out + (((size_t)(b * 9 + lrow)) << 14) + yx0) = wvec;
    }
    if (lrow == 4) {
        const f32x4 mk = *(const f32x4*)(mask + (((size_t)b) << 14) + yx0);
#pragma unroll
        for (int r = 0; r < 4; ++r)
            vbce += mk[r] * __logf(1.0f - ov[r]) + (1.0f - mk[r]) * __logf(ov[r]);
    }
    float v = (lrow == 4) ? vbce : 0.0f;
#pragma unroll
    for (int d = 1; d < 64; d <<= 1) v += __shfl_xor(v, d);
    if (lane == 0) red[wv] = v;
    __syncthreads();
    if (tid == 0) bceP[bid] = red[0] + red[1] + red[2] + red[3];
}

// ------------------------------------------------------------- final: merge h_8 + bce total + loss
__global__ __launch_bounds__(256) void final_fused(const unsigned short* __restrict__ hyp,
                                                   const float* __restrict__ o_all,
                                                   const float* __restrict__ bceP,
                                                   float* __restrict__ hidd7,
                                                   float* __restrict__ loss) {
    __shared__ __align__(16) float ostrip[9 * 68];
    __shared__ float o4s[3 * 68];
    __shared__ float redsh[256];
    const int tid = threadIdx.x;
    const int bid = swz_bid(blockIdx.x);
    const int b = bid >> 8, y = (bid >> 1) & 127, hh2 = bid & 1;
    const int pxb = hh2 * 64, yxrow = y * 128;

    // issue bce partial loads first (independent); reduce later so they hide under merge
    float s = 0.0f;
    for (int i = tid; i < 8192; i += 256) s += bceP[i];

    {
        const int c = tid >> 2, pq = tid & 3;
        const int gx0 = pxb + pq * 16;
        const float* ob = o_all + (size_t)7 * O_SZ + (((size_t)b * 9) << 14);
        for (int e = tid; e < 594; e += 256) {
            const int j = e / 66, ss = e - j * 66;
            const int rj = y + 1 - j / 3;
            const int gx = pxb - 1 + ss;
            const bool ok = (rj >= 0) && (rj < 128) && (gx >= 0) && (gx < 128);
            ostrip[j * 68 + ss] = ok ? ob[(((size_t)j) << 14) + rj * 128 + gx] : 0.0f;
        }
        __syncthreads();
        const unsigned short* hb = hyp + (((size_t)(b * 64 + c)) << 14);
        float a[16];
#pragma unroll
        for (int px = 0; px < 16; ++px) a[px] = 0.0f;
#pragma unroll
        for (int r = 0; r < 3; ++r) {
            const int gyc = min(max(y + r - 1, 0), 127);
            const unsigned short* src = hb + gyc * 128 + gx0 - 8;
            ushort8 w8[4];
#pragma unroll
            for (int q = 0; q < 4; ++q) w8[q] = *(const ushort8*)(src + q * 8);
            float wf[18];
#pragma unroll
            for (int k = 0; k < 18; ++k)
                wf[k] = bf2f((unsigned short)w8[(k + 7) >> 3][(k + 7) & 7]);
#pragma unroll
            for (int ex = -1; ex <= 1; ++ex) {
                const int j = 8 - (r * 3 + (ex + 1));
                const float* osj = ostrip + j * 68 + pq * 16 + 1 + ex;
#pragma unroll
                for (int px = 0; px < 16; ++px)
                    a[px] = fmaf(wf[px + ex + 1], osj[px], a[px]);
            }
        }
        const size_t hob = (((size_t)(b * 64 + c)) << 14) + yxrow + gx0;
#pragma unroll
        for (int q = 0; q < 4; ++q) {
            f32x4 v = {a[q * 4], a[q * 4 + 1], a[q * 4 + 2], a[q * 4 + 3]};
            *(f32x4*)(hidd7 + hob + q * 4) = v;
        }
    }

    // bce reduction (after merge so loads overlapped)
    __syncthreads();
    redsh[tid] = s;
    __syncthreads();
    for (int off = 128; off > 0; off >>= 1) {
        if (tid < off) redsh[tid] += redsh[tid + off];
        __syncthreads();
    }
    const float bt = -redsh[0] * (1.0f / 65536.0f);

    const int px = tid & 63, tq = tid >> 6;
    const int yx = yxrow + pxb + px;
    const int i0 = tq, i1 = tq + 4;
    float a0 = 0.0f, a1 = 0.0f, a2 = 0.0f;
    for (int t = 0; t < 8; ++t) {
        const float* ot = o_all + (size_t)t * O_SZ + (((size_t)b * 9) << 14);
        __syncthreads();
        for (int e = tid; e < 198; e += 256) {
            const int r = e / 66, ss = e - r * 66;
            const int ry = y + r - 1, gx = pxb - 1 + ss;
            const bool ok = (ry >= 0) && (ry < 128) && (gx >= 0) && (gx < 128);
            o4s[r * 68 + ss] = ok ? ot[(((size_t)4) << 14) + ry * 128 + gx] : 0.0f;
        }
        __syncthreads();
        {
            const float oi = ot[(((size_t)i0) << 14) + yx];
            const float g = o4s[(i0 / 3) * 68 + px + 1 + (i0 % 3 - 1)];
            const float d = g - oi;
            a0 = fmaf(d * d, oi, a0);
        }
        {
            const float oi = ot[(((size_t)i1) << 14) + yx];
            const float g = o4s[(i1 / 3) * 68 + px + 1 + (i1 % 3 - 1)];
            const float d = g - oi;
            a1 = fmaf(d * d, oi, a1);
        }
        if (tq == 0) {
            const float oi = ot[(((size_t)8) << 14) + yx];
            const float g = o4s[2 * 68 + px + 2];
            const float d = g - oi;
            a2 = fmaf(d * d, oi, a2);
        }
    }
    loss[(((size_t)(b * 9 + i0)) << 14) + yx] = a0 * 0.01f + bt;
    loss[(((size_t)(b * 9 + i1)) << 14) + yx] = a1 * 0.01f + bt;
    if (tq == 0) loss[(((size_t)(b * 9 + 8)) << 14) + yx] = a2 * 0.01f + bt;
}

// ------------------------------------------------------------- launcher
extern "C" void kernel_launch(void* const* d_in, const int* in_sizes, int n_in,
                              void* d_out, int out_size, void* d_ws, size_t ws_size,
                              hipStream_t stream) {
    const float* x    = (const float*)d_in[0];
    const float* mask = (const float*)d_in[1];
    const float* w_ih = (const float*)d_in[2];
    const float* b_ih = (const float*)d_in[3];
    const float* w_hh = (const float*)d_in[4];
    const float* b_hh = (const float*)d_in[5];
    const float* w_ho = (const float*)d_in[6];
    const float* b_ho = (const float*)d_in[7];
    float* out = (float*)d_out;
    float* ws  = (float*)d_ws;

    unsigned short* iall0 = (unsigned short*)(ws + WS_IALL0);
    unsigned short* iall1 = (unsigned short*)(ws + WS_IALL1);
    unsigned short* xTh   = (unsigned short*)(ws + WS_XTH);
    unsigned short* hyA   = (unsigned short*)(ws + WS_HYA) + 8;   // guarded payload
    unsigned short* hyB   = (unsigned short*)(ws + WS_HYB) + 8;
    unsigned short* whhBf = (unsigned short*)(ws + WS_WHH);
    unsigned short* whoBf = (unsigned short*)(ws + WS_WHOB);
    unsigned short* BTf   = (unsigned short*)(ws + WS_BTF);
    float* bceP = ws + WS_BCEP;
    float* lossp = out + LOSS_OFF;

    prep_all<<<740, 256, 0, stream>>>(x, w_hh, w_ho, w_ih, xTh, whhBf, whoBf, BTf);
    conv_step0<<<1024, 256, 0, stream>>>(xTh, BTf, b_ih, b_hh, whoBf, b_ho, mask,
                                         iall0, iall1, hyA, out + OUTS_OFF, bceP);
    for (int t = 1; t < 8; ++t) {
        const unsigned short* hypr = (t & 1) ? hyA : hyB;
        unsigned short* hyc = (t & 1) ? hyB : hyA;
        step_kernel<<<1024, 256, 0, stream>>>(hypr, out + OUTS_OFF + (size_t)(t - 1) * O_SZ,
                                              iall0, iall1, whhBf, b_hh, whoBf, b_ho, mask,
                                              out + (size_t)(t - 1) * HID_SZ, hyc,
                                              out + OUTS_OFF + (size_t)t * O_SZ,
                                              bceP + t * 1024);
    }
    final_fused<<<1024, 256, 0, stream>>>(hyB, out + OUTS_OFF, bceP,
                                          out + (size_t)7 * HID_SZ, lossp);
}